// Round 7
// baseline (1112.627 us; speedup 1.0000x reference)
//
#include <hip/hip_runtime.h>
#include <cstdint>
#include <cstddef>

#define NN 50000
#define NE 500000

typedef unsigned short u16;
typedef __attribute__((ext_vector_type(8))) short bf16x8;
typedef __attribute__((ext_vector_type(4))) float f32x4;
typedef __attribute__((ext_vector_type(4))) unsigned short u16x4;
typedef __attribute__((ext_vector_type(8))) unsigned short u16x8;

__device__ __forceinline__ float relu_f(float v) { return fmaxf(v, 0.0f); }

__device__ __forceinline__ u16 f2bf(float f) {
    union { float f; unsigned u; } c; c.f = f;
    unsigned u = c.u;
    unsigned r = u + 0x7FFFu + ((u >> 16) & 1u);
    return (u16)(r >> 16);
}
__device__ __forceinline__ float bf2f(u16 h) {
    union { unsigned u; float f; } c; c.u = ((unsigned)h) << 16;
    return c.f;
}

// ---------------- degree count + reciprocal ----------------
__global__ __launch_bounds__(256) void k_count(const int* __restrict__ dst, float* __restrict__ cnt) {
    int e = blockIdx.x * 256 + threadIdx.x;
    if (e < NE) atomicAdd(&cnt[dst[e]], 1.0f);
}

__global__ __launch_bounds__(256) void k_invcnt(float* __restrict__ cnt) {
    int i = blockIdx.x * 256 + threadIdx.x;
    if (i < NN) cnt[i] = 1.0f / fmaxf(cnt[i], 1.0f);
}

// ---------------- counting sort of edges by dst ----------------
__global__ __launch_bounds__(256) void k_hist(const int* __restrict__ dst, int* __restrict__ h) {
    int e = blockIdx.x * 256 + threadIdx.x;
    if (e < NE) atomicAdd(&h[dst[e]], 1);
}

__global__ __launch_bounds__(512) void k_scan1(const int* __restrict__ h,
                                               int* __restrict__ excl, int* __restrict__ bsum) {
    __shared__ int s[512];
    int tid = threadIdx.x;
    int i = blockIdx.x * 512 + tid;
    int v = (i < NN) ? h[i] : 0;
    s[tid] = v;
    __syncthreads();
    for (int off = 1; off < 512; off <<= 1) {
        int t = (tid >= off) ? s[tid - off] : 0;
        __syncthreads();
        s[tid] += t;
        __syncthreads();
    }
    if (i < NN) excl[i] = s[tid] - v;
    if (tid == 511) bsum[blockIdx.x] = s[511];
}

__global__ __launch_bounds__(128) void k_scan2(int* __restrict__ bsum, int nb) {
    __shared__ int s[128];
    int tid = threadIdx.x;
    int v = (tid < nb) ? bsum[tid] : 0;
    s[tid] = v;
    __syncthreads();
    for (int off = 1; off < 128; off <<= 1) {
        int t = (tid >= off) ? s[tid - off] : 0;
        __syncthreads();
        s[tid] += t;
        __syncthreads();
    }
    if (tid < nb) bsum[tid] = s[tid] - v;
}

__global__ __launch_bounds__(512) void k_scan3(const int* __restrict__ excl, const int* __restrict__ bsum,
                                               int* __restrict__ cursor) {
    int i = blockIdx.x * 512 + threadIdx.x;
    if (i < NN) cursor[i] = excl[i] + bsum[blockIdx.x];
}

__global__ __launch_bounds__(256) void k_scatter(const int* __restrict__ dst,
                                                 int* __restrict__ cursor, int* __restrict__ perm) {
    int e = blockIdx.x * 256 + threadIdx.x;
    if (e < NE) {
        int pos = atomicAdd(&cursor[dst[e]], 1);
        perm[pos] = e;
    }
}

__global__ __launch_bounds__(256) void k_permidx(const int* __restrict__ src, const int* __restrict__ dst,
                                                 const int* __restrict__ perm,
                                                 int* __restrict__ sp, int* __restrict__ dp) {
    int i = blockIdx.x * 256 + threadIdx.x;
    if (i < NE) {
        int pe = perm[i];
        sp[i] = src[pe];
        dp[i] = dst[pe];
    }
}

// ---------------- fp32 -> split bf16 planes (x4 vectorized) ----------------
__global__ __launch_bounds__(256) void k_split(const float* __restrict__ in,
                                               u16* __restrict__ hi, u16* __restrict__ lo, int n4) {
    int i = blockIdx.x * 256 + threadIdx.x;   // over n/4 quads
    if (i < n4) {
        float4 v = ((const float4*)in)[i];
        float vv[4] = {v.x, v.y, v.z, v.w};
        u16x4 hv, lv;
#pragma unroll
        for (int j = 0; j < 4; ++j) {
            u16 h = f2bf(vv[j]);
            hv[j] = h;
            lv[j] = f2bf(vv[j] - bf2f(h));
        }
        ((u16x4*)hi)[i] = hv;
        ((u16x4*)lo)[i] = lv;
    }
}

// permuted (dst-sorted) split of edge features, x4 vectorized:
// 16 lanes cover one 256B row; float4 gathered read + 2x ushort4 writes per lane
__global__ __launch_bounds__(256) void k_split_e_perm(const float* __restrict__ e,
                                                      const int* __restrict__ perm,
                                                      u16* __restrict__ eh, u16* __restrict__ el) {
    int g = blockIdx.x * 256 + threadIdx.x;  // over NE*16
    int i = g >> 4, c4 = (g & 15) << 2;
    if (i < NE) {
        float4 v = *(const float4*)(e + (long)perm[i] * 64 + c4);
        float vv[4] = {v.x, v.y, v.z, v.w};
        u16x4 hv, lv;
#pragma unroll
        for (int j = 0; j < 4; ++j) {
            u16 h = f2bf(vv[j]);
            hv[j] = h;
            lv[j] = f2bf(vv[j] - bf2f(h));
        }
        long o = (long)i * 64 + c4;
        *(u16x4*)(eh + o) = hv;
        *(u16x4*)(el + o) = lv;
    }
}

// ---------------- W[k][n] -> transposed split planes Wt[n][k] ----------------
__global__ __launch_bounds__(256) void k_wt(const float* __restrict__ W,
                                            u16* __restrict__ th, u16* __restrict__ tl,
                                            int K, int N) {
    int i = blockIdx.x * 256 + threadIdx.x;
    if (i < K * N) {
        int n = i / K, k = i - n * K;
        float v = W[(size_t)k * N + n];
        u16 h = f2bf(v);
        th[i] = h;
        tl[i] = f2bf(v - bf2f(h));
    }
}

// WeX^T: out[j][k] = We[k + (j>=64?128:0)][j&63], j,k in [0,128)
__global__ __launch_bounds__(256) void k_wt2(const float* __restrict__ We,
                                             u16* __restrict__ th, u16* __restrict__ tl) {
    int i = blockIdx.x * 256 + threadIdx.x;
    if (i < 128 * 128) {
        int j = i >> 7, k = i & 127;
        float v = We[(size_t)(k + ((j >> 6) << 7)) * 64 + (j & 63)];
        u16 h = f2bf(v);
        th[i] = h;
        tl[i] = f2bf(v - bf2f(h));
    }
}

// ================= generic node GEMM: C = x @ B + bias (fp32 out, no relu) =================
// rows=nodes (128/block), K=128 from x planes; B transposed planes with row stride bstride
__global__ __launch_bounds__(256) void k_ngemm(
    const u16* __restrict__ xh, const u16* __restrict__ xl,
    const u16* __restrict__ Bth, const u16* __restrict__ Btl, int bstride,
    const float* __restrict__ bias0, const float* __restrict__ bias1,  // cols 0-63 / 64-127
    float* __restrict__ C)
{
    __shared__ u16 Ah[128][40], Al[128][40], Bh[128][40], Bl[128][40];
    const int tid = threadIdx.x;
    const long rowbase = (long)blockIdx.x * 128;
    const int wave = tid >> 6, lane = tid & 63;
    const int quad = lane >> 4, lrow = lane & 15;
    const int wr = wave >> 1, wc = wave & 1;
    const int arow = tid >> 1, akh = (tid & 1) << 4;

    f32x4 acc[4][4];
#pragma unroll
    for (int r = 0; r < 4; ++r)
#pragma unroll
        for (int c = 0; c < 4; ++c) acc[r][c] = (f32x4){0.f, 0.f, 0.f, 0.f};

    for (int kp = 0; kp < 4; ++kp) {
        const int k0 = kp * 32;
        {
            long r = rowbase + arow; if (r >= NN) r = NN - 1;
            long b = r * 128 + k0 + akh;
            *(int4*)&Ah[arow][akh]     = *(const int4*)(xh + b);
            *(int4*)&Ah[arow][akh + 8] = *(const int4*)(xh + b + 8);
            *(int4*)&Al[arow][akh]     = *(const int4*)(xl + b);
            *(int4*)&Al[arow][akh + 8] = *(const int4*)(xl + b + 8);
        }
        {
            long b = (long)arow * bstride + k0 + akh;
            *(int4*)&Bh[arow][akh]     = *(const int4*)(Bth + b);
            *(int4*)&Bh[arow][akh + 8] = *(const int4*)(Bth + b + 8);
            *(int4*)&Bl[arow][akh]     = *(const int4*)(Btl + b);
            *(int4*)&Bl[arow][akh + 8] = *(const int4*)(Btl + b + 8);
        }
        __syncthreads();
        bf16x8 ah[4], al[4], bh[4], bl[4];
#pragma unroll
        for (int r = 0; r < 4; ++r) {
            ah[r] = *(const bf16x8*)&Ah[wr * 64 + r * 16 + lrow][quad * 8];
            al[r] = *(const bf16x8*)&Al[wr * 64 + r * 16 + lrow][quad * 8];
        }
#pragma unroll
        for (int c = 0; c < 4; ++c) {
            bh[c] = *(const bf16x8*)&Bh[wc * 64 + c * 16 + lrow][quad * 8];
            bl[c] = *(const bf16x8*)&Bl[wc * 64 + c * 16 + lrow][quad * 8];
        }
#pragma unroll
        for (int r = 0; r < 4; ++r)
#pragma unroll
            for (int c = 0; c < 4; ++c) {
                acc[r][c] = __builtin_amdgcn_mfma_f32_16x16x32_bf16(ah[r], bh[c], acc[r][c], 0, 0, 0);
                acc[r][c] = __builtin_amdgcn_mfma_f32_16x16x32_bf16(ah[r], bl[c], acc[r][c], 0, 0, 0);
                acc[r][c] = __builtin_amdgcn_mfma_f32_16x16x32_bf16(al[r], bh[c], acc[r][c], 0, 0, 0);
            }
        __syncthreads();
    }
#pragma unroll
    for (int c = 0; c < 4; ++c) {
        int colg = wc * 64 + c * 16 + lrow;
        float bv = (colg < 64) ? bias0[colg] : bias1[colg - 64];
#pragma unroll
        for (int r = 0; r < 4; ++r)
#pragma unroll
            for (int j = 0; j < 4; ++j) {
                long grow = rowbase + wr * 64 + r * 16 + quad * 4 + j;
                if (grow < NN) C[grow * 128 + colg] = acc[r][c][j] + bv;
            }
    }
}

// ================= message kernel: m = relu(y[src] + e@Wme); run-scan aggregate =================
// 64 edges/block, 256 threads, R3-best epilogue. This round: NO B LDS-staging — B fragments
// read directly from global (L2-resident 32KB weight slice). LDS drops 37.4KB -> ~17.4KB,
// lifting the 4-blocks/CU LDS occupancy cap (was pinning occupancy at ~41%).
__global__ __launch_bounds__(256) void k_msg2(
    const u16* __restrict__ eh, const u16* __restrict__ el,
    const int* __restrict__ sp, const int* __restrict__ dp,
    const u16* __restrict__ Bth, const u16* __restrict__ Btl,  // layer Wmt base [128][192]; use k=128..191
    const float* __restrict__ y,
    float* __restrict__ agg)
{
    __shared__ float cbuf[64][66];     // 16896 B
    __shared__ int s_sp[64], s_dp[64];
    const int tid = threadIdx.x;
    const long rowbase = (long)blockIdx.x * 64;
    if (tid < 64) {
        long r = rowbase + tid;
        if (r < NE) { s_sp[tid] = sp[r]; s_dp[tid] = dp[r]; }
        else        { s_sp[tid] = 0;     s_dp[tid] = -1;    }
    }
    const int wave = tid >> 6, lane = tid & 63;
    const int quad = lane >> 4, lrow = lane & 15;
    const int wr = wave >> 1, wc = wave & 1;

    f32x4 acc[2][4];
#pragma unroll
    for (int r = 0; r < 2; ++r)
#pragma unroll
        for (int c = 0; c < 4; ++c) acc[r][c] = (f32x4){0.f, 0.f, 0.f, 0.f};

    // per-lane B base: row (wc*64 + lrow), k offset 128 + quad*8
    const u16* pBh = Bth + (long)(wc * 64 + lrow) * 192 + 128 + quad * 8;
    const u16* pBl = Btl + (long)(wc * 64 + lrow) * 192 + 128 + quad * 8;

#pragma unroll
    for (int kp = 0; kp < 2; ++kp) {
        bf16x8 ah[2], al[2], bh[4], bl[4];
#pragma unroll
        for (int r = 0; r < 2; ++r) {
            long row = rowbase + wr * 32 + r * 16 + lrow; if (row >= NE) row = NE - 1;
            long ba = row * 64 + kp * 32 + quad * 8;
            ah[r] = *(const bf16x8*)(eh + ba);
            al[r] = *(const bf16x8*)(el + ba);
        }
#pragma unroll
        for (int c = 0; c < 4; ++c) {
            bh[c] = *(const bf16x8*)(pBh + (long)c * 16 * 192 + kp * 32);
            bl[c] = *(const bf16x8*)(pBl + (long)c * 16 * 192 + kp * 32);
        }
#pragma unroll
        for (int r = 0; r < 2; ++r)
#pragma unroll
            for (int c = 0; c < 4; ++c) {
                acc[r][c] = __builtin_amdgcn_mfma_f32_16x16x32_bf16(ah[r], bh[c], acc[r][c], 0, 0, 0);
                acc[r][c] = __builtin_amdgcn_mfma_f32_16x16x32_bf16(ah[r], bl[c], acc[r][c], 0, 0, 0);
                acc[r][c] = __builtin_amdgcn_mfma_f32_16x16x32_bf16(al[r], bh[c], acc[r][c], 0, 0, 0);
            }
    }
    // epilogue: add gathered y, relu, run-scan over dst-runs, coalesced atomic flush
    const int col = tid & 63, seg = tid >> 6;
    for (int p = 0; p < 2; ++p) {
        // phase A: raw acc -> cbuf (waves owning these columns)
        if (wc == p) {
#pragma unroll
            for (int c = 0; c < 4; ++c)
#pragma unroll
                for (int r = 0; r < 2; ++r)
#pragma unroll
                    for (int j = 0; j < 4; ++j)
                        cbuf[wr * 32 + r * 16 + quad * 4 + j][c * 16 + lrow] = acc[r][c][j];
        }
        __syncthreads();
        // phase B: vectorized y add + relu; thread t: row=t>>2, 16 contiguous cols
        {
            int row = tid >> 2, q = tid & 3;
            const float* py = y + (long)s_sp[row] * 128 + p * 64 + q * 16;
            float* pc = &cbuf[row][q * 16];
#pragma unroll
            for (int g = 0; g < 4; ++g) {
                float4 yv = *(const float4*)(py + g * 4);
                pc[g * 4 + 0] = relu_f(pc[g * 4 + 0] + yv.x);
                pc[g * 4 + 1] = relu_f(pc[g * 4 + 1] + yv.y);
                pc[g * 4 + 2] = relu_f(pc[g * 4 + 2] + yv.z);
                pc[g * 4 + 3] = relu_f(pc[g * 4 + 3] + yv.w);
            }
        }
        __syncthreads();
        // phase C: run-scan over dst-runs, coalesced atomic flush
        int cur = -1; float sum = 0.0f;
        for (int rr = seg * 16; rr < seg * 16 + 16; ++rr) {
            int d = s_dp[rr];
            if (d != cur) {
                if (cur >= 0) atomicAdd(&agg[(long)cur * 128 + p * 64 + col], sum);
                cur = d; sum = 0.0f;
            }
            sum += cbuf[rr][col];
        }
        if (cur >= 0) atomicAdd(&agg[(long)cur * 128 + p * 64 + col], sum);
        __syncthreads();
    }
}

// ================= node update GEMM (MFMA, split bf16, fused L2-norm) =================
__global__ __launch_bounds__(256) void k_update_mfma(
    const float* __restrict__ agg, const float* __restrict__ icnt,
    u16* __restrict__ xh, u16* __restrict__ xl,
    const u16* __restrict__ Bth, const u16* __restrict__ Btl,   // [128][256]
    const float* __restrict__ bias)
{
    __shared__ u16 Ah[128][40], Al[128][40], Bh[128][40], Bl[128][40];
    __shared__ float s_ic[128];
    __shared__ float sP[128][2];
    const int tid = threadIdx.x;
    const long rowbase = (long)blockIdx.x * 128;
    if (tid < 128) {
        long r = rowbase + tid;
        int rr = (r < NN) ? (int)r : (NN - 1);
        s_ic[tid] = icnt[rr];
    }
    __syncthreads();
    const int wave = tid >> 6, lane = tid & 63;
    const int quad = lane >> 4, lrow = lane & 15;
    const int wr = wave >> 1, wc = wave & 1;
    const int arow = tid >> 1, akh = (tid & 1) << 4;

    f32x4 acc[4][4];
#pragma unroll
    for (int r = 0; r < 4; ++r)
#pragma unroll
        for (int c = 0; c < 4; ++c) acc[r][c] = (f32x4){0.f, 0.f, 0.f, 0.f};

    for (int kp = 0; kp < 8; ++kp) {
        const int k0 = kp * 32;
        if (k0 < 128) {
            long r = rowbase + arow; if (r >= NN) r = NN - 1;
            const float* pa = agg + r * 128 + k0 + akh;
            float ic = s_ic[arow];
#pragma unroll
            for (int q = 0; q < 16; q += 4) {
                float4 f = *(const float4*)(pa + q);
                float vv[4] = {f.x, f.y, f.z, f.w};
#pragma unroll
                for (int j = 0; j < 4; ++j) {
                    float v = vv[j] * ic;
                    u16 h = f2bf(v);
                    Ah[arow][akh + q + j] = h;
                    Al[arow][akh + q + j] = f2bf(v - bf2f(h));
                }
            }
        } else {
            long r = rowbase + arow; if (r >= NN) r = NN - 1;
            long b = r * 128 + (k0 - 128 + akh);
            *(int4*)&Ah[arow][akh]     = *(const int4*)(xh + b);
            *(int4*)&Ah[arow][akh + 8] = *(const int4*)(xh + b + 8);
            *(int4*)&Al[arow][akh]     = *(const int4*)(xl + b);
            *(int4*)&Al[arow][akh + 8] = *(const int4*)(xl + b + 8);
        }
        {
            long b = (long)arow * 256 + k0 + akh;
            *(int4*)&Bh[arow][akh]     = *(const int4*)(Bth + b);
            *(int4*)&Bh[arow][akh + 8] = *(const int4*)(Bth + b + 8);
            *(int4*)&Bl[arow][akh]     = *(const int4*)(Btl + b);
            *(int4*)&Bl[arow][akh + 8] = *(const int4*)(Btl + b + 8);
        }
        __syncthreads();
        bf16x8 ah[4], al[4], bh[4], bl[4];
#pragma unroll
        for (int r = 0; r < 4; ++r) {
            ah[r] = *(const bf16x8*)&Ah[wr * 64 + r * 16 + lrow][quad * 8];
            al[r] = *(const bf16x8*)&Al[wr * 64 + r * 16 + lrow][quad * 8];
        }
#pragma unroll
        for (int c = 0; c < 4; ++c) {
            bh[c] = *(const bf16x8*)&Bh[wc * 64 + c * 16 + lrow][quad * 8];
            bl[c] = *(const bf16x8*)&Bl[wc * 64 + c * 16 + lrow][quad * 8];
        }
#pragma unroll
        for (int r = 0; r < 4; ++r)
#pragma unroll
            for (int c = 0; c < 4; ++c) {
                acc[r][c] = __builtin_amdgcn_mfma_f32_16x16x32_bf16(ah[r], bh[c], acc[r][c], 0, 0, 0);
                acc[r][c] = __builtin_amdgcn_mfma_f32_16x16x32_bf16(ah[r], bl[c], acc[r][c], 0, 0, 0);
                acc[r][c] = __builtin_amdgcn_mfma_f32_16x16x32_bf16(al[r], bh[c], acc[r][c], 0, 0, 0);
            }
        __syncthreads();
    }
#pragma unroll
    for (int r = 0; r < 4; ++r)
#pragma unroll
        for (int c = 0; c < 4; ++c)
#pragma unroll
            for (int j = 0; j < 4; ++j)
                acc[r][c][j] = relu_f(acc[r][c][j] + bias[wc * 64 + c * 16 + lrow]);
#pragma unroll
    for (int r = 0; r < 4; ++r)
#pragma unroll
        for (int j = 0; j < 4; ++j) {
            float s2 = 0.0f;
#pragma unroll
            for (int c = 0; c < 4; ++c) { float v = acc[r][c][j]; s2 += v * v; }
#pragma unroll
            for (int m = 1; m < 16; m <<= 1) s2 += __shfl_xor(s2, m, 64);
            if (lrow == 0) sP[wr * 64 + r * 16 + quad * 4 + j][wc] = s2;
        }
    __syncthreads();
#pragma unroll
    for (int r = 0; r < 4; ++r)
#pragma unroll
        for (int j = 0; j < 4; ++j) {
            int lr = wr * 64 + r * 16 + quad * 4 + j;
            long grow = rowbase + lr;
            if (grow < NN) {
                float tot = sP[lr][0] + sP[lr][1];
                float rn = 1.0f / fmaxf(sqrtf(tot), 1e-12f);
#pragma unroll
                for (int c = 0; c < 4; ++c) {
                    float v = acc[r][c][j] * rn;
                    long o = grow * 128 + wc * 64 + c * 16 + lrow;
                    u16 h = f2bf(v);
                    xh[o] = h;
                    xl[o] = f2bf(v - bf2f(h));
                }
            }
        }
}

// ================= edge update: e' = relu(u1[src] + u2[dst] + e@We3) =================
// edges dst-sorted; A-frags direct global; B (We3, 64x64) LDS-resident.
// Epilogue via LDS transpose: acc -> cbuf, then row-contiguous pass with float4 uu
// gathers and ushort8 (16B) split-plane stores. 4 waves/SIMD.
__global__ __launch_bounds__(256, 4) void k_edge2(
    u16* __restrict__ eh, u16* __restrict__ el,
    const int* __restrict__ sp, const int* __restrict__ dp,
    const u16* __restrict__ Bth, const u16* __restrict__ Btl,  // Wet layer [64][320]; use k=256..319
    const float* __restrict__ uu)                              // [NN][128] = [u1|u2]
{
    __shared__ union {
        struct { u16 Bh[64][72]; u16 Bl[64][72]; } b;   // 18432 B
        float cbuf[128][66];                             // 33792 B
    } u;
    __shared__ int s_sp[128], s_dp[128];
    const int tid = threadIdx.x;
    const long rowbase = (long)blockIdx.x * 128;
    if (tid < 128) {
        long r = rowbase + tid;
        int rr = (r < NE) ? (int)r : (NE - 1);
        s_sp[tid] = sp[rr];
        s_dp[tid] = dp[rr];
    }
    {
        int colb = tid >> 2, kh = (tid & 3) * 16;
        long bb = (long)colb * 320 + 256 + kh;
        *(int4*)&u.b.Bh[colb][kh]     = *(const int4*)(Bth + bb);
        *(int4*)&u.b.Bh[colb][kh + 8] = *(const int4*)(Bth + bb + 8);
        *(int4*)&u.b.Bl[colb][kh]     = *(const int4*)(Btl + bb);
        *(int4*)&u.b.Bl[colb][kh + 8] = *(const int4*)(Btl + bb + 8);
    }
    __syncthreads();
    const int wave = tid >> 6, lane = tid & 63;
    const int quad = lane >> 4, lrow = lane & 15;

    f32x4 acc[2][4];
#pragma unroll
    for (int r = 0; r < 2; ++r)
#pragma unroll
        for (int c = 0; c < 4; ++c) acc[r][c] = (f32x4){0.f, 0.f, 0.f, 0.f};

#pragma unroll
    for (int kp = 0; kp < 2; ++kp) {
        bf16x8 ah[2], al[2], bh[4], bl[4];
#pragma unroll
        for (int r = 0; r < 2; ++r) {
            long row = rowbase + wave * 32 + r * 16 + lrow; if (row >= NE) row = NE - 1;
            long ba = row * 64 + kp * 32 + quad * 8;
            ah[r] = *(const bf16x8*)(eh + ba);
            al[r] = *(const bf16x8*)(el + ba);
        }
#pragma unroll
        for (int c = 0; c < 4; ++c) {
            bh[c] = *(const bf16x8*)&u.b.Bh[c * 16 + lrow][kp * 32 + quad * 8];
            bl[c] = *(const bf16x8*)&u.b.Bl[c * 16 + lrow][kp * 32 + quad * 8];
        }
#pragma unroll
        for (int r = 0; r < 2; ++r)
#pragma unroll
            for (int c = 0; c < 4; ++c) {
                acc[r][c] = __builtin_amdgcn_mfma_f32_16x16x32_bf16(ah[r], bh[c], acc[r][c], 0, 0, 0);
                acc[r][c] = __builtin_amdgcn_mfma_f32_16x16x32_bf16(ah[r], bl[c], acc[r][c], 0, 0, 0);
                acc[r][c] = __builtin_amdgcn_mfma_f32_16x16x32_bf16(al[r], bh[c], acc[r][c], 0, 0, 0);
            }
    }
    __syncthreads();   // all waves done reading B; LDS reusable as cbuf
    // transpose acc -> cbuf
#pragma unroll
    for (int c = 0; c < 4; ++c)
#pragma unroll
        for (int r = 0; r < 2; ++r)
#pragma unroll
            for (int j = 0; j < 4; ++j)
                u.cbuf[wave * 32 + r * 16 + quad * 4 + j][c * 16 + lrow] = acc[r][c][j];
    __syncthreads();
    // vectorized epilogue: thread t owns row t>>1, 32 contiguous cols (half = t&1)
    {
        const int row = tid >> 1, half = tid & 1;
        const long grow = rowbase + row;
        if (grow < NE) {
            const float* pu1 = uu + (long)s_sp[row] * 128 + half * 32;
            const float* pu2 = uu + (long)s_dp[row] * 128 + 64 + half * 32;
            const long o = grow * 64 + half * 32;
#pragma unroll
            for (int g = 0; g < 4; ++g) {
                float4 a0 = *(const float4*)(pu1 + g * 8);
                float4 a1 = *(const float4*)(pu1 + g * 8 + 4);
                float4 b0 = *(const float4*)(pu2 + g * 8);
                float4 b1 = *(const float4*)(pu2 + g * 8 + 4);
                float s[8] = {a0.x + b0.x, a0.y + b0.y, a0.z + b0.z, a0.w + b0.w,
                              a1.x + b1.x, a1.y + b1.y, a1.z + b1.z, a1.w + b1.w};
                u16x8 hv, lv;
#pragma unroll
                for (int k = 0; k < 8; ++k) {
                    float v = relu_f(u.cbuf[row][half * 32 + g * 8 + k] + s[k]);
                    u16 h = f2bf(v);
                    hv[k] = h;
                    lv[k] = f2bf(v - bf2f(h));
                }
                *(u16x8*)(eh + o + g * 8) = hv;
                *(u16x8*)(el + o + g * 8) = lv;
            }
        }
    }
}

// ---------------- MLP head, layer 1: 128 -> 64, relu ----------------
__global__ __launch_bounds__(256) void k_head1(
    const u16* __restrict__ xh, const u16* __restrict__ xl,
    const float* __restrict__ W, const float* __restrict__ bias,
    float* __restrict__ h)
{
    constexpr int KC = 64, NP = 2, EB = 32;
    __shared__ __align__(16) float At[KC][EB + 4];
    __shared__ __align__(16) float Wc[KC][64];
    const int tid = threadIdx.x;
    const int rowbase = blockIdx.x * EB;
    const int wave = tid >> 6, lane = tid & 63;
    float acc[8];
#pragma unroll
    for (int i = 0; i < 8; ++i) acc[i] = 0.0f;

    for (int kp = 0; kp < NP; ++kp) {
        const int k0 = kp * KC;
        for (int i = tid; i < KC * EB; i += 256) {
            int e = i >> 6, kk = i & 63, k = k0 + kk;
            int r = min(rowbase + e, NN - 1);
            long b = (long)r * 128 + k;
            At[kk][e] = bf2f(xh[b]) + bf2f(xl[b]);
        }
        for (int i = tid; i < KC * 64; i += 256) {
            int kk = i >> 6, cc = i & 63;
            Wc[kk][cc] = W[(size_t)(k0 + kk) * 64 + cc];
        }
        __syncthreads();
#pragma unroll 4
        for (int kk = 0; kk < KC; ++kk) {
            const float* ar = &At[kk][wave * 8];
            float4 a0 = *(const float4*)ar;
            float4 a1 = *(const float4*)(ar + 4);
            float wv = Wc[kk][lane];
            acc[0] += a0.x * wv; acc[1] += a0.y * wv; acc[2] += a0.z * wv; acc[3] += a0.w * wv;
            acc[4] += a1.x * wv; acc[5] += a1.y * wv; acc[6] += a1.z * wv; acc[7] += a1.w * wv;
        }
        __syncthreads();
    }
    const float bv = bias[lane];
#pragma unroll
    for (int j = 0; j < 8; ++j) {
        int r = rowbase + wave * 8 + j;
        if (r < NN) h[(size_t)r * 64 + lane] = relu_f(acc[j] + bv);
    }
}

// ---------------- MLP head, layer 2: 64 -> 128, no relu ----------------
__global__ __launch_bounds__(256) void k_head2(
    const float* __restrict__ h, const float* __restrict__ W, const float* __restrict__ bias,
    float* __restrict__ out)
{
    constexpr int KC = 64, EB = 32;
    __shared__ __align__(16) float At[KC][EB + 4];
    __shared__ __align__(16) float Wc[KC][128];
    const int tid = threadIdx.x;
    const int rowbase = blockIdx.x * EB;
    const int wave = tid >> 6, lane = tid & 63;
    float acc[16];
#pragma unroll
    for (int i = 0; i < 16; ++i) acc[i] = 0.0f;

    for (int i = tid; i < KC * EB; i += 256) {
        int e = i >> 6, kk = i & 63;
        int r = min(rowbase + e, NN - 1);
        At[kk][e] = h[(size_t)r * 64 + kk];
    }
    for (int i = tid; i < KC * 128; i += 256) {
        int kk = i >> 7, cc = i & 127;
        Wc[kk][cc] = W[(size_t)kk * 128 + cc];
    }
    __syncthreads();
#pragma unroll 4
    for (int kk = 0; kk < KC; ++kk) {
        const float* ar = &At[kk][wave * 8];
        float4 a0 = *(const float4*)ar;
        float4 a1 = *(const float4*)(ar + 4);
        float w0 = Wc[kk][lane], w1 = Wc[kk][64 + lane];
        acc[0] += a0.x * w0;  acc[1] += a0.y * w0;  acc[2] += a0.z * w0;  acc[3] += a0.w * w0;
        acc[4] += a1.x * w0;  acc[5] += a1.y * w0;  acc[6] += a1.z * w0;  acc[7] += a1.w * w0;
        acc[8] += a0.x * w1;  acc[9] += a0.y * w1;  acc[10] += a0.z * w1; acc[11] += a0.w * w1;
        acc[12] += a1.x * w1; acc[13] += a1.y * w1; acc[14] += a1.z * w1; acc[15] += a1.w * w1;
    }
    const float b0 = bias[lane], b1 = bias[64 + lane];
#pragma unroll
    for (int j = 0; j < 8; ++j) {
        int r = rowbase + wave * 8 + j;
        if (r < NN) {
            out[(size_t)r * 128 + lane] = acc[j] + b0;
            out[(size_t)r * 128 + 64 + lane] = acc[8 + j] + b1;
        }
    }
}

// ---------------- host-side launch ----------------
extern "C" void kernel_launch(void* const* d_in, const int* in_sizes, int n_in,
                              void* d_out, int out_size, void* d_ws, size_t ws_size,
                              hipStream_t stream) {
    const float* d_x  = (const float*)d_in[0];
    const float* d_ea = (const float*)d_in[1];
    const int*   d_ei = (const int*)d_in[2];
    const float* Wm   = (const float*)d_in[3];
    const float* bm   = (const float*)d_in[4];
    const float* Wa   = (const float*)d_in[5];
    const float* ba   = (const float*)d_in[6];
    const float* We   = (const float*)d_in[7];
    const float* be   = (const float*)d_in[8];
    const float* W1   = (const float*)d_in[9];
    const float* b1   = (const float*)d_in[10];
    const float* W2   = (const float*)d_in[11];
    const float* b2   = (const float*)d_in[12];
    float* out = (float*)d_out;

    const int* src = d_ei;
    const int* dst = d_ei + NE;

    char* p = (char*)d_ws;
    auto alloc = [&](size_t bytes) { char* q = p; p += (bytes + 255) & ~(size_t)255; return q; };
    u16* xh  = (u16*)alloc((size_t)NN * 128 * 2);
    u16* xl  = (u16*)alloc((size_t)NN * 128 * 2);
    u16* ehb = (u16*)alloc((size_t)NE * 64 * 2);
    u16* elb = (u16*)alloc((size_t)NE * 64 * 2);
    float* agg = (float*)alloc((size_t)NN * 128 * 4);
    float* yu  = (float*)alloc((size_t)NN * 128 * 4);   // y, then u (disjoint lifetimes)
    float* cnt = (float*)alloc((size_t)NN * 4);
    float* zbuf = (float*)alloc(64 * 4);
    u16* Wmt_h = (u16*)alloc((size_t)3 * 192 * 128 * 2);
    u16* Wmt_l = (u16*)alloc((size_t)3 * 192 * 128 * 2);
    u16* Wat_h = (u16*)alloc((size_t)3 * 256 * 128 * 2);
    u16* Wat_l = (u16*)alloc((size_t)3 * 256 * 128 * 2);
    u16* Wet_h = (u16*)alloc((size_t)3 * 320 * 64 * 2);
    u16* Wet_l = (u16*)alloc((size_t)3 * 320 * 64 * 2);
    u16* Wxt_h = (u16*)alloc((size_t)3 * 128 * 128 * 2);
    u16* Wxt_l = (u16*)alloc((size_t)3 * 128 * 128 * 2);
    int* hist   = (int*)alloc((size_t)NN * 4);
    int* excl   = (int*)alloc((size_t)NN * 4);
    int* bsum   = (int*)alloc(128 * 4);
    int* cursor = (int*)alloc((size_t)NN * 4);
    int* perm   = (int*)alloc((size_t)NE * 4);
    int* sp     = (int*)alloc((size_t)NE * 4);
    int* dp     = (int*)alloc((size_t)NE * 4);
    float* hbuf = yu;   // alias: yu free after last k_edge2

    const int NB1 = (NN + 511) / 512;

    hipMemsetAsync(cnt, 0, NN * sizeof(float), stream);
    hipMemsetAsync(hist, 0, NN * sizeof(int), stream);
    hipMemsetAsync(zbuf, 0, 64 * sizeof(float), stream);
    k_count<<<(NE + 255) / 256, 256, 0, stream>>>(dst, cnt);
    k_invcnt<<<(NN + 255) / 256, 256, 0, stream>>>(cnt);

    // counting sort by dst; physical permutation of edge data
    k_hist<<<(NE + 255) / 256, 256, 0, stream>>>(dst, hist);
    k_scan1<<<NB1, 512, 0, stream>>>(hist, excl, bsum);
    k_scan2<<<1, 128, 0, stream>>>(bsum, NB1);
    k_scan3<<<NB1, 512, 0, stream>>>(excl, bsum, cursor);
    k_scatter<<<(NE + 255) / 256, 256, 0, stream>>>(dst, cursor, perm);
    k_permidx<<<(NE + 255) / 256, 256, 0, stream>>>(src, dst, perm, sp, dp);

    k_split<<<(NN * 128 / 4 + 255) / 256, 256, 0, stream>>>(d_x, xh, xl, NN * 128 / 4);
    k_split_e_perm<<<(NE * 16 + 255) / 256, 256, 0, stream>>>(d_ea, perm, ehb, elb);
    for (int l = 0; l < 3; ++l) {
        k_wt<<<(192 * 128 + 255) / 256, 256, 0, stream>>>(Wm + (size_t)l * 192 * 128,
            Wmt_h + (size_t)l * 192 * 128, Wmt_l + (size_t)l * 192 * 128, 192, 128);
        k_wt<<<(256 * 128 + 255) / 256, 256, 0, stream>>>(Wa + (size_t)l * 256 * 128,
            Wat_h + (size_t)l * 256 * 128, Wat_l + (size_t)l * 256 * 128, 256, 128);
        if (l < 2) {
            // layer-2 edge update is dead (edge_attr unused after last layer)
            k_wt<<<(320 * 64 + 255) / 256, 256, 0, stream>>>(We + (size_t)l * 320 * 64,
                Wet_h + (size_t)l * 320 * 64, Wet_l + (size_t)l * 320 * 64, 320, 64);
            k_wt2<<<(128 * 128 + 255) / 256, 256, 0, stream>>>(We + (size_t)l * 320 * 64,
                Wxt_h + (size_t)l * 128 * 128, Wxt_l + (size_t)l * 128 * 128);
        }
    }

    const int NGB = (NN + 127) / 128;
    for (int l = 0; l < 3; ++l) {
        // y = x @ Wm[0:128] + bm   (node-level hoist of message GEMM)
        k_ngemm<<<NGB, 256, 0, stream>>>(xh, xl,
            Wmt_h + (size_t)l * 192 * 128, Wmt_l + (size_t)l * 192 * 128, 192,
            bm + (size_t)l * 128, bm + (size_t)l * 128 + 64, yu);
        hipMemsetAsync(agg, 0, (size_t)NN * 128 * sizeof(float), stream);
        k_msg2<<<(NE + 63) / 64, 256, 0, stream>>>(
            ehb, elb, sp, dp,
            Wmt_h + (size_t)l * 192 * 128, Wmt_l + (size_t)l * 192 * 128,
            yu, agg);
        k_update_mfma<<<NGB, 256, 0, stream>>>(
            agg, cnt, xh, xl,
            Wat_h + (size_t)l * 256 * 128, Wat_l + (size_t)l * 256 * 128,
            ba + (size_t)l * 128);
        if (l < 2) {
            // u = x_new @ [We1|We2] (+be on u1 half)   (node-level hoist of edge GEMM)
            k_ngemm<<<NGB, 256, 0, stream>>>(xh, xl,
                Wxt_h + (size_t)l * 128 * 128, Wxt_l + (size_t)l * 128 * 128, 128,
                be + (size_t)l * 64, zbuf, yu);
            k_edge2<<<(NE + 127) / 128, 256, 0, stream>>>(
                ehb, elb, sp, dp,
                Wet_h + (size_t)l * 320 * 64, Wet_l + (size_t)l * 320 * 64,
                yu);
        }
    }
    k_head1<<<(NN + 31) / 32, 256, 0, stream>>>(xh, xl, W1, b1, hbuf);
    k_head2<<<(NN + 31) / 32, 256, 0, stream>>>(hbuf, W2, b2, out);
}

// Round 8
// 1039.875 us; speedup vs baseline: 1.0700x; 1.0700x over previous
//
#include <hip/hip_runtime.h>
#include <cstdint>
#include <cstddef>

#define NN 50000
#define NE 500000

typedef unsigned short u16;
typedef __attribute__((ext_vector_type(8))) short bf16x8;
typedef __attribute__((ext_vector_type(4))) float f32x4;
typedef __attribute__((ext_vector_type(4))) unsigned short u16x4;
typedef __attribute__((ext_vector_type(8))) unsigned short u16x8;

__device__ __forceinline__ float relu_f(float v) { return fmaxf(v, 0.0f); }

__device__ __forceinline__ u16 f2bf(float f) {
    union { float f; unsigned u; } c; c.f = f;
    unsigned u = c.u;
    unsigned r = u + 0x7FFFu + ((u >> 16) & 1u);
    return (u16)(r >> 16);
}
__device__ __forceinline__ float bf2f(u16 h) {
    union { unsigned u; float f; } c; c.u = ((unsigned)h) << 16;
    return c.f;
}

// ---------------- degree count + reciprocal ----------------
__global__ __launch_bounds__(256) void k_count(const int* __restrict__ dst, float* __restrict__ cnt) {
    int e = blockIdx.x * 256 + threadIdx.x;
    if (e < NE) atomicAdd(&cnt[dst[e]], 1.0f);
}

__global__ __launch_bounds__(256) void k_invcnt(float* __restrict__ cnt) {
    int i = blockIdx.x * 256 + threadIdx.x;
    if (i < NN) cnt[i] = 1.0f / fmaxf(cnt[i], 1.0f);
}

// ---------------- counting sort of edges by dst ----------------
__global__ __launch_bounds__(256) void k_hist(const int* __restrict__ dst, int* __restrict__ h) {
    int e = blockIdx.x * 256 + threadIdx.x;
    if (e < NE) atomicAdd(&h[dst[e]], 1);
}

__global__ __launch_bounds__(512) void k_scan1(const int* __restrict__ h,
                                               int* __restrict__ excl, int* __restrict__ bsum) {
    __shared__ int s[512];
    int tid = threadIdx.x;
    int i = blockIdx.x * 512 + tid;
    int v = (i < NN) ? h[i] : 0;
    s[tid] = v;
    __syncthreads();
    for (int off = 1; off < 512; off <<= 1) {
        int t = (tid >= off) ? s[tid - off] : 0;
        __syncthreads();
        s[tid] += t;
        __syncthreads();
    }
    if (i < NN) excl[i] = s[tid] - v;
    if (tid == 511) bsum[blockIdx.x] = s[511];
}

__global__ __launch_bounds__(128) void k_scan2(int* __restrict__ bsum, int nb) {
    __shared__ int s[128];
    int tid = threadIdx.x;
    int v = (tid < nb) ? bsum[tid] : 0;
    s[tid] = v;
    __syncthreads();
    for (int off = 1; off < 128; off <<= 1) {
        int t = (tid >= off) ? s[tid - off] : 0;
        __syncthreads();
        s[tid] += t;
        __syncthreads();
    }
    if (tid < nb) bsum[tid] = s[tid] - v;
}

__global__ __launch_bounds__(512) void k_scan3(const int* __restrict__ excl, const int* __restrict__ bsum,
                                               int* __restrict__ cursor) {
    int i = blockIdx.x * 512 + threadIdx.x;
    if (i < NN) cursor[i] = excl[i] + bsum[blockIdx.x];
}

__global__ __launch_bounds__(256) void k_scatter(const int* __restrict__ dst,
                                                 int* __restrict__ cursor, int* __restrict__ perm) {
    int e = blockIdx.x * 256 + threadIdx.x;
    if (e < NE) {
        int pos = atomicAdd(&cursor[dst[e]], 1);
        perm[pos] = e;
    }
}

__global__ __launch_bounds__(256) void k_permidx(const int* __restrict__ src, const int* __restrict__ dst,
                                                 const int* __restrict__ perm,
                                                 int* __restrict__ sp, int* __restrict__ dp) {
    int i = blockIdx.x * 256 + threadIdx.x;
    if (i < NE) {
        int pe = perm[i];
        sp[i] = src[pe];
        dp[i] = dst[pe];
    }
}

// ---------------- fp32 -> split bf16 planes (x4 vectorized) ----------------
__global__ __launch_bounds__(256) void k_split(const float* __restrict__ in,
                                               u16* __restrict__ hi, u16* __restrict__ lo, int n4) {
    int i = blockIdx.x * 256 + threadIdx.x;   // over n/4 quads
    if (i < n4) {
        float4 v = ((const float4*)in)[i];
        float vv[4] = {v.x, v.y, v.z, v.w};
        u16x4 hv, lv;
#pragma unroll
        for (int j = 0; j < 4; ++j) {
            u16 h = f2bf(vv[j]);
            hv[j] = h;
            lv[j] = f2bf(vv[j] - bf2f(h));
        }
        ((u16x4*)hi)[i] = hv;
        ((u16x4*)lo)[i] = lv;
    }
}

// permuted (dst-sorted) split of edge features, x4 vectorized:
// 16 lanes cover one 256B row; float4 gathered read + 2x ushort4 writes per lane
__global__ __launch_bounds__(256) void k_split_e_perm(const float* __restrict__ e,
                                                      const int* __restrict__ perm,
                                                      u16* __restrict__ eh, u16* __restrict__ el) {
    int g = blockIdx.x * 256 + threadIdx.x;  // over NE*16
    int i = g >> 4, c4 = (g & 15) << 2;
    if (i < NE) {
        float4 v = *(const float4*)(e + (long)perm[i] * 64 + c4);
        float vv[4] = {v.x, v.y, v.z, v.w};
        u16x4 hv, lv;
#pragma unroll
        for (int j = 0; j < 4; ++j) {
            u16 h = f2bf(vv[j]);
            hv[j] = h;
            lv[j] = f2bf(vv[j] - bf2f(h));
        }
        long o = (long)i * 64 + c4;
        *(u16x4*)(eh + o) = hv;
        *(u16x4*)(el + o) = lv;
    }
}

// ---------------- W[k][n] -> transposed split planes Wt[n][k] ----------------
__global__ __launch_bounds__(256) void k_wt(const float* __restrict__ W,
                                            u16* __restrict__ th, u16* __restrict__ tl,
                                            int K, int N) {
    int i = blockIdx.x * 256 + threadIdx.x;
    if (i < K * N) {
        int n = i / K, k = i - n * K;
        float v = W[(size_t)k * N + n];
        u16 h = f2bf(v);
        th[i] = h;
        tl[i] = f2bf(v - bf2f(h));
    }
}

// WeX^T: out[j][k] = We[k + (j>=64?128:0)][j&63], j,k in [0,128)
__global__ __launch_bounds__(256) void k_wt2(const float* __restrict__ We,
                                             u16* __restrict__ th, u16* __restrict__ tl) {
    int i = blockIdx.x * 256 + threadIdx.x;
    if (i < 128 * 128) {
        int j = i >> 7, k = i & 127;
        float v = We[(size_t)(k + ((j >> 6) << 7)) * 64 + (j & 63)];
        u16 h = f2bf(v);
        th[i] = h;
        tl[i] = f2bf(v - bf2f(h));
    }
}

// ================= node GEMM: C = x @ B + bias (fp32 out, no relu) =================
// RETILED: 64 rows/block (grid 782 ~ 3 blocks/CU, was 391 = 1.5/CU with 2:1 imbalance).
// 4 waves in 2x2 grid: per-wave 32 rows x 64 cols, acc[2][4]=32 AGPR. LDS ~31KB.
__global__ __launch_bounds__(256) void k_ngemm(
    const u16* __restrict__ xh, const u16* __restrict__ xl,
    const u16* __restrict__ Bth, const u16* __restrict__ Btl, int bstride,
    const float* __restrict__ bias0, const float* __restrict__ bias1,  // cols 0-63 / 64-127
    float* __restrict__ C)
{
    __shared__ u16 Ah[64][40], Al[64][40], Bh[128][40], Bl[128][40];
    const int tid = threadIdx.x;
    const long rowbase = (long)blockIdx.x * 64;
    const int wave = tid >> 6, lane = tid & 63;
    const int quad = lane >> 4, lrow = lane & 15;
    const int wr = wave >> 1, wc = wave & 1;
    const int arow = tid >> 2, akh = (tid & 3) * 8;      // A: 64 rows x 4 chunks of 8
    const int brow = tid >> 1, bkh = (tid & 1) << 4;     // B: 128 rows x 2 chunks of 16

    f32x4 acc[2][4];
#pragma unroll
    for (int r = 0; r < 2; ++r)
#pragma unroll
        for (int c = 0; c < 4; ++c) acc[r][c] = (f32x4){0.f, 0.f, 0.f, 0.f};

    for (int kp = 0; kp < 4; ++kp) {
        const int k0 = kp * 32;
        {
            long r = rowbase + arow; if (r >= NN) r = NN - 1;
            long b = r * 128 + k0 + akh;
            *(int4*)&Ah[arow][akh] = *(const int4*)(xh + b);
            *(int4*)&Al[arow][akh] = *(const int4*)(xl + b);
        }
        {
            long b = (long)brow * bstride + k0 + bkh;
            *(int4*)&Bh[brow][bkh]     = *(const int4*)(Bth + b);
            *(int4*)&Bh[brow][bkh + 8] = *(const int4*)(Bth + b + 8);
            *(int4*)&Bl[brow][bkh]     = *(const int4*)(Btl + b);
            *(int4*)&Bl[brow][bkh + 8] = *(const int4*)(Btl + b + 8);
        }
        __syncthreads();
        bf16x8 ah[2], al[2], bh[4], bl[4];
#pragma unroll
        for (int r = 0; r < 2; ++r) {
            ah[r] = *(const bf16x8*)&Ah[wr * 32 + r * 16 + lrow][quad * 8];
            al[r] = *(const bf16x8*)&Al[wr * 32 + r * 16 + lrow][quad * 8];
        }
#pragma unroll
        for (int c = 0; c < 4; ++c) {
            bh[c] = *(const bf16x8*)&Bh[wc * 64 + c * 16 + lrow][quad * 8];
            bl[c] = *(const bf16x8*)&Bl[wc * 64 + c * 16 + lrow][quad * 8];
        }
#pragma unroll
        for (int r = 0; r < 2; ++r)
#pragma unroll
            for (int c = 0; c < 4; ++c) {
                acc[r][c] = __builtin_amdgcn_mfma_f32_16x16x32_bf16(ah[r], bh[c], acc[r][c], 0, 0, 0);
                acc[r][c] = __builtin_amdgcn_mfma_f32_16x16x32_bf16(ah[r], bl[c], acc[r][c], 0, 0, 0);
                acc[r][c] = __builtin_amdgcn_mfma_f32_16x16x32_bf16(al[r], bh[c], acc[r][c], 0, 0, 0);
            }
        __syncthreads();
    }
#pragma unroll
    for (int c = 0; c < 4; ++c) {
        int colg = wc * 64 + c * 16 + lrow;
        float bv = (colg < 64) ? bias0[colg] : bias1[colg - 64];
#pragma unroll
        for (int r = 0; r < 2; ++r)
#pragma unroll
            for (int j = 0; j < 4; ++j) {
                long grow = rowbase + wr * 32 + r * 16 + quad * 4 + j;
                if (grow < NN) C[grow * 128 + colg] = acc[r][c][j] + bv;
            }
    }
}

// ================= message kernel: m = relu(y[src] + e@Wme); run-scan aggregate =================
// R4 measured-best version (101us): 64 edges/block, 256 threads, B LDS-staged, 3-phase epilogue.
__global__ __launch_bounds__(256, 4) void k_msg2(
    const u16* __restrict__ eh, const u16* __restrict__ el,
    const int* __restrict__ sp, const int* __restrict__ dp,
    const u16* __restrict__ Bth, const u16* __restrict__ Btl,  // layer Wmt base [128][192]; use k=128..191
    const float* __restrict__ y,
    float* __restrict__ agg)
{
    __shared__ union {
        struct { u16 Bh[128][72]; u16 Bl[128][72]; } b;  // 36864 B
        float cbuf[64][66];                               // 16896 B
    } u;
    __shared__ int s_sp[64], s_dp[64];
    const int tid = threadIdx.x;
    const long rowbase = (long)blockIdx.x * 64;
    if (tid < 64) {
        long r = rowbase + tid;
        if (r < NE) { s_sp[tid] = sp[r]; s_dp[tid] = dp[r]; }
        else        { s_sp[tid] = 0;     s_dp[tid] = -1;    }
    }
    // stage B (whole K=64) once
    {
        int colb = tid >> 1, kh = (tid & 1) * 32;
        long bb = (long)colb * 192 + 128 + kh;
#pragma unroll
        for (int q = 0; q < 32; q += 8) {
            *(int4*)&u.b.Bh[colb][kh + q] = *(const int4*)(Bth + bb + q);
            *(int4*)&u.b.Bl[colb][kh + q] = *(const int4*)(Btl + bb + q);
        }
    }
    __syncthreads();
    const int wave = tid >> 6, lane = tid & 63;
    const int quad = lane >> 4, lrow = lane & 15;
    const int wr = wave >> 1, wc = wave & 1;

    f32x4 acc[2][4];
#pragma unroll
    for (int r = 0; r < 2; ++r)
#pragma unroll
        for (int c = 0; c < 4; ++c) acc[r][c] = (f32x4){0.f, 0.f, 0.f, 0.f};

#pragma unroll
    for (int kp = 0; kp < 2; ++kp) {
        bf16x8 ah[2], al[2], bh[4], bl[4];
#pragma unroll
        for (int r = 0; r < 2; ++r) {
            long row = rowbase + wr * 32 + r * 16 + lrow; if (row >= NE) row = NE - 1;
            long ba = row * 64 + kp * 32 + quad * 8;
            ah[r] = *(const bf16x8*)(eh + ba);
            al[r] = *(const bf16x8*)(el + ba);
        }
#pragma unroll
        for (int c = 0; c < 4; ++c) {
            bh[c] = *(const bf16x8*)&u.b.Bh[wc * 64 + c * 16 + lrow][kp * 32 + quad * 8];
            bl[c] = *(const bf16x8*)&u.b.Bl[wc * 64 + c * 16 + lrow][kp * 32 + quad * 8];
        }
#pragma unroll
        for (int r = 0; r < 2; ++r)
#pragma unroll
            for (int c = 0; c < 4; ++c) {
                acc[r][c] = __builtin_amdgcn_mfma_f32_16x16x32_bf16(ah[r], bh[c], acc[r][c], 0, 0, 0);
                acc[r][c] = __builtin_amdgcn_mfma_f32_16x16x32_bf16(ah[r], bl[c], acc[r][c], 0, 0, 0);
                acc[r][c] = __builtin_amdgcn_mfma_f32_16x16x32_bf16(al[r], bh[c], acc[r][c], 0, 0, 0);
            }
    }
    __syncthreads();   // B region now reusable as cbuf
    const int col = tid & 63, seg = tid >> 6;
    for (int p = 0; p < 2; ++p) {
        // phase A: raw acc -> cbuf (waves owning these columns)
        if (wc == p) {
#pragma unroll
            for (int c = 0; c < 4; ++c)
#pragma unroll
                for (int r = 0; r < 2; ++r)
#pragma unroll
                    for (int j = 0; j < 4; ++j)
                        u.cbuf[wr * 32 + r * 16 + quad * 4 + j][c * 16 + lrow] = acc[r][c][j];
        }
        __syncthreads();
        // phase B: vectorized y add + relu; thread t: row=t>>2, 16 contiguous cols
        {
            int row = tid >> 2, q = tid & 3;
            const float* py = y + (long)s_sp[row] * 128 + p * 64 + q * 16;
            float* pc = &u.cbuf[row][q * 16];
#pragma unroll
            for (int g = 0; g < 4; ++g) {
                float4 yv = *(const float4*)(py + g * 4);
                pc[g * 4 + 0] = relu_f(pc[g * 4 + 0] + yv.x);
                pc[g * 4 + 1] = relu_f(pc[g * 4 + 1] + yv.y);
                pc[g * 4 + 2] = relu_f(pc[g * 4 + 2] + yv.z);
                pc[g * 4 + 3] = relu_f(pc[g * 4 + 3] + yv.w);
            }
        }
        __syncthreads();
        // phase C: run-scan over dst-runs, coalesced atomic flush
        int cur = -1; float sum = 0.0f;
        for (int rr = seg * 16; rr < seg * 16 + 16; ++rr) {
            int d = s_dp[rr];
            if (d != cur) {
                if (cur >= 0) atomicAdd(&agg[(long)cur * 128 + p * 64 + col], sum);
                cur = d; sum = 0.0f;
            }
            sum += u.cbuf[rr][col];
        }
        if (cur >= 0) atomicAdd(&agg[(long)cur * 128 + p * 64 + col], sum);
        __syncthreads();
    }
}

// ================= node update GEMM (MFMA, split bf16, fused L2-norm) =================
// RETILED: 64 rows/block (grid 782), per-wave 32x64, acc[2][4]. LDS ~31KB.
__global__ __launch_bounds__(256) void k_update_mfma(
    const float* __restrict__ agg, const float* __restrict__ icnt,
    u16* __restrict__ xh, u16* __restrict__ xl,
    const u16* __restrict__ Bth, const u16* __restrict__ Btl,   // [128][256]
    const float* __restrict__ bias)
{
    __shared__ u16 Ah[64][40], Al[64][40], Bh[128][40], Bl[128][40];
    __shared__ float s_ic[64];
    __shared__ float sP[64][2];
    const int tid = threadIdx.x;
    const long rowbase = (long)blockIdx.x * 64;
    if (tid < 64) {
        long r = rowbase + tid;
        int rr = (r < NN) ? (int)r : (NN - 1);
        s_ic[tid] = icnt[rr];
    }
    __syncthreads();
    const int wave = tid >> 6, lane = tid & 63;
    const int quad = lane >> 4, lrow = lane & 15;
    const int wr = wave >> 1, wc = wave & 1;
    const int arow = tid >> 2, akh = (tid & 3) * 8;      // A: 64 rows x 4 chunks of 8
    const int brow = tid >> 1, bkh = (tid & 1) << 4;     // B: 128 rows x 2 chunks of 16

    f32x4 acc[2][4];
#pragma unroll
    for (int r = 0; r < 2; ++r)
#pragma unroll
        for (int c = 0; c < 4; ++c) acc[r][c] = (f32x4){0.f, 0.f, 0.f, 0.f};

    for (int kp = 0; kp < 8; ++kp) {
        const int k0 = kp * 32;
        if (k0 < 128) {
            long r = rowbase + arow; if (r >= NN) r = NN - 1;
            const float* pa = agg + r * 128 + k0 + akh;
            float ic = s_ic[arow];
#pragma unroll
            for (int q = 0; q < 8; q += 4) {
                float4 f = *(const float4*)(pa + q);
                float vv[4] = {f.x, f.y, f.z, f.w};
#pragma unroll
                for (int j = 0; j < 4; ++j) {
                    float v = vv[j] * ic;
                    u16 h = f2bf(v);
                    Ah[arow][akh + q + j] = h;
                    Al[arow][akh + q + j] = f2bf(v - bf2f(h));
                }
            }
        } else {
            long r = rowbase + arow; if (r >= NN) r = NN - 1;
            long b = r * 128 + (k0 - 128 + akh);
            *(int4*)&Ah[arow][akh] = *(const int4*)(xh + b);
            *(int4*)&Al[arow][akh] = *(const int4*)(xl + b);
        }
        {
            long b = (long)brow * 256 + k0 + bkh;
            *(int4*)&Bh[brow][bkh]     = *(const int4*)(Bth + b);
            *(int4*)&Bh[brow][bkh + 8] = *(const int4*)(Bth + b + 8);
            *(int4*)&Bl[brow][bkh]     = *(const int4*)(Btl + b);
            *(int4*)&Bl[brow][bkh + 8] = *(const int4*)(Btl + b + 8);
        }
        __syncthreads();
        bf16x8 ah[2], al[2], bh[4], bl[4];
#pragma unroll
        for (int r = 0; r < 2; ++r) {
            ah[r] = *(const bf16x8*)&Ah[wr * 32 + r * 16 + lrow][quad * 8];
            al[r] = *(const bf16x8*)&Al[wr * 32 + r * 16 + lrow][quad * 8];
        }
#pragma unroll
        for (int c = 0; c < 4; ++c) {
            bh[c] = *(const bf16x8*)&Bh[wc * 64 + c * 16 + lrow][quad * 8];
            bl[c] = *(const bf16x8*)&Bl[wc * 64 + c * 16 + lrow][quad * 8];
        }
#pragma unroll
        for (int r = 0; r < 2; ++r)
#pragma unroll
            for (int c = 0; c < 4; ++c) {
                acc[r][c] = __builtin_amdgcn_mfma_f32_16x16x32_bf16(ah[r], bh[c], acc[r][c], 0, 0, 0);
                acc[r][c] = __builtin_amdgcn_mfma_f32_16x16x32_bf16(ah[r], bl[c], acc[r][c], 0, 0, 0);
                acc[r][c] = __builtin_amdgcn_mfma_f32_16x16x32_bf16(al[r], bh[c], acc[r][c], 0, 0, 0);
            }
        __syncthreads();
    }
#pragma unroll
    for (int r = 0; r < 2; ++r)
#pragma unroll
        for (int c = 0; c < 4; ++c)
#pragma unroll
            for (int j = 0; j < 4; ++j)
                acc[r][c][j] = relu_f(acc[r][c][j] + bias[wc * 64 + c * 16 + lrow]);
#pragma unroll
    for (int r = 0; r < 2; ++r)
#pragma unroll
        for (int j = 0; j < 4; ++j) {
            float s2 = 0.0f;
#pragma unroll
            for (int c = 0; c < 4; ++c) { float v = acc[r][c][j]; s2 += v * v; }
#pragma unroll
            for (int m = 1; m < 16; m <<= 1) s2 += __shfl_xor(s2, m, 64);
            if (lrow == 0) sP[wr * 32 + r * 16 + quad * 4 + j][wc] = s2;
        }
    __syncthreads();
#pragma unroll
    for (int r = 0; r < 2; ++r)
#pragma unroll
        for (int j = 0; j < 4; ++j) {
            int lr = wr * 32 + r * 16 + quad * 4 + j;
            long grow = rowbase + lr;
            if (grow < NN) {
                float tot = sP[lr][0] + sP[lr][1];
                float rn = 1.0f / fmaxf(sqrtf(tot), 1e-12f);
#pragma unroll
                for (int c = 0; c < 4; ++c) {
                    float v = acc[r][c][j] * rn;
                    long o = grow * 128 + wc * 64 + c * 16 + lrow;
                    u16 h = f2bf(v);
                    xh[o] = h;
                    xl[o] = f2bf(v - bf2f(h));
                }
            }
        }
}

// ================= edge update: e' = relu(u1[src] + u2[dst] + e@We3) =================
// edges dst-sorted; A-frags direct global; B (We3, 64x64) LDS-resident.
// Epilogue via LDS transpose: acc -> cbuf, then row-contiguous pass with float4 uu
// gathers and ushort8 (16B) split-plane stores. 4 waves/SIMD.
__global__ __launch_bounds__(256, 4) void k_edge2(
    u16* __restrict__ eh, u16* __restrict__ el,
    const int* __restrict__ sp, const int* __restrict__ dp,
    const u16* __restrict__ Bth, const u16* __restrict__ Btl,  // Wet layer [64][320]; use k=256..319
    const float* __restrict__ uu)                              // [NN][128] = [u1|u2]
{
    __shared__ union {
        struct { u16 Bh[64][72]; u16 Bl[64][72]; } b;   // 18432 B
        float cbuf[128][66];                             // 33792 B
    } u;
    __shared__ int s_sp[128], s_dp[128];
    const int tid = threadIdx.x;
    const long rowbase = (long)blockIdx.x * 128;
    if (tid < 128) {
        long r = rowbase + tid;
        int rr = (r < NE) ? (int)r : (NE - 1);
        s_sp[tid] = sp[rr];
        s_dp[tid] = dp[rr];
    }
    {
        int colb = tid >> 2, kh = (tid & 3) * 16;
        long bb = (long)colb * 320 + 256 + kh;
        *(int4*)&u.b.Bh[colb][kh]     = *(const int4*)(Bth + bb);
        *(int4*)&u.b.Bh[colb][kh + 8] = *(const int4*)(Bth + bb + 8);
        *(int4*)&u.b.Bl[colb][kh]     = *(const int4*)(Btl + bb);
        *(int4*)&u.b.Bl[colb][kh + 8] = *(const int4*)(Btl + bb + 8);
    }
    __syncthreads();
    const int wave = tid >> 6, lane = tid & 63;
    const int quad = lane >> 4, lrow = lane & 15;

    f32x4 acc[2][4];
#pragma unroll
    for (int r = 0; r < 2; ++r)
#pragma unroll
        for (int c = 0; c < 4; ++c) acc[r][c] = (f32x4){0.f, 0.f, 0.f, 0.f};

#pragma unroll
    for (int kp = 0; kp < 2; ++kp) {
        bf16x8 ah[2], al[2], bh[4], bl[4];
#pragma unroll
        for (int r = 0; r < 2; ++r) {
            long row = rowbase + wave * 32 + r * 16 + lrow; if (row >= NE) row = NE - 1;
            long ba = row * 64 + kp * 32 + quad * 8;
            ah[r] = *(const bf16x8*)(eh + ba);
            al[r] = *(const bf16x8*)(el + ba);
        }
#pragma unroll
        for (int c = 0; c < 4; ++c) {
            bh[c] = *(const bf16x8*)&u.b.Bh[c * 16 + lrow][kp * 32 + quad * 8];
            bl[c] = *(const bf16x8*)&u.b.Bl[c * 16 + lrow][kp * 32 + quad * 8];
        }
#pragma unroll
        for (int r = 0; r < 2; ++r)
#pragma unroll
            for (int c = 0; c < 4; ++c) {
                acc[r][c] = __builtin_amdgcn_mfma_f32_16x16x32_bf16(ah[r], bh[c], acc[r][c], 0, 0, 0);
                acc[r][c] = __builtin_amdgcn_mfma_f32_16x16x32_bf16(ah[r], bl[c], acc[r][c], 0, 0, 0);
                acc[r][c] = __builtin_amdgcn_mfma_f32_16x16x32_bf16(al[r], bh[c], acc[r][c], 0, 0, 0);
            }
    }
    __syncthreads();   // all waves done reading B; LDS reusable as cbuf
    // transpose acc -> cbuf
#pragma unroll
    for (int c = 0; c < 4; ++c)
#pragma unroll
        for (int r = 0; r < 2; ++r)
#pragma unroll
            for (int j = 0; j < 4; ++j)
                u.cbuf[wave * 32 + r * 16 + quad * 4 + j][c * 16 + lrow] = acc[r][c][j];
    __syncthreads();
    // vectorized epilogue: thread t owns row t>>1, 32 contiguous cols (half = t&1)
    {
        const int row = tid >> 1, half = tid & 1;
        const long grow = rowbase + row;
        if (grow < NE) {
            const float* pu1 = uu + (long)s_sp[row] * 128 + half * 32;
            const float* pu2 = uu + (long)s_dp[row] * 128 + 64 + half * 32;
            const long o = grow * 64 + half * 32;
#pragma unroll
            for (int g = 0; g < 4; ++g) {
                float4 a0 = *(const float4*)(pu1 + g * 8);
                float4 a1 = *(const float4*)(pu1 + g * 8 + 4);
                float4 b0 = *(const float4*)(pu2 + g * 8);
                float4 b1 = *(const float4*)(pu2 + g * 8 + 4);
                float s[8] = {a0.x + b0.x, a0.y + b0.y, a0.z + b0.z, a0.w + b0.w,
                              a1.x + b1.x, a1.y + b1.y, a1.z + b1.z, a1.w + b1.w};
                u16x8 hv, lv;
#pragma unroll
                for (int k = 0; k < 8; ++k) {
                    float v = relu_f(u.cbuf[row][half * 32 + g * 8 + k] + s[k]);
                    u16 h = f2bf(v);
                    hv[k] = h;
                    lv[k] = f2bf(v - bf2f(h));
                }
                *(u16x8*)(eh + o + g * 8) = hv;
                *(u16x8*)(el + o + g * 8) = lv;
            }
        }
    }
}

// ---------------- MLP head, layer 1: 128 -> 64, relu ----------------
__global__ __launch_bounds__(256) void k_head1(
    const u16* __restrict__ xh, const u16* __restrict__ xl,
    const float* __restrict__ W, const float* __restrict__ bias,
    float* __restrict__ h)
{
    constexpr int KC = 64, NP = 2, EB = 32;
    __shared__ __align__(16) float At[KC][EB + 4];
    __shared__ __align__(16) float Wc[KC][64];
    const int tid = threadIdx.x;
    const int rowbase = blockIdx.x * EB;
    const int wave = tid >> 6, lane = tid & 63;
    float acc[8];
#pragma unroll
    for (int i = 0; i < 8; ++i) acc[i] = 0.0f;

    for (int kp = 0; kp < NP; ++kp) {
        const int k0 = kp * KC;
        for (int i = tid; i < KC * EB; i += 256) {
            int e = i >> 6, kk = i & 63, k = k0 + kk;
            int r = min(rowbase + e, NN - 1);
            long b = (long)r * 128 + k;
            At[kk][e] = bf2f(xh[b]) + bf2f(xl[b]);
        }
        for (int i = tid; i < KC * 64; i += 256) {
            int kk = i >> 6, cc = i & 63;
            Wc[kk][cc] = W[(size_t)(k0 + kk) * 64 + cc];
        }
        __syncthreads();
#pragma unroll 4
        for (int kk = 0; kk < KC; ++kk) {
            const float* ar = &At[kk][wave * 8];
            float4 a0 = *(const float4*)ar;
            float4 a1 = *(const float4*)(ar + 4);
            float wv = Wc[kk][lane];
            acc[0] += a0.x * wv; acc[1] += a0.y * wv; acc[2] += a0.z * wv; acc[3] += a0.w * wv;
            acc[4] += a1.x * wv; acc[5] += a1.y * wv; acc[6] += a1.z * wv; acc[7] += a1.w * wv;
        }
        __syncthreads();
    }
    const float bv = bias[lane];
#pragma unroll
    for (int j = 0; j < 8; ++j) {
        int r = rowbase + wave * 8 + j;
        if (r < NN) h[(size_t)r * 64 + lane] = relu_f(acc[j] + bv);
    }
}

// ---------------- MLP head, layer 2: 64 -> 128, no relu ----------------
__global__ __launch_bounds__(256) void k_head2(
    const float* __restrict__ h, const float* __restrict__ W, const float* __restrict__ bias,
    float* __restrict__ out)
{
    constexpr int KC = 64, EB = 32;
    __shared__ __align__(16) float At[KC][EB + 4];
    __shared__ __align__(16) float Wc[KC][128];
    const int tid = threadIdx.x;
    const int rowbase = blockIdx.x * EB;
    const int wave = tid >> 6, lane = tid & 63;
    float acc[16];
#pragma unroll
    for (int i = 0; i < 16; ++i) acc[i] = 0.0f;

    for (int i = tid; i < KC * EB; i += 256) {
        int e = i >> 6, kk = i & 63;
        int r = min(rowbase + e, NN - 1);
        At[kk][e] = h[(size_t)r * 64 + kk];
    }
    for (int i = tid; i < KC * 128; i += 256) {
        int kk = i >> 7, cc = i & 127;
        Wc[kk][cc] = W[(size_t)kk * 128 + cc];
    }
    __syncthreads();
#pragma unroll 4
    for (int kk = 0; kk < KC; ++kk) {
        const float* ar = &At[kk][wave * 8];
        float4 a0 = *(const float4*)ar;
        float4 a1 = *(const float4*)(ar + 4);
        float w0 = Wc[kk][lane], w1 = Wc[kk][64 + lane];
        acc[0] += a0.x * w0;  acc[1] += a0.y * w0;  acc[2] += a0.z * w0;  acc[3] += a0.w * w0;
        acc[4] += a1.x * w0;  acc[5] += a1.y * w0;  acc[6] += a1.z * w0;  acc[7] += a1.w * w0;
        acc[8] += a0.x * w1;  acc[9] += a0.y * w1;  acc[10] += a0.z * w1; acc[11] += a0.w * w1;
        acc[12] += a1.x * w1; acc[13] += a1.y * w1; acc[14] += a1.z * w1; acc[15] += a1.w * w1;
    }
    const float b0 = bias[lane], b1 = bias[64 + lane];
#pragma unroll
    for (int j = 0; j < 8; ++j) {
        int r = rowbase + wave * 8 + j;
        if (r < NN) {
            out[(size_t)r * 128 + lane] = acc[j] + b0;
            out[(size_t)r * 128 + 64 + lane] = acc[8 + j] + b1;
        }
    }
}

// ---------------- host-side launch ----------------
extern "C" void kernel_launch(void* const* d_in, const int* in_sizes, int n_in,
                              void* d_out, int out_size, void* d_ws, size_t ws_size,
                              hipStream_t stream) {
    const float* d_x  = (const float*)d_in[0];
    const float* d_ea = (const float*)d_in[1];
    const int*   d_ei = (const int*)d_in[2];
    const float* Wm   = (const float*)d_in[3];
    const float* bm   = (const float*)d_in[4];
    const float* Wa   = (const float*)d_in[5];
    const float* ba   = (const float*)d_in[6];
    const float* We   = (const float*)d_in[7];
    const float* be   = (const float*)d_in[8];
    const float* W1   = (const float*)d_in[9];
    const float* b1   = (const float*)d_in[10];
    const float* W2   = (const float*)d_in[11];
    const float* b2   = (const float*)d_in[12];
    float* out = (float*)d_out;

    const int* src = d_ei;
    const int* dst = d_ei + NE;

    char* p = (char*)d_ws;
    auto alloc = [&](size_t bytes) { char* q = p; p += (bytes + 255) & ~(size_t)255; return q; };
    u16* xh  = (u16*)alloc((size_t)NN * 128 * 2);
    u16* xl  = (u16*)alloc((size_t)NN * 128 * 2);
    u16* ehb = (u16*)alloc((size_t)NE * 64 * 2);
    u16* elb = (u16*)alloc((size_t)NE * 64 * 2);
    float* agg = (float*)alloc((size_t)NN * 128 * 4);
    float* yu  = (float*)alloc((size_t)NN * 128 * 4);   // y, then u (disjoint lifetimes)
    float* cnt = (float*)alloc((size_t)NN * 4);
    float* zbuf = (float*)alloc(64 * 4);
    u16* Wmt_h = (u16*)alloc((size_t)3 * 192 * 128 * 2);
    u16* Wmt_l = (u16*)alloc((size_t)3 * 192 * 128 * 2);
    u16* Wat_h = (u16*)alloc((size_t)3 * 256 * 128 * 2);
    u16* Wat_l = (u16*)alloc((size_t)3 * 256 * 128 * 2);
    u16* Wet_h = (u16*)alloc((size_t)3 * 320 * 64 * 2);
    u16* Wet_l = (u16*)alloc((size_t)3 * 320 * 64 * 2);
    u16* Wxt_h = (u16*)alloc((size_t)3 * 128 * 128 * 2);
    u16* Wxt_l = (u16*)alloc((size_t)3 * 128 * 128 * 2);
    int* hist   = (int*)alloc((size_t)NN * 4);
    int* excl   = (int*)alloc((size_t)NN * 4);
    int* bsum   = (int*)alloc(128 * 4);
    int* cursor = (int*)alloc((size_t)NN * 4);
    int* perm   = (int*)alloc((size_t)NE * 4);
    int* sp     = (int*)alloc((size_t)NE * 4);
    int* dp     = (int*)alloc((size_t)NE * 4);
    float* hbuf = yu;   // alias: yu free after last k_edge2

    const int NB1 = (NN + 511) / 512;

    hipMemsetAsync(cnt, 0, NN * sizeof(float), stream);
    hipMemsetAsync(hist, 0, NN * sizeof(int), stream);
    hipMemsetAsync(zbuf, 0, 64 * sizeof(float), stream);
    k_count<<<(NE + 255) / 256, 256, 0, stream>>>(dst, cnt);
    k_invcnt<<<(NN + 255) / 256, 256, 0, stream>>>(cnt);

    // counting sort by dst; physical permutation of edge data
    k_hist<<<(NE + 255) / 256, 256, 0, stream>>>(dst, hist);
    k_scan1<<<NB1, 512, 0, stream>>>(hist, excl, bsum);
    k_scan2<<<1, 128, 0, stream>>>(bsum, NB1);
    k_scan3<<<NB1, 512, 0, stream>>>(excl, bsum, cursor);
    k_scatter<<<(NE + 255) / 256, 256, 0, stream>>>(dst, cursor, perm);
    k_permidx<<<(NE + 255) / 256, 256, 0, stream>>>(src, dst, perm, sp, dp);

    k_split<<<(NN * 128 / 4 + 255) / 256, 256, 0, stream>>>(d_x, xh, xl, NN * 128 / 4);
    k_split_e_perm<<<(NE * 16 + 255) / 256, 256, 0, stream>>>(d_ea, perm, ehb, elb);
    for (int l = 0; l < 3; ++l) {
        k_wt<<<(192 * 128 + 255) / 256, 256, 0, stream>>>(Wm + (size_t)l * 192 * 128,
            Wmt_h + (size_t)l * 192 * 128, Wmt_l + (size_t)l * 192 * 128, 192, 128);
        k_wt<<<(256 * 128 + 255) / 256, 256, 0, stream>>>(Wa + (size_t)l * 256 * 128,
            Wat_h + (size_t)l * 256 * 128, Wat_l + (size_t)l * 256 * 128, 256, 128);
        if (l < 2) {
            // layer-2 edge update is dead (edge_attr unused after last layer)
            k_wt<<<(320 * 64 + 255) / 256, 256, 0, stream>>>(We + (size_t)l * 320 * 64,
                Wet_h + (size_t)l * 320 * 64, Wet_l + (size_t)l * 320 * 64, 320, 64);
            k_wt2<<<(128 * 128 + 255) / 256, 256, 0, stream>>>(We + (size_t)l * 320 * 64,
                Wxt_h + (size_t)l * 128 * 128, Wxt_l + (size_t)l * 128 * 128);
        }
    }

    const int NGB = (NN + 63) / 64;
    for (int l = 0; l < 3; ++l) {
        // y = x @ Wm[0:128] + bm   (node-level hoist of message GEMM)
        k_ngemm<<<NGB, 256, 0, stream>>>(xh, xl,
            Wmt_h + (size_t)l * 192 * 128, Wmt_l + (size_t)l * 192 * 128, 192,
            bm + (size_t)l * 128, bm + (size_t)l * 128 + 64, yu);
        hipMemsetAsync(agg, 0, (size_t)NN * 128 * sizeof(float), stream);
        k_msg2<<<(NE + 63) / 64, 256, 0, stream>>>(
            ehb, elb, sp, dp,
            Wmt_h + (size_t)l * 192 * 128, Wmt_l + (size_t)l * 192 * 128,
            yu, agg);
        k_update_mfma<<<NGB, 256, 0, stream>>>(
            agg, cnt, xh, xl,
            Wat_h + (size_t)l * 256 * 128, Wat_l + (size_t)l * 256 * 128,
            ba + (size_t)l * 128);
        if (l < 2) {
            // u = x_new @ [We1|We2] (+be on u1 half)   (node-level hoist of edge GEMM)
            k_ngemm<<<NGB, 256, 0, stream>>>(xh, xl,
                Wxt_h + (size_t)l * 128 * 128, Wxt_l + (size_t)l * 128 * 128, 128,
                be + (size_t)l * 64, zbuf, yu);
            k_edge2<<<(NE + 127) / 128, 256, 0, stream>>>(
                ehb, elb, sp, dp,
                Wet_h + (size_t)l * 320 * 64, Wet_l + (size_t)l * 320 * 64,
                yu);
        }
    }
    k_head1<<<(NN + 31) / 32, 256, 0, stream>>>(xh, xl, W1, b1, hbuf);
    k_head2<<<(NN + 31) / 32, 256, 0, stream>>>(hbuf, W2, b2, out);
}

// Round 9
// 974.572 us; speedup vs baseline: 1.1417x; 1.0670x over previous
//
#include <hip/hip_runtime.h>
#include <cstdint>
#include <cstddef>

#define NN 50000
#define NE 500000
#define XQ (NN * 128 / 4)

typedef unsigned short u16;
typedef __attribute__((ext_vector_type(8))) short bf16x8;
typedef __attribute__((ext_vector_type(4))) float f32x4;
typedef __attribute__((ext_vector_type(4))) unsigned short u16x4;
typedef __attribute__((ext_vector_type(8))) unsigned short u16x8;

__device__ __forceinline__ float relu_f(float v) { return fmaxf(v, 0.0f); }

__device__ __forceinline__ u16 f2bf(float f) {
    union { float f; unsigned u; } c; c.f = f;
    unsigned u = c.u;
    unsigned r = u + 0x7FFFu + ((u >> 16) & 1u);
    return (u16)(r >> 16);
}
__device__ __forceinline__ float bf2f(u16 h) {
    union { unsigned u; float f; } c; c.u = ((unsigned)h) << 16;
    return c.f;
}

// ---------------- counting sort of edges by dst ----------------
__global__ __launch_bounds__(256) void k_hist(const int* __restrict__ dst, int* __restrict__ h) {
    int e = blockIdx.x * 256 + threadIdx.x;
    if (e < NE) atomicAdd(&h[dst[e]], 1);
}

// prefix-scan of hist; also emits cnt = 1/max(hist,1) (folds old k_count/k_invcnt)
__global__ __launch_bounds__(512) void k_scan1(const int* __restrict__ h,
                                               int* __restrict__ excl, int* __restrict__ bsum,
                                               float* __restrict__ cnt) {
    __shared__ int s[512];
    int tid = threadIdx.x;
    int i = blockIdx.x * 512 + tid;
    int v = (i < NN) ? h[i] : 0;
    if (i < NN) cnt[i] = 1.0f / fmaxf((float)v, 1.0f);
    s[tid] = v;
    __syncthreads();
    for (int off = 1; off < 512; off <<= 1) {
        int t = (tid >= off) ? s[tid - off] : 0;
        __syncthreads();
        s[tid] += t;
        __syncthreads();
    }
    if (i < NN) excl[i] = s[tid] - v;
    if (tid == 511) bsum[blockIdx.x] = s[511];
}

__global__ __launch_bounds__(128) void k_scan2(int* __restrict__ bsum, int nb) {
    __shared__ int s[128];
    int tid = threadIdx.x;
    int v = (tid < nb) ? bsum[tid] : 0;
    s[tid] = v;
    __syncthreads();
    for (int off = 1; off < 128; off <<= 1) {
        int t = (tid >= off) ? s[tid - off] : 0;
        __syncthreads();
        s[tid] += t;
        __syncthreads();
    }
    if (tid < nb) bsum[tid] = s[tid] - v;
}

__global__ __launch_bounds__(512) void k_scan3(const int* __restrict__ excl, const int* __restrict__ bsum,
                                               int* __restrict__ cursor) {
    int i = blockIdx.x * 512 + threadIdx.x;
    if (i < NN) cursor[i] = excl[i] + bsum[blockIdx.x];
}

__global__ __launch_bounds__(256) void k_scatter(const int* __restrict__ dst,
                                                 int* __restrict__ cursor, int* __restrict__ perm) {
    int e = blockIdx.x * 256 + threadIdx.x;
    if (e < NE) {
        int pos = atomicAdd(&cursor[dst[e]], 1);
        perm[pos] = e;
    }
}

// ---------------- merged split kernel: x-split + permuted e-split + sp/dp ----------------
__global__ __launch_bounds__(256) void k_split_all(
    const float* __restrict__ x, u16* __restrict__ xh, u16* __restrict__ xl,
    const float* __restrict__ e, const int* __restrict__ perm,
    u16* __restrict__ eh, u16* __restrict__ el,
    const int* __restrict__ src, const int* __restrict__ dst,
    int* __restrict__ sp, int* __restrict__ dp)
{
    long t = (long)blockIdx.x * 256 + threadIdx.x;
    if (t < XQ) {
        float4 v = ((const float4*)x)[t];
        float vv[4] = {v.x, v.y, v.z, v.w};
        u16x4 hv, lv;
#pragma unroll
        for (int j = 0; j < 4; ++j) {
            u16 h = f2bf(vv[j]);
            hv[j] = h;
            lv[j] = f2bf(vv[j] - bf2f(h));
        }
        ((u16x4*)xh)[t] = hv;
        ((u16x4*)xl)[t] = lv;
    } else {
        long g = t - XQ;
        int i = (int)(g >> 4), c4 = ((int)g & 15) << 2;
        if (i < NE) {
            int pe = perm[i];
            if ((g & 15) == 0) { sp[i] = src[pe]; dp[i] = dst[pe]; }
            float4 v = *(const float4*)(e + (long)pe * 64 + c4);
            float vv[4] = {v.x, v.y, v.z, v.w};
            u16x4 hv, lv;
#pragma unroll
            for (int j = 0; j < 4; ++j) {
                u16 h = f2bf(vv[j]);
                hv[j] = h;
                lv[j] = f2bf(vv[j] - bf2f(h));
            }
            long o = (long)i * 64 + c4;
            *(u16x4*)(eh + o) = hv;
            *(u16x4*)(el + o) = lv;
        }
    }
}

// ---------------- batched weight transposes (all layers, all W) + zbuf zero ----------------
// sections: Wm^T 3x(K=192,N=128)=73728 | Wa^T 3x(K=256,N=128)=98304 |
//           Wet^T 2x(K=320,N=64)=40960 | Wx^T 2x(128x128)=32768 | zbuf 64
__global__ __launch_bounds__(256) void k_wtall(
    const float* __restrict__ Wm, const float* __restrict__ Wa, const float* __restrict__ We,
    u16* __restrict__ Wmt_h, u16* __restrict__ Wmt_l,
    u16* __restrict__ Wat_h, u16* __restrict__ Wat_l,
    u16* __restrict__ Wet_h, u16* __restrict__ Wet_l,
    u16* __restrict__ Wxt_h, u16* __restrict__ Wxt_l,
    float* __restrict__ zbuf)
{
    int i = blockIdx.x * 256 + threadIdx.x;
    float v; u16* th; u16* tl; int oi;
    if (i < 73728) {
        int l = i / 24576, j = i % 24576;
        int n = j / 192, k = j - n * 192;
        v = Wm[(size_t)l * 24576 + (size_t)k * 128 + n];
        th = Wmt_h; tl = Wmt_l; oi = i;
    } else if ((i -= 73728) < 98304) {
        int l = i / 32768, j = i % 32768;
        int n = j / 256, k = j - n * 256;
        v = Wa[(size_t)l * 32768 + (size_t)k * 128 + n];
        th = Wat_h; tl = Wat_l; oi = i;
    } else if ((i -= 98304) < 40960) {
        int l = i / 20480, j = i % 20480;
        int n = j / 320, k = j - n * 320;
        v = We[(size_t)l * 20480 + (size_t)k * 64 + n];
        th = Wet_h; tl = Wet_l; oi = i;
    } else if ((i -= 40960) < 32768) {
        int l = i / 16384, j2 = i % 16384;
        int jj = j2 >> 7, k = j2 & 127;
        v = We[(size_t)l * 20480 + (size_t)(k + ((jj >> 6) << 7)) * 64 + (jj & 63)];
        th = Wxt_h; tl = Wxt_l; oi = i;
    } else if ((i -= 32768) < 64) {
        zbuf[i] = 0.0f;
        return;
    } else {
        return;
    }
    u16 h = f2bf(v);
    th[oi] = h;
    tl[oi] = f2bf(v - bf2f(h));
}

// ================= node GEMM: C = x @ B + bias (fp32 out, no relu) =================
// 64 rows/block (grid 782 ~ 3 blocks/CU). 4 waves 2x2: per-wave 32x64, acc[2][4].
__global__ __launch_bounds__(256) void k_ngemm(
    const u16* __restrict__ xh, const u16* __restrict__ xl,
    const u16* __restrict__ Bth, const u16* __restrict__ Btl, int bstride,
    const float* __restrict__ bias0, const float* __restrict__ bias1,  // cols 0-63 / 64-127
    float* __restrict__ C)
{
    __shared__ u16 Ah[64][40], Al[64][40], Bh[128][40], Bl[128][40];
    const int tid = threadIdx.x;
    const long rowbase = (long)blockIdx.x * 64;
    const int wave = tid >> 6, lane = tid & 63;
    const int quad = lane >> 4, lrow = lane & 15;
    const int wr = wave >> 1, wc = wave & 1;
    const int arow = tid >> 2, akh = (tid & 3) * 8;
    const int brow = tid >> 1, bkh = (tid & 1) << 4;

    f32x4 acc[2][4];
#pragma unroll
    for (int r = 0; r < 2; ++r)
#pragma unroll
        for (int c = 0; c < 4; ++c) acc[r][c] = (f32x4){0.f, 0.f, 0.f, 0.f};

    for (int kp = 0; kp < 4; ++kp) {
        const int k0 = kp * 32;
        {
            long r = rowbase + arow; if (r >= NN) r = NN - 1;
            long b = r * 128 + k0 + akh;
            *(int4*)&Ah[arow][akh] = *(const int4*)(xh + b);
            *(int4*)&Al[arow][akh] = *(const int4*)(xl + b);
        }
        {
            long b = (long)brow * bstride + k0 + bkh;
            *(int4*)&Bh[brow][bkh]     = *(const int4*)(Bth + b);
            *(int4*)&Bh[brow][bkh + 8] = *(const int4*)(Bth + b + 8);
            *(int4*)&Bl[brow][bkh]     = *(const int4*)(Btl + b);
            *(int4*)&Bl[brow][bkh + 8] = *(const int4*)(Btl + b + 8);
        }
        __syncthreads();
        bf16x8 ah[2], al[2], bh[4], bl[4];
#pragma unroll
        for (int r = 0; r < 2; ++r) {
            ah[r] = *(const bf16x8*)&Ah[wr * 32 + r * 16 + lrow][quad * 8];
            al[r] = *(const bf16x8*)&Al[wr * 32 + r * 16 + lrow][quad * 8];
        }
#pragma unroll
        for (int c = 0; c < 4; ++c) {
            bh[c] = *(const bf16x8*)&Bh[wc * 64 + c * 16 + lrow][quad * 8];
            bl[c] = *(const bf16x8*)&Bl[wc * 64 + c * 16 + lrow][quad * 8];
        }
#pragma unroll
        for (int r = 0; r < 2; ++r)
#pragma unroll
            for (int c = 0; c < 4; ++c) {
                acc[r][c] = __builtin_amdgcn_mfma_f32_16x16x32_bf16(ah[r], bh[c], acc[r][c], 0, 0, 0);
                acc[r][c] = __builtin_amdgcn_mfma_f32_16x16x32_bf16(ah[r], bl[c], acc[r][c], 0, 0, 0);
                acc[r][c] = __builtin_amdgcn_mfma_f32_16x16x32_bf16(al[r], bh[c], acc[r][c], 0, 0, 0);
            }
        __syncthreads();
    }
#pragma unroll
    for (int c = 0; c < 4; ++c) {
        int colg = wc * 64 + c * 16 + lrow;
        float bv = (colg < 64) ? bias0[colg] : bias1[colg - 64];
#pragma unroll
        for (int r = 0; r < 2; ++r)
#pragma unroll
            for (int j = 0; j < 4; ++j) {
                long grow = rowbase + wr * 32 + r * 16 + quad * 4 + j;
                if (grow < NN) C[grow * 128 + colg] = acc[r][c][j] + bv;
            }
    }
}

// ================= message kernel: m = relu(y[src] + e@Wme); run-scan aggregate =================
// R4 measured-best version (101us): 64 edges/block, 256 threads, B LDS-staged, 3-phase epilogue.
__global__ __launch_bounds__(256, 4) void k_msg2(
    const u16* __restrict__ eh, const u16* __restrict__ el,
    const int* __restrict__ sp, const int* __restrict__ dp,
    const u16* __restrict__ Bth, const u16* __restrict__ Btl,  // layer Wmt base [128][192]; use k=128..191
    const float* __restrict__ y,
    float* __restrict__ agg)
{
    __shared__ union {
        struct { u16 Bh[128][72]; u16 Bl[128][72]; } b;  // 36864 B
        float cbuf[64][66];                               // 16896 B
    } u;
    __shared__ int s_sp[64], s_dp[64];
    const int tid = threadIdx.x;
    const long rowbase = (long)blockIdx.x * 64;
    if (tid < 64) {
        long r = rowbase + tid;
        if (r < NE) { s_sp[tid] = sp[r]; s_dp[tid] = dp[r]; }
        else        { s_sp[tid] = 0;     s_dp[tid] = -1;    }
    }
    // stage B (whole K=64) once
    {
        int colb = tid >> 1, kh = (tid & 1) * 32;
        long bb = (long)colb * 192 + 128 + kh;
#pragma unroll
        for (int q = 0; q < 32; q += 8) {
            *(int4*)&u.b.Bh[colb][kh + q] = *(const int4*)(Bth + bb + q);
            *(int4*)&u.b.Bl[colb][kh + q] = *(const int4*)(Btl + bb + q);
        }
    }
    __syncthreads();
    const int wave = tid >> 6, lane = tid & 63;
    const int quad = lane >> 4, lrow = lane & 15;
    const int wr = wave >> 1, wc = wave & 1;

    f32x4 acc[2][4];
#pragma unroll
    for (int r = 0; r < 2; ++r)
#pragma unroll
        for (int c = 0; c < 4; ++c) acc[r][c] = (f32x4){0.f, 0.f, 0.f, 0.f};

#pragma unroll
    for (int kp = 0; kp < 2; ++kp) {
        bf16x8 ah[2], al[2], bh[4], bl[4];
#pragma unroll
        for (int r = 0; r < 2; ++r) {
            long row = rowbase + wr * 32 + r * 16 + lrow; if (row >= NE) row = NE - 1;
            long ba = row * 64 + kp * 32 + quad * 8;
            ah[r] = *(const bf16x8*)(eh + ba);
            al[r] = *(const bf16x8*)(el + ba);
        }
#pragma unroll
        for (int c = 0; c < 4; ++c) {
            bh[c] = *(const bf16x8*)&u.b.Bh[wc * 64 + c * 16 + lrow][kp * 32 + quad * 8];
            bl[c] = *(const bf16x8*)&u.b.Bl[wc * 64 + c * 16 + lrow][kp * 32 + quad * 8];
        }
#pragma unroll
        for (int r = 0; r < 2; ++r)
#pragma unroll
            for (int c = 0; c < 4; ++c) {
                acc[r][c] = __builtin_amdgcn_mfma_f32_16x16x32_bf16(ah[r], bh[c], acc[r][c], 0, 0, 0);
                acc[r][c] = __builtin_amdgcn_mfma_f32_16x16x32_bf16(ah[r], bl[c], acc[r][c], 0, 0, 0);
                acc[r][c] = __builtin_amdgcn_mfma_f32_16x16x32_bf16(al[r], bh[c], acc[r][c], 0, 0, 0);
            }
    }
    __syncthreads();   // B region now reusable as cbuf
    const int col = tid & 63, seg = tid >> 6;
    for (int p = 0; p < 2; ++p) {
        // phase A: raw acc -> cbuf (waves owning these columns)
        if (wc == p) {
#pragma unroll
            for (int c = 0; c < 4; ++c)
#pragma unroll
                for (int r = 0; r < 2; ++r)
#pragma unroll
                    for (int j = 0; j < 4; ++j)
                        u.cbuf[wr * 32 + r * 16 + quad * 4 + j][c * 16 + lrow] = acc[r][c][j];
        }
        __syncthreads();
        // phase B: vectorized y add + relu; thread t: row=t>>2, 16 contiguous cols
        {
            int row = tid >> 2, q = tid & 3;
            const float* py = y + (long)s_sp[row] * 128 + p * 64 + q * 16;
            float* pc = &u.cbuf[row][q * 16];
#pragma unroll
            for (int g = 0; g < 4; ++g) {
                float4 yv = *(const float4*)(py + g * 4);
                pc[g * 4 + 0] = relu_f(pc[g * 4 + 0] + yv.x);
                pc[g * 4 + 1] = relu_f(pc[g * 4 + 1] + yv.y);
                pc[g * 4 + 2] = relu_f(pc[g * 4 + 2] + yv.z);
                pc[g * 4 + 3] = relu_f(pc[g * 4 + 3] + yv.w);
            }
        }
        __syncthreads();
        // phase C: run-scan over dst-runs, coalesced atomic flush
        int cur = -1; float sum = 0.0f;
        for (int rr = seg * 16; rr < seg * 16 + 16; ++rr) {
            int d = s_dp[rr];
            if (d != cur) {
                if (cur >= 0) atomicAdd(&agg[(long)cur * 128 + p * 64 + col], sum);
                cur = d; sum = 0.0f;
            }
            sum += u.cbuf[rr][col];
        }
        if (cur >= 0) atomicAdd(&agg[(long)cur * 128 + p * 64 + col], sum);
        __syncthreads();
    }
}

// ================= node update GEMM (MFMA, split bf16, fused L2-norm) =================
// 64 rows/block (grid 782). If zero_agg, each agg element is zeroed right after its single
// read (saves the separate 25.6MB memset for the next layer's msg2 atomics).
__global__ __launch_bounds__(256) void k_update_mfma(
    float* __restrict__ agg, const float* __restrict__ icnt,
    u16* __restrict__ xh, u16* __restrict__ xl,
    const u16* __restrict__ Bth, const u16* __restrict__ Btl,   // [128][256]
    const float* __restrict__ bias, int zero_agg)
{
    __shared__ u16 Ah[64][40], Al[64][40], Bh[128][40], Bl[128][40];
    __shared__ float s_ic[64];
    __shared__ float sP[64][2];
    const int tid = threadIdx.x;
    const long rowbase = (long)blockIdx.x * 64;
    if (tid < 64) {
        long r = rowbase + tid;
        int rr = (r < NN) ? (int)r : (NN - 1);
        s_ic[tid] = icnt[rr];
    }
    __syncthreads();
    const int wave = tid >> 6, lane = tid & 63;
    const int quad = lane >> 4, lrow = lane & 15;
    const int wr = wave >> 1, wc = wave & 1;
    const int arow = tid >> 2, akh = (tid & 3) * 8;
    const int brow = tid >> 1, bkh = (tid & 1) << 4;

    f32x4 acc[2][4];
#pragma unroll
    for (int r = 0; r < 2; ++r)
#pragma unroll
        for (int c = 0; c < 4; ++c) acc[r][c] = (f32x4){0.f, 0.f, 0.f, 0.f};

    for (int kp = 0; kp < 8; ++kp) {
        const int k0 = kp * 32;
        if (k0 < 128) {
            long r = rowbase + arow;
            const bool own = (r < NN);
            if (!own) r = NN - 1;
            float* pa = agg + r * 128 + k0 + akh;
            float ic = s_ic[arow];
#pragma unroll
            for (int q = 0; q < 8; q += 4) {
                float4 f = *(const float4*)(pa + q);
                float vv[4] = {f.x, f.y, f.z, f.w};
#pragma unroll
                for (int j = 0; j < 4; ++j) {
                    float v = vv[j] * ic;
                    u16 h = f2bf(v);
                    Ah[arow][akh + q + j] = h;
                    Al[arow][akh + q + j] = f2bf(v - bf2f(h));
                }
            }
            if (zero_agg && own) {
                float4 z = {0.f, 0.f, 0.f, 0.f};
                *(float4*)(pa + 0) = z;
                *(float4*)(pa + 4) = z;
            }
        } else {
            long r = rowbase + arow; if (r >= NN) r = NN - 1;
            long b = r * 128 + (k0 - 128 + akh);
            *(int4*)&Ah[arow][akh] = *(const int4*)(xh + b);
            *(int4*)&Al[arow][akh] = *(const int4*)(xl + b);
        }
        {
            long b = (long)brow * 256 + k0 + bkh;
            *(int4*)&Bh[brow][bkh]     = *(const int4*)(Bth + b);
            *(int4*)&Bh[brow][bkh + 8] = *(const int4*)(Bth + b + 8);
            *(int4*)&Bl[brow][bkh]     = *(const int4*)(Btl + b);
            *(int4*)&Bl[brow][bkh + 8] = *(const int4*)(Btl + b + 8);
        }
        __syncthreads();
        bf16x8 ah[2], al[2], bh[4], bl[4];
#pragma unroll
        for (int r = 0; r < 2; ++r) {
            ah[r] = *(const bf16x8*)&Ah[wr * 32 + r * 16 + lrow][quad * 8];
            al[r] = *(const bf16x8*)&Al[wr * 32 + r * 16 + lrow][quad * 8];
        }
#pragma unroll
        for (int c = 0; c < 4; ++c) {
            bh[c] = *(const bf16x8*)&Bh[wc * 64 + c * 16 + lrow][quad * 8];
            bl[c] = *(const bf16x8*)&Bl[wc * 64 + c * 16 + lrow][quad * 8];
        }
#pragma unroll
        for (int r = 0; r < 2; ++r)
#pragma unroll
            for (int c = 0; c < 4; ++c) {
                acc[r][c] = __builtin_amdgcn_mfma_f32_16x16x32_bf16(ah[r], bh[c], acc[r][c], 0, 0, 0);
                acc[r][c] = __builtin_amdgcn_mfma_f32_16x16x32_bf16(ah[r], bl[c], acc[r][c], 0, 0, 0);
                acc[r][c] = __builtin_amdgcn_mfma_f32_16x16x32_bf16(al[r], bh[c], acc[r][c], 0, 0, 0);
            }
        __syncthreads();
    }
#pragma unroll
    for (int r = 0; r < 2; ++r)
#pragma unroll
        for (int c = 0; c < 4; ++c)
#pragma unroll
            for (int j = 0; j < 4; ++j)
                acc[r][c][j] = relu_f(acc[r][c][j] + bias[wc * 64 + c * 16 + lrow]);
#pragma unroll
    for (int r = 0; r < 2; ++r)
#pragma unroll
        for (int j = 0; j < 4; ++j) {
            float s2 = 0.0f;
#pragma unroll
            for (int c = 0; c < 4; ++c) { float v = acc[r][c][j]; s2 += v * v; }
#pragma unroll
            for (int m = 1; m < 16; m <<= 1) s2 += __shfl_xor(s2, m, 64);
            if (lrow == 0) sP[wr * 32 + r * 16 + quad * 4 + j][wc] = s2;
        }
    __syncthreads();
#pragma unroll
    for (int r = 0; r < 2; ++r)
#pragma unroll
        for (int j = 0; j < 4; ++j) {
            int lr = wr * 32 + r * 16 + quad * 4 + j;
            long grow = rowbase + lr;
            if (grow < NN) {
                float tot = sP[lr][0] + sP[lr][1];
                float rn = 1.0f / fmaxf(sqrtf(tot), 1e-12f);
#pragma unroll
                for (int c = 0; c < 4; ++c) {
                    float v = acc[r][c][j] * rn;
                    long o = grow * 128 + wc * 64 + c * 16 + lrow;
                    u16 h = f2bf(v);
                    xh[o] = h;
                    xl[o] = f2bf(v - bf2f(h));
                }
            }
        }
}

// ================= edge update: e' = relu(u1[src] + u2[dst] + e@We3) =================
__global__ __launch_bounds__(256, 4) void k_edge2(
    u16* __restrict__ eh, u16* __restrict__ el,
    const int* __restrict__ sp, const int* __restrict__ dp,
    const u16* __restrict__ Bth, const u16* __restrict__ Btl,  // Wet layer [64][320]; use k=256..319
    const float* __restrict__ uu)                              // [NN][128] = [u1|u2]
{
    __shared__ union {
        struct { u16 Bh[64][72]; u16 Bl[64][72]; } b;   // 18432 B
        float cbuf[128][66];                             // 33792 B
    } u;
    __shared__ int s_sp[128], s_dp[128];
    const int tid = threadIdx.x;
    const long rowbase = (long)blockIdx.x * 128;
    if (tid < 128) {
        long r = rowbase + tid;
        int rr = (r < NE) ? (int)r : (NE - 1);
        s_sp[tid] = sp[rr];
        s_dp[tid] = dp[rr];
    }
    {
        int colb = tid >> 2, kh = (tid & 3) * 16;
        long bb = (long)colb * 320 + 256 + kh;
        *(int4*)&u.b.Bh[colb][kh]     = *(const int4*)(Bth + bb);
        *(int4*)&u.b.Bh[colb][kh + 8] = *(const int4*)(Bth + bb + 8);
        *(int4*)&u.b.Bl[colb][kh]     = *(const int4*)(Btl + bb);
        *(int4*)&u.b.Bl[colb][kh + 8] = *(const int4*)(Btl + bb + 8);
    }
    __syncthreads();
    const int wave = tid >> 6, lane = tid & 63;
    const int quad = lane >> 4, lrow = lane & 15;

    f32x4 acc[2][4];
#pragma unroll
    for (int r = 0; r < 2; ++r)
#pragma unroll
        for (int c = 0; c < 4; ++c) acc[r][c] = (f32x4){0.f, 0.f, 0.f, 0.f};

#pragma unroll
    for (int kp = 0; kp < 2; ++kp) {
        bf16x8 ah[2], al[2], bh[4], bl[4];
#pragma unroll
        for (int r = 0; r < 2; ++r) {
            long row = rowbase + wave * 32 + r * 16 + lrow; if (row >= NE) row = NE - 1;
            long ba = row * 64 + kp * 32 + quad * 8;
            ah[r] = *(const bf16x8*)(eh + ba);
            al[r] = *(const bf16x8*)(el + ba);
        }
#pragma unroll
        for (int c = 0; c < 4; ++c) {
            bh[c] = *(const bf16x8*)&u.b.Bh[c * 16 + lrow][kp * 32 + quad * 8];
            bl[c] = *(const bf16x8*)&u.b.Bl[c * 16 + lrow][kp * 32 + quad * 8];
        }
#pragma unroll
        for (int r = 0; r < 2; ++r)
#pragma unroll
            for (int c = 0; c < 4; ++c) {
                acc[r][c] = __builtin_amdgcn_mfma_f32_16x16x32_bf16(ah[r], bh[c], acc[r][c], 0, 0, 0);
                acc[r][c] = __builtin_amdgcn_mfma_f32_16x16x32_bf16(ah[r], bl[c], acc[r][c], 0, 0, 0);
                acc[r][c] = __builtin_amdgcn_mfma_f32_16x16x32_bf16(al[r], bh[c], acc[r][c], 0, 0, 0);
            }
    }
    __syncthreads();   // all waves done reading B; LDS reusable as cbuf
    // transpose acc -> cbuf
#pragma unroll
    for (int c = 0; c < 4; ++c)
#pragma unroll
        for (int r = 0; r < 2; ++r)
#pragma unroll
            for (int j = 0; j < 4; ++j)
                u.cbuf[wave * 32 + r * 16 + quad * 4 + j][c * 16 + lrow] = acc[r][c][j];
    __syncthreads();
    // vectorized epilogue: thread t owns row t>>1, 32 contiguous cols (half = t&1)
    {
        const int row = tid >> 1, half = tid & 1;
        const long grow = rowbase + row;
        if (grow < NE) {
            const float* pu1 = uu + (long)s_sp[row] * 128 + half * 32;
            const float* pu2 = uu + (long)s_dp[row] * 128 + 64 + half * 32;
            const long o = grow * 64 + half * 32;
#pragma unroll
            for (int g = 0; g < 4; ++g) {
                float4 a0 = *(const float4*)(pu1 + g * 8);
                float4 a1 = *(const float4*)(pu1 + g * 8 + 4);
                float4 b0 = *(const float4*)(pu2 + g * 8);
                float4 b1 = *(const float4*)(pu2 + g * 8 + 4);
                float s[8] = {a0.x + b0.x, a0.y + b0.y, a0.z + b0.z, a0.w + b0.w,
                              a1.x + b1.x, a1.y + b1.y, a1.z + b1.z, a1.w + b1.w};
                u16x8 hv, lv;
#pragma unroll
                for (int k = 0; k < 8; ++k) {
                    float v = relu_f(u.cbuf[row][half * 32 + g * 8 + k] + s[k]);
                    u16 h = f2bf(v);
                    hv[k] = h;
                    lv[k] = f2bf(v - bf2f(h));
                }
                *(u16x8*)(eh + o + g * 8) = hv;
                *(u16x8*)(el + o + g * 8) = lv;
            }
        }
    }
}

// ---------------- fused MLP head: out = relu(x@W1+b1)@W2+b2 ----------------
// stage1 identical to old k_head1; h kept in LDS (At reused); stage2 = old k_head2 from LDS.
__global__ __launch_bounds__(256) void k_head(
    const u16* __restrict__ xh, const u16* __restrict__ xl,
    const float* __restrict__ W1, const float* __restrict__ b1,
    const float* __restrict__ W2, const float* __restrict__ b2,
    float* __restrict__ out)
{
    constexpr int KC = 64, NP = 2, EB = 32;
    __shared__ __align__(16) float At[KC][EB + 4];
    __shared__ __align__(16) union { float W1s[KC][64]; float W2s[KC][128]; } w;
    const int tid = threadIdx.x;
    const int rowbase = blockIdx.x * EB;
    const int wave = tid >> 6, lane = tid & 63;
    float acc[8];
#pragma unroll
    for (int i = 0; i < 8; ++i) acc[i] = 0.0f;

    for (int kp = 0; kp < NP; ++kp) {
        const int k0 = kp * KC;
        for (int i = tid; i < KC * EB; i += 256) {
            int e = i >> 6, kk = i & 63, k = k0 + kk;
            int r = min(rowbase + e, NN - 1);
            long b = (long)r * 128 + k;
            At[kk][e] = bf2f(xh[b]) + bf2f(xl[b]);
        }
        for (int i = tid; i < KC * 64; i += 256) {
            int kk = i >> 6, cc = i & 63;
            w.W1s[kk][cc] = W1[(size_t)(k0 + kk) * 64 + cc];
        }
        __syncthreads();
#pragma unroll 4
        for (int kk = 0; kk < KC; ++kk) {
            const float* ar = &At[kk][wave * 8];
            float4 a0 = *(const float4*)ar;
            float4 a1 = *(const float4*)(ar + 4);
            float wv = w.W1s[kk][lane];
            acc[0] += a0.x * wv; acc[1] += a0.y * wv; acc[2] += a0.z * wv; acc[3] += a0.w * wv;
            acc[4] += a1.x * wv; acc[5] += a1.y * wv; acc[6] += a1.z * wv; acc[7] += a1.w * wv;
        }
        __syncthreads();
    }
    // h -> At (overwrite; protected by the loop-final barrier). At[kk=lane][e=wave*8+j]
    {
        const float bv = b1[lane];
#pragma unroll
        for (int j = 0; j < 8; ++j)
            At[lane][wave * 8 + j] = relu_f(acc[j] + bv);
    }
    // stage W2 (overwrites W1s region — all reads done)
    for (int i = tid; i < KC * 128; i += 256) {
        int kk = i >> 7, cc = i & 127;
        w.W2s[kk][cc] = W2[(size_t)kk * 128 + cc];
    }
    __syncthreads();
    float a2[16];
#pragma unroll
    for (int i = 0; i < 16; ++i) a2[i] = 0.0f;
#pragma unroll 4
    for (int kk = 0; kk < KC; ++kk) {
        const float* ar = &At[kk][wave * 8];
        float4 a0 = *(const float4*)ar;
        float4 a1 = *(const float4*)(ar + 4);
        float w0 = w.W2s[kk][lane], w1 = w.W2s[kk][64 + lane];
        a2[0] += a0.x * w0;  a2[1] += a0.y * w0;  a2[2] += a0.z * w0;  a2[3] += a0.w * w0;
        a2[4] += a1.x * w0;  a2[5] += a1.y * w0;  a2[6] += a1.z * w0;  a2[7] += a1.w * w0;
        a2[8] += a0.x * w1;  a2[9] += a0.y * w1;  a2[10] += a0.z * w1; a2[11] += a0.w * w1;
        a2[12] += a1.x * w1; a2[13] += a1.y * w1; a2[14] += a1.z * w1; a2[15] += a1.w * w1;
    }
    const float o0 = b2[lane], o1 = b2[64 + lane];
#pragma unroll
    for (int j = 0; j < 8; ++j) {
        int r = rowbase + wave * 8 + j;
        if (r < NN) {
            out[(size_t)r * 128 + lane] = a2[j] + o0;
            out[(size_t)r * 128 + 64 + lane] = a2[8 + j] + o1;
        }
    }
}

// ---------------- host-side launch ----------------
extern "C" void kernel_launch(void* const* d_in, const int* in_sizes, int n_in,
                              void* d_out, int out_size, void* d_ws, size_t ws_size,
                              hipStream_t stream) {
    const float* d_x  = (const float*)d_in[0];
    const float* d_ea = (const float*)d_in[1];
    const int*   d_ei = (const int*)d_in[2];
    const float* Wm   = (const float*)d_in[3];
    const float* bm   = (const float*)d_in[4];
    const float* Wa   = (const float*)d_in[5];
    const float* ba   = (const float*)d_in[6];
    const float* We   = (const float*)d_in[7];
    const float* be   = (const float*)d_in[8];
    const float* W1   = (const float*)d_in[9];
    const float* b1   = (const float*)d_in[10];
    const float* W2   = (const float*)d_in[11];
    const float* b2   = (const float*)d_in[12];
    float* out = (float*)d_out;

    const int* src = d_ei;
    const int* dst = d_ei + NE;

    char* p = (char*)d_ws;
    auto alloc = [&](size_t bytes) { char* q = p; p += (bytes + 255) & ~(size_t)255; return q; };
    u16* xh  = (u16*)alloc((size_t)NN * 128 * 2);
    u16* xl  = (u16*)alloc((size_t)NN * 128 * 2);
    u16* ehb = (u16*)alloc((size_t)NE * 64 * 2);
    u16* elb = (u16*)alloc((size_t)NE * 64 * 2);
    float* agg = (float*)alloc((size_t)NN * 128 * 4);
    float* yu  = (float*)alloc((size_t)NN * 128 * 4);   // y, then u (disjoint lifetimes)
    float* cnt = (float*)alloc((size_t)NN * 4);
    float* zbuf = (float*)alloc(64 * 4);
    u16* Wmt_h = (u16*)alloc((size_t)3 * 192 * 128 * 2);
    u16* Wmt_l = (u16*)alloc((size_t)3 * 192 * 128 * 2);
    u16* Wat_h = (u16*)alloc((size_t)3 * 256 * 128 * 2);
    u16* Wat_l = (u16*)alloc((size_t)3 * 256 * 128 * 2);
    u16* Wet_h = (u16*)alloc((size_t)3 * 320 * 64 * 2);
    u16* Wet_l = (u16*)alloc((size_t)3 * 320 * 64 * 2);
    u16* Wxt_h = (u16*)alloc((size_t)3 * 128 * 128 * 2);
    u16* Wxt_l = (u16*)alloc((size_t)3 * 128 * 128 * 2);
    int* hist   = (int*)alloc((size_t)NN * 4);
    int* excl   = (int*)alloc((size_t)NN * 4);
    int* bsum   = (int*)alloc(128 * 4);
    int* cursor = (int*)alloc((size_t)NN * 4);
    int* perm   = (int*)alloc((size_t)NE * 4);
    int* sp     = (int*)alloc((size_t)NE * 4);
    int* dp     = (int*)alloc((size_t)NE * 4);

    const int NB1 = (NN + 511) / 512;

    hipMemsetAsync(hist, 0, NN * sizeof(int), stream);
    // counting sort by dst + degree reciprocal (folded into scan1)
    k_hist<<<(NE + 255) / 256, 256, 0, stream>>>(dst, hist);
    k_scan1<<<NB1, 512, 0, stream>>>(hist, excl, bsum, cnt);
    k_scan2<<<1, 128, 0, stream>>>(bsum, NB1);
    k_scan3<<<NB1, 512, 0, stream>>>(excl, bsum, cursor);
    k_scatter<<<(NE + 255) / 256, 256, 0, stream>>>(dst, cursor, perm);

    // merged splits (x planes + permuted e planes + sp/dp)
    k_split_all<<<(XQ + NE * 16 + 255) / 256, 256, 0, stream>>>(
        d_x, xh, xl, d_ea, perm, ehb, elb, src, dst, sp, dp);
    // all weight transposes + zbuf zero, one launch
    k_wtall<<<(245824 + 255) / 256, 256, 0, stream>>>(
        Wm, Wa, We, Wmt_h, Wmt_l, Wat_h, Wat_l, Wet_h, Wet_l, Wxt_h, Wxt_l, zbuf);

    hipMemsetAsync(agg, 0, (size_t)NN * 128 * sizeof(float), stream);   // layer-0 only

    const int NGB = (NN + 63) / 64;
    for (int l = 0; l < 3; ++l) {
        // y = x @ Wm[0:128] + bm   (node-level hoist of message GEMM)
        k_ngemm<<<NGB, 256, 0, stream>>>(xh, xl,
            Wmt_h + (size_t)l * 192 * 128, Wmt_l + (size_t)l * 192 * 128, 192,
            bm + (size_t)l * 128, bm + (size_t)l * 128 + 64, yu);
        k_msg2<<<(NE + 63) / 64, 256, 0, stream>>>(
            ehb, elb, sp, dp,
            Wmt_h + (size_t)l * 192 * 128, Wmt_l + (size_t)l * 192 * 128,
            yu, agg);
        // update; zeroes agg in-pass for next layer's msg2 (skip on last layer)
        k_update_mfma<<<NGB, 256, 0, stream>>>(
            agg, cnt, xh, xl,
            Wat_h + (size_t)l * 256 * 128, Wat_l + (size_t)l * 256 * 128,
            ba + (size_t)l * 128, (l < 2) ? 1 : 0);
        if (l < 2) {
            // u = x_new @ [We1|We2] (+be on u1 half)   (node-level hoist of edge GEMM)
            k_ngemm<<<NGB, 256, 0, stream>>>(xh, xl,
                Wxt_h + (size_t)l * 128 * 128, Wxt_l + (size_t)l * 128 * 128, 128,
                be + (size_t)l * 64, zbuf, yu);
            k_edge2<<<(NE + 127) / 128, 256, 0, stream>>>(
                ehb, elb, sp, dp,
                Wet_h + (size_t)l * 320 * 64, Wet_l + (size_t)l * 320 * 64,
                yu);
        }
    }
    k_head<<<(NN + 31) / 32, 256, 0, stream>>>(xh, xl, W1, b1, W2, b2, out);
}

// Round 10
// 955.357 us; speedup vs baseline: 1.1646x; 1.0201x over previous
//
#include <hip/hip_runtime.h>
#include <cstdint>
#include <cstddef>

#define NN 50000
#define NE 500000
#define XQ (NN * 128 / 4)

typedef unsigned short u16;
typedef __attribute__((ext_vector_type(8))) short bf16x8;
typedef __attribute__((ext_vector_type(4))) float f32x4;
typedef __attribute__((ext_vector_type(4))) unsigned short u16x4;
typedef __attribute__((ext_vector_type(8))) unsigned short u16x8;

__device__ __forceinline__ float relu_f(float v) { return fmaxf(v, 0.0f); }

__device__ __forceinline__ u16 f2bf(float f) {
    union { float f; unsigned u; } c; c.f = f;
    unsigned u = c.u;
    unsigned r = u + 0x7FFFu + ((u >> 16) & 1u);
    return (u16)(r >> 16);
}
__device__ __forceinline__ float bf2f(u16 h) {
    union { unsigned u; float f; } c; c.u = ((unsigned)h) << 16;
    return c.f;
}

// ---------------- counting sort of edges by dst ----------------
__global__ __launch_bounds__(256) void k_hist(const int* __restrict__ dst, int* __restrict__ h) {
    int e = blockIdx.x * 256 + threadIdx.x;
    if (e < NE) atomicAdd(&h[dst[e]], 1);
}

// prefix-scan of hist; also emits cnt = 1/max(hist,1)
__global__ __launch_bounds__(512) void k_scan1(const int* __restrict__ h,
                                               int* __restrict__ excl, int* __restrict__ bsum,
                                               float* __restrict__ cnt) {
    __shared__ int s[512];
    int tid = threadIdx.x;
    int i = blockIdx.x * 512 + tid;
    int v = (i < NN) ? h[i] : 0;
    if (i < NN) cnt[i] = 1.0f / fmaxf((float)v, 1.0f);
    s[tid] = v;
    __syncthreads();
    for (int off = 1; off < 512; off <<= 1) {
        int t = (tid >= off) ? s[tid - off] : 0;
        __syncthreads();
        s[tid] += t;
        __syncthreads();
    }
    if (i < NN) excl[i] = s[tid] - v;
    if (tid == 511) bsum[blockIdx.x] = s[511];
}

__global__ __launch_bounds__(128) void k_scan2(int* __restrict__ bsum, int nb) {
    __shared__ int s[128];
    int tid = threadIdx.x;
    int v = (tid < nb) ? bsum[tid] : 0;
    s[tid] = v;
    __syncthreads();
    for (int off = 1; off < 128; off <<= 1) {
        int t = (tid >= off) ? s[tid - off] : 0;
        __syncthreads();
        s[tid] += t;
        __syncthreads();
    }
    if (tid < nb) bsum[tid] = s[tid] - v;
}

__global__ __launch_bounds__(512) void k_scan3(const int* __restrict__ excl, const int* __restrict__ bsum,
                                               int* __restrict__ cursor) {
    int i = blockIdx.x * 512 + threadIdx.x;
    if (i < NN) cursor[i] = excl[i] + bsum[blockIdx.x];
}

__global__ __launch_bounds__(256) void k_scatter(const int* __restrict__ dst,
                                                 int* __restrict__ cursor, int* __restrict__ perm) {
    int e = blockIdx.x * 256 + threadIdx.x;
    if (e < NE) {
        int pos = atomicAdd(&cursor[dst[e]], 1);
        perm[pos] = e;
    }
}

// ---------------- merged split kernel: x-split + permuted e-split + sp/dp ----------------
__global__ __launch_bounds__(256) void k_split_all(
    const float* __restrict__ x, u16* __restrict__ xh, u16* __restrict__ xl,
    const float* __restrict__ e, const int* __restrict__ perm,
    u16* __restrict__ eh, u16* __restrict__ el,
    const int* __restrict__ src, const int* __restrict__ dst,
    int* __restrict__ sp, int* __restrict__ dp)
{
    long t = (long)blockIdx.x * 256 + threadIdx.x;
    if (t < XQ) {
        float4 v = ((const float4*)x)[t];
        float vv[4] = {v.x, v.y, v.z, v.w};
        u16x4 hv, lv;
#pragma unroll
        for (int j = 0; j < 4; ++j) {
            u16 h = f2bf(vv[j]);
            hv[j] = h;
            lv[j] = f2bf(vv[j] - bf2f(h));
        }
        ((u16x4*)xh)[t] = hv;
        ((u16x4*)xl)[t] = lv;
    } else {
        long g = t - XQ;
        int i = (int)(g >> 4), c4 = ((int)g & 15) << 2;
        if (i < NE) {
            int pe = perm[i];
            if ((g & 15) == 0) { sp[i] = src[pe]; dp[i] = dst[pe]; }
            float4 v = *(const float4*)(e + (long)pe * 64 + c4);
            float vv[4] = {v.x, v.y, v.z, v.w};
            u16x4 hv, lv;
#pragma unroll
            for (int j = 0; j < 4; ++j) {
                u16 h = f2bf(vv[j]);
                hv[j] = h;
                lv[j] = f2bf(vv[j] - bf2f(h));
            }
            long o = (long)i * 64 + c4;
            *(u16x4*)(eh + o) = hv;
            *(u16x4*)(el + o) = lv;
        }
    }
}

// ---------------- batched weight transposes (all layers, all W) + zbuf zero ----------------
__global__ __launch_bounds__(256) void k_wtall(
    const float* __restrict__ Wm, const float* __restrict__ Wa, const float* __restrict__ We,
    u16* __restrict__ Wmt_h, u16* __restrict__ Wmt_l,
    u16* __restrict__ Wat_h, u16* __restrict__ Wat_l,
    u16* __restrict__ Wet_h, u16* __restrict__ Wet_l,
    u16* __restrict__ Wxt_h, u16* __restrict__ Wxt_l,
    float* __restrict__ zbuf)
{
    int i = blockIdx.x * 256 + threadIdx.x;
    float v; u16* th; u16* tl; int oi;
    if (i < 73728) {
        int l = i / 24576, j = i % 24576;
        int n = j / 192, k = j - n * 192;
        v = Wm[(size_t)l * 24576 + (size_t)k * 128 + n];
        th = Wmt_h; tl = Wmt_l; oi = i;
    } else if ((i -= 73728) < 98304) {
        int l = i / 32768, j = i % 32768;
        int n = j / 256, k = j - n * 256;
        v = Wa[(size_t)l * 32768 + (size_t)k * 128 + n];
        th = Wat_h; tl = Wat_l; oi = i;
    } else if ((i -= 98304) < 40960) {
        int l = i / 20480, j = i % 20480;
        int n = j / 320, k = j - n * 320;
        v = We[(size_t)l * 20480 + (size_t)k * 64 + n];
        th = Wet_h; tl = Wet_l; oi = i;
    } else if ((i -= 40960) < 32768) {
        int l = i / 16384, j2 = i % 16384;
        int jj = j2 >> 7, k = j2 & 127;
        v = We[(size_t)l * 20480 + (size_t)(k + ((jj >> 6) << 7)) * 64 + (jj & 63)];
        th = Wxt_h; tl = Wxt_l; oi = i;
    } else if ((i -= 32768) < 64) {
        zbuf[i] = 0.0f;
        return;
    } else {
        return;
    }
    u16 h = f2bf(v);
    th[oi] = h;
    tl[oi] = f2bf(v - bf2f(h));
}

// ================= node GEMM: C = x @ B + bias (fp32 out, no relu) =================
__global__ __launch_bounds__(256) void k_ngemm(
    const u16* __restrict__ xh, const u16* __restrict__ xl,
    const u16* __restrict__ Bth, const u16* __restrict__ Btl, int bstride,
    const float* __restrict__ bias0, const float* __restrict__ bias1,
    float* __restrict__ C)
{
    __shared__ u16 Ah[64][40], Al[64][40], Bh[128][40], Bl[128][40];
    const int tid = threadIdx.x;
    const long rowbase = (long)blockIdx.x * 64;
    const int wave = tid >> 6, lane = tid & 63;
    const int quad = lane >> 4, lrow = lane & 15;
    const int wr = wave >> 1, wc = wave & 1;
    const int arow = tid >> 2, akh = (tid & 3) * 8;
    const int brow = tid >> 1, bkh = (tid & 1) << 4;

    f32x4 acc[2][4];
#pragma unroll
    for (int r = 0; r < 2; ++r)
#pragma unroll
        for (int c = 0; c < 4; ++c) acc[r][c] = (f32x4){0.f, 0.f, 0.f, 0.f};

    for (int kp = 0; kp < 4; ++kp) {
        const int k0 = kp * 32;
        {
            long r = rowbase + arow; if (r >= NN) r = NN - 1;
            long b = r * 128 + k0 + akh;
            *(int4*)&Ah[arow][akh] = *(const int4*)(xh + b);
            *(int4*)&Al[arow][akh] = *(const int4*)(xl + b);
        }
        {
            long b = (long)brow * bstride + k0 + bkh;
            *(int4*)&Bh[brow][bkh]     = *(const int4*)(Bth + b);
            *(int4*)&Bh[brow][bkh + 8] = *(const int4*)(Bth + b + 8);
            *(int4*)&Bl[brow][bkh]     = *(const int4*)(Btl + b);
            *(int4*)&Bl[brow][bkh + 8] = *(const int4*)(Btl + b + 8);
        }
        __syncthreads();
        bf16x8 ah[2], al[2], bh[4], bl[4];
#pragma unroll
        for (int r = 0; r < 2; ++r) {
            ah[r] = *(const bf16x8*)&Ah[wr * 32 + r * 16 + lrow][quad * 8];
            al[r] = *(const bf16x8*)&Al[wr * 32 + r * 16 + lrow][quad * 8];
        }
#pragma unroll
        for (int c = 0; c < 4; ++c) {
            bh[c] = *(const bf16x8*)&Bh[wc * 64 + c * 16 + lrow][quad * 8];
            bl[c] = *(const bf16x8*)&Bl[wc * 64 + c * 16 + lrow][quad * 8];
        }
#pragma unroll
        for (int r = 0; r < 2; ++r)
#pragma unroll
            for (int c = 0; c < 4; ++c) {
                acc[r][c] = __builtin_amdgcn_mfma_f32_16x16x32_bf16(ah[r], bh[c], acc[r][c], 0, 0, 0);
                acc[r][c] = __builtin_amdgcn_mfma_f32_16x16x32_bf16(ah[r], bl[c], acc[r][c], 0, 0, 0);
                acc[r][c] = __builtin_amdgcn_mfma_f32_16x16x32_bf16(al[r], bh[c], acc[r][c], 0, 0, 0);
            }
        __syncthreads();
    }
#pragma unroll
    for (int c = 0; c < 4; ++c) {
        int colg = wc * 64 + c * 16 + lrow;
        float bv = (colg < 64) ? bias0[colg] : bias1[colg - 64];
#pragma unroll
        for (int r = 0; r < 2; ++r)
#pragma unroll
            for (int j = 0; j < 4; ++j) {
                long grow = rowbase + wr * 32 + r * 16 + quad * 4 + j;
                if (grow < NN) C[grow * 128 + colg] = acc[r][c][j] + bv;
            }
    }
}

// ================= message kernel: m = relu(y[src] + e@Wme); run-scan aggregate =================
__global__ __launch_bounds__(256, 4) void k_msg2(
    const u16* __restrict__ eh, const u16* __restrict__ el,
    const int* __restrict__ sp, const int* __restrict__ dp,
    const u16* __restrict__ Bth, const u16* __restrict__ Btl,
    const float* __restrict__ y,
    float* __restrict__ agg)
{
    __shared__ union {
        struct { u16 Bh[128][72]; u16 Bl[128][72]; } b;
        float cbuf[64][66];
    } u;
    __shared__ int s_sp[64], s_dp[64];
    const int tid = threadIdx.x;
    const long rowbase = (long)blockIdx.x * 64;
    if (tid < 64) {
        long r = rowbase + tid;
        if (r < NE) { s_sp[tid] = sp[r]; s_dp[tid] = dp[r]; }
        else        { s_sp[tid] = 0;     s_dp[tid] = -1;    }
    }
    {
        int colb = tid >> 1, kh = (tid & 1) * 32;
        long bb = (long)colb * 192 + 128 + kh;
#pragma unroll
        for (int q = 0; q < 32; q += 8) {
            *(int4*)&u.b.Bh[colb][kh + q] = *(const int4*)(Bth + bb + q);
            *(int4*)&u.b.Bl[colb][kh + q] = *(const int4*)(Btl + bb + q);
        }
    }
    __syncthreads();
    const int wave = tid >> 6, lane = tid & 63;
    const int quad = lane >> 4, lrow = lane & 15;
    const int wr = wave >> 1, wc = wave & 1;

    f32x4 acc[2][4];
#pragma unroll
    for (int r = 0; r < 2; ++r)
#pragma unroll
        for (int c = 0; c < 4; ++c) acc[r][c] = (f32x4){0.f, 0.f, 0.f, 0.f};

#pragma unroll
    for (int kp = 0; kp < 2; ++kp) {
        bf16x8 ah[2], al[2], bh[4], bl[4];
#pragma unroll
        for (int r = 0; r < 2; ++r) {
            long row = rowbase + wr * 32 + r * 16 + lrow; if (row >= NE) row = NE - 1;
            long ba = row * 64 + kp * 32 + quad * 8;
            ah[r] = *(const bf16x8*)(eh + ba);
            al[r] = *(const bf16x8*)(el + ba);
        }
#pragma unroll
        for (int c = 0; c < 4; ++c) {
            bh[c] = *(const bf16x8*)&u.b.Bh[wc * 64 + c * 16 + lrow][kp * 32 + quad * 8];
            bl[c] = *(const bf16x8*)&u.b.Bl[wc * 64 + c * 16 + lrow][kp * 32 + quad * 8];
        }
#pragma unroll
        for (int r = 0; r < 2; ++r)
#pragma unroll
            for (int c = 0; c < 4; ++c) {
                acc[r][c] = __builtin_amdgcn_mfma_f32_16x16x32_bf16(ah[r], bh[c], acc[r][c], 0, 0, 0);
                acc[r][c] = __builtin_amdgcn_mfma_f32_16x16x32_bf16(ah[r], bl[c], acc[r][c], 0, 0, 0);
                acc[r][c] = __builtin_amdgcn_mfma_f32_16x16x32_bf16(al[r], bh[c], acc[r][c], 0, 0, 0);
            }
    }
    __syncthreads();
    const int col = tid & 63, seg = tid >> 6;
    for (int p = 0; p < 2; ++p) {
        if (wc == p) {
#pragma unroll
            for (int c = 0; c < 4; ++c)
#pragma unroll
                for (int r = 0; r < 2; ++r)
#pragma unroll
                    for (int j = 0; j < 4; ++j)
                        u.cbuf[wr * 32 + r * 16 + quad * 4 + j][c * 16 + lrow] = acc[r][c][j];
        }
        __syncthreads();
        {
            int row = tid >> 2, q = tid & 3;
            const float* py = y + (long)s_sp[row] * 128 + p * 64 + q * 16;
            float* pc = &u.cbuf[row][q * 16];
#pragma unroll
            for (int g = 0; g < 4; ++g) {
                float4 yv = *(const float4*)(py + g * 4);
                pc[g * 4 + 0] = relu_f(pc[g * 4 + 0] + yv.x);
                pc[g * 4 + 1] = relu_f(pc[g * 4 + 1] + yv.y);
                pc[g * 4 + 2] = relu_f(pc[g * 4 + 2] + yv.z);
                pc[g * 4 + 3] = relu_f(pc[g * 4 + 3] + yv.w);
            }
        }
        __syncthreads();
        int cur = -1; float sum = 0.0f;
        for (int rr = seg * 16; rr < seg * 16 + 16; ++rr) {
            int d = s_dp[rr];
            if (d != cur) {
                if (cur >= 0) atomicAdd(&agg[(long)cur * 128 + p * 64 + col], sum);
                cur = d; sum = 0.0f;
            }
            sum += u.cbuf[rr][col];
        }
        if (cur >= 0) atomicAdd(&agg[(long)cur * 128 + p * 64 + col], sum);
        __syncthreads();
    }
}

// ========== fused last-layer kernel: e' = relu(e@We3 + u1[src]+u2[dst]) in LDS, then
// ========== m = relu(y[src] + e'@Wm); run-scan aggregate. Eliminates edge2(l=1)'s 256MB
// ========== e'-plane write + msg2(l=2)'s 256MB read. B2 (128 cols) staged in two halves.
__global__ __launch_bounds__(256) void k_msg2e(
    const u16* __restrict__ eh, const u16* __restrict__ el,
    const int* __restrict__ sp, const int* __restrict__ dp,
    const u16* __restrict__ B1th, const u16* __restrict__ B1tl,  // Wet l=1 [64][320]; k=256..319
    const u16* __restrict__ B2th, const u16* __restrict__ B2tl,  // Wmt l=2 [128][192]; k=128..191
    const float* __restrict__ uu,   // [NN][128] = [u1|u2]  (from ngemm Wx l=1)
    const float* __restrict__ y,    // [NN][128]            (from ngemm Wm l=2)
    float* __restrict__ agg)
{
    __shared__ union {                                   // region R1: 18432 B
        struct { u16 h[64][72]; u16 l[64][72]; } b1;     //   We3 tile (MFMA-1)
        float cb[64][66];                                //   then edge-cbuf, then msg-cbuf
    } r1;
    __shared__ struct { u16 h[64][72]; u16 l[64][72]; } r2;  // B2 half tile: 18432 B
    __shared__ struct { u16 h[64][72]; u16 l[64][72]; } r3;  // e' planes:    18432 B
    __shared__ int s_sp[64], s_dp[64];
    const int tid = threadIdx.x;
    const long rowbase = (long)blockIdx.x * 64;
    if (tid < 64) {
        long r = rowbase + tid;
        int rr = (r < NE) ? (int)r : (NE - 1);
        s_sp[tid] = sp[rr];
        s_dp[tid] = dp[rr];
    }
    // stage B1 (We3: 64 cols x K=64)
    {
        int colb = tid >> 2, kh = (tid & 3) * 16;
        long bb = (long)colb * 320 + 256 + kh;
        *(int4*)&r1.b1.h[colb][kh]     = *(const int4*)(B1th + bb);
        *(int4*)&r1.b1.h[colb][kh + 8] = *(const int4*)(B1th + bb + 8);
        *(int4*)&r1.b1.l[colb][kh]     = *(const int4*)(B1tl + bb);
        *(int4*)&r1.b1.l[colb][kh + 8] = *(const int4*)(B1tl + bb + 8);
    }
    __syncthreads();
    const int wave = tid >> 6, lane = tid & 63;
    const int quad = lane >> 4, lrow = lane & 15;
    const int wr = wave >> 1, wc = wave & 1;   // 2x2 wave grid; 32-row x 32-col tiles

    // ---- MFMA-1: e @ We3 -> acc1 (64 edges x 64 cols) ----
    f32x4 acc1[2][2];
#pragma unroll
    for (int r = 0; r < 2; ++r)
#pragma unroll
        for (int c = 0; c < 2; ++c) acc1[r][c] = (f32x4){0.f, 0.f, 0.f, 0.f};
#pragma unroll
    for (int kp = 0; kp < 2; ++kp) {
        bf16x8 ah[2], al[2], bh[2], bl[2];
#pragma unroll
        for (int r = 0; r < 2; ++r) {
            long row = rowbase + wr * 32 + r * 16 + lrow; if (row >= NE) row = NE - 1;
            long ba = row * 64 + kp * 32 + quad * 8;
            ah[r] = *(const bf16x8*)(eh + ba);
            al[r] = *(const bf16x8*)(el + ba);
        }
#pragma unroll
        for (int c = 0; c < 2; ++c) {
            bh[c] = *(const bf16x8*)&r1.b1.h[wc * 32 + c * 16 + lrow][kp * 32 + quad * 8];
            bl[c] = *(const bf16x8*)&r1.b1.l[wc * 32 + c * 16 + lrow][kp * 32 + quad * 8];
        }
#pragma unroll
        for (int r = 0; r < 2; ++r)
#pragma unroll
            for (int c = 0; c < 2; ++c) {
                acc1[r][c] = __builtin_amdgcn_mfma_f32_16x16x32_bf16(ah[r], bh[c], acc1[r][c], 0, 0, 0);
                acc1[r][c] = __builtin_amdgcn_mfma_f32_16x16x32_bf16(ah[r], bl[c], acc1[r][c], 0, 0, 0);
                acc1[r][c] = __builtin_amdgcn_mfma_f32_16x16x32_bf16(al[r], bh[c], acc1[r][c], 0, 0, 0);
            }
    }
    __syncthreads();   // all waves done reading B1 -> R1 reusable as cbuf
    // transpose acc1 -> r1.cb
#pragma unroll
    for (int c = 0; c < 2; ++c)
#pragma unroll
        for (int r = 0; r < 2; ++r)
#pragma unroll
            for (int j = 0; j < 4; ++j)
                r1.cb[wr * 32 + r * 16 + quad * 4 + j][wc * 32 + c * 16 + lrow] = acc1[r][c][j];
    __syncthreads();
    // edge epilogue: e' = relu(cb + u1[src] + u2[dst]) -> r3 bf16 split planes (16 cols/thread)
    {
        const int row = tid >> 2, q = tid & 3;
        const float* pu1 = uu + (long)s_sp[row] * 128 + q * 16;
        const float* pu2 = uu + (long)s_dp[row] * 128 + 64 + q * 16;
        const float* pc = &r1.cb[row][q * 16];
        u16x8 hv0, lv0, hv1, lv1;
#pragma unroll
        for (int half = 0; half < 2; ++half) {
            float4 a0 = *(const float4*)(pu1 + half * 8);
            float4 a1 = *(const float4*)(pu1 + half * 8 + 4);
            float4 b0 = *(const float4*)(pu2 + half * 8);
            float4 b1 = *(const float4*)(pu2 + half * 8 + 4);
            float s[8] = {a0.x + b0.x, a0.y + b0.y, a0.z + b0.z, a0.w + b0.w,
                          a1.x + b1.x, a1.y + b1.y, a1.z + b1.z, a1.w + b1.w};
            u16x8 hv, lv;
#pragma unroll
            for (int k = 0; k < 8; ++k) {
                float v = relu_f(pc[half * 8 + k] + s[k]);
                u16 h = f2bf(v);
                hv[k] = h;
                lv[k] = f2bf(v - bf2f(h));
            }
            if (half == 0) { hv0 = hv; lv0 = lv; } else { hv1 = hv; lv1 = lv; }
        }
        *(u16x8*)&r3.h[row][q * 16]     = hv0;
        *(u16x8*)&r3.h[row][q * 16 + 8] = hv1;
        *(u16x8*)&r3.l[row][q * 16]     = lv0;
        *(u16x8*)&r3.l[row][q * 16 + 8] = lv1;
    }
    __syncthreads();
    // ---- per col-half of the message GEMM: stage B2-half, MFMA-2, msg epilogue ----
    const int col = tid & 63, seg = tid >> 6;
    for (int p = 0; p < 2; ++p) {
        {
            int colb = tid >> 2, kh = (tid & 3) * 16;
            long bb = (long)(p * 64 + colb) * 192 + 128 + kh;
            *(int4*)&r2.h[colb][kh]     = *(const int4*)(B2th + bb);
            *(int4*)&r2.h[colb][kh + 8] = *(const int4*)(B2th + bb + 8);
            *(int4*)&r2.l[colb][kh]     = *(const int4*)(B2tl + bb);
            *(int4*)&r2.l[colb][kh + 8] = *(const int4*)(B2tl + bb + 8);
        }
        __syncthreads();
        f32x4 acc2[2][2];
#pragma unroll
        for (int r = 0; r < 2; ++r)
#pragma unroll
            for (int c = 0; c < 2; ++c) acc2[r][c] = (f32x4){0.f, 0.f, 0.f, 0.f};
#pragma unroll
        for (int kp = 0; kp < 2; ++kp) {
            bf16x8 ah[2], al[2], bh[2], bl[2];
#pragma unroll
            for (int r = 0; r < 2; ++r) {
                ah[r] = *(const bf16x8*)&r3.h[wr * 32 + r * 16 + lrow][kp * 32 + quad * 8];
                al[r] = *(const bf16x8*)&r3.l[wr * 32 + r * 16 + lrow][kp * 32 + quad * 8];
            }
#pragma unroll
            for (int c = 0; c < 2; ++c) {
                bh[c] = *(const bf16x8*)&r2.h[wc * 32 + c * 16 + lrow][kp * 32 + quad * 8];
                bl[c] = *(const bf16x8*)&r2.l[wc * 32 + c * 16 + lrow][kp * 32 + quad * 8];
            }
#pragma unroll
            for (int r = 0; r < 2; ++r)
#pragma unroll
                for (int c = 0; c < 2; ++c) {
                    acc2[r][c] = __builtin_amdgcn_mfma_f32_16x16x32_bf16(ah[r], bh[c], acc2[r][c], 0, 0, 0);
                    acc2[r][c] = __builtin_amdgcn_mfma_f32_16x16x32_bf16(ah[r], bl[c], acc2[r][c], 0, 0, 0);
                    acc2[r][c] = __builtin_amdgcn_mfma_f32_16x16x32_bf16(al[r], bh[c], acc2[r][c], 0, 0, 0);
                }
        }
        // phase A: acc2 -> r1.cb (R1 free: prior reader finished before last barrier)
#pragma unroll
        for (int c = 0; c < 2; ++c)
#pragma unroll
            for (int r = 0; r < 2; ++r)
#pragma unroll
                for (int j = 0; j < 4; ++j)
                    r1.cb[wr * 32 + r * 16 + quad * 4 + j][wc * 32 + c * 16 + lrow] = acc2[r][c][j];
        __syncthreads();
        // phase B: y add + relu
        {
            int row = tid >> 2, q = tid & 3;
            const float* py = y + (long)s_sp[row] * 128 + p * 64 + q * 16;
            float* pc = &r1.cb[row][q * 16];
#pragma unroll
            for (int g = 0; g < 4; ++g) {
                float4 yv = *(const float4*)(py + g * 4);
                pc[g * 4 + 0] = relu_f(pc[g * 4 + 0] + yv.x);
                pc[g * 4 + 1] = relu_f(pc[g * 4 + 1] + yv.y);
                pc[g * 4 + 2] = relu_f(pc[g * 4 + 2] + yv.z);
                pc[g * 4 + 3] = relu_f(pc[g * 4 + 3] + yv.w);
            }
        }
        __syncthreads();
        // phase C: run-scan over dst-runs, atomic flush (ghost rows masked by row bound)
        {
            int cur = -1; float sum = 0.0f;
            for (int rr = seg * 16; rr < seg * 16 + 16; ++rr) {
                int d = (rowbase + rr < NE) ? s_dp[rr] : -1;
                if (d != cur) {
                    if (cur >= 0) atomicAdd(&agg[(long)cur * 128 + p * 64 + col], sum);
                    cur = d; sum = 0.0f;
                }
                sum += r1.cb[rr][col];
            }
            if (cur >= 0) atomicAdd(&agg[(long)cur * 128 + p * 64 + col], sum);
        }
        __syncthreads();
    }
}

// ================= node update GEMM (MFMA, split bf16, fused L2-norm) =================
__global__ __launch_bounds__(256) void k_update_mfma(
    float* __restrict__ agg, const float* __restrict__ icnt,
    u16* __restrict__ xh, u16* __restrict__ xl,
    const u16* __restrict__ Bth, const u16* __restrict__ Btl,
    const float* __restrict__ bias, int zero_agg)
{
    __shared__ u16 Ah[64][40], Al[64][40], Bh[128][40], Bl[128][40];
    __shared__ float s_ic[64];
    __shared__ float sP[64][2];
    const int tid = threadIdx.x;
    const long rowbase = (long)blockIdx.x * 64;
    if (tid < 64) {
        long r = rowbase + tid;
        int rr = (r < NN) ? (int)r : (NN - 1);
        s_ic[tid] = icnt[rr];
    }
    __syncthreads();
    const int wave = tid >> 6, lane = tid & 63;
    const int quad = lane >> 4, lrow = lane & 15;
    const int wr = wave >> 1, wc = wave & 1;
    const int arow = tid >> 2, akh = (tid & 3) * 8;
    const int brow = tid >> 1, bkh = (tid & 1) << 4;

    f32x4 acc[2][4];
#pragma unroll
    for (int r = 0; r < 2; ++r)
#pragma unroll
        for (int c = 0; c < 4; ++c) acc[r][c] = (f32x4){0.f, 0.f, 0.f, 0.f};

    for (int kp = 0; kp < 8; ++kp) {
        const int k0 = kp * 32;
        if (k0 < 128) {
            long r = rowbase + arow;
            const bool own = (r < NN);
            if (!own) r = NN - 1;
            float* pa = agg + r * 128 + k0 + akh;
            float ic = s_ic[arow];
#pragma unroll
            for (int q = 0; q < 8; q += 4) {
                float4 f = *(const float4*)(pa + q);
                float vv[4] = {f.x, f.y, f.z, f.w};
#pragma unroll
                for (int j = 0; j < 4; ++j) {
                    float v = vv[j] * ic;
                    u16 h = f2bf(v);
                    Ah[arow][akh + q + j] = h;
                    Al[arow][akh + q + j] = f2bf(v - bf2f(h));
                }
            }
            if (zero_agg && own) {
                float4 z = {0.f, 0.f, 0.f, 0.f};
                *(float4*)(pa + 0) = z;
                *(float4*)(pa + 4) = z;
            }
        } else {
            long r = rowbase + arow; if (r >= NN) r = NN - 1;
            long b = r * 128 + (k0 - 128 + akh);
            *(int4*)&Ah[arow][akh] = *(const int4*)(xh + b);
            *(int4*)&Al[arow][akh] = *(const int4*)(xl + b);
        }
        {
            long b = (long)brow * 256 + k0 + bkh;
            *(int4*)&Bh[brow][bkh]     = *(const int4*)(Bth + b);
            *(int4*)&Bh[brow][bkh + 8] = *(const int4*)(Bth + b + 8);
            *(int4*)&Bl[brow][bkh]     = *(const int4*)(Btl + b);
            *(int4*)&Bl[brow][bkh + 8] = *(const int4*)(Btl + b + 8);
        }
        __syncthreads();
        bf16x8 ah[2], al[2], bh[4], bl[4];
#pragma unroll
        for (int r = 0; r < 2; ++r) {
            ah[r] = *(const bf16x8*)&Ah[wr * 32 + r * 16 + lrow][quad * 8];
            al[r] = *(const bf16x8*)&Al[wr * 32 + r * 16 + lrow][quad * 8];
        }
#pragma unroll
        for (int c = 0; c < 4; ++c) {
            bh[c] = *(const bf16x8*)&Bh[wc * 64 + c * 16 + lrow][quad * 8];
            bl[c] = *(const bf16x8*)&Bl[wc * 64 + c * 16 + lrow][quad * 8];
        }
#pragma unroll
        for (int r = 0; r < 2; ++r)
#pragma unroll
            for (int c = 0; c < 4; ++c) {
                acc[r][c] = __builtin_amdgcn_mfma_f32_16x16x32_bf16(ah[r], bh[c], acc[r][c], 0, 0, 0);
                acc[r][c] = __builtin_amdgcn_mfma_f32_16x16x32_bf16(ah[r], bl[c], acc[r][c], 0, 0, 0);
                acc[r][c] = __builtin_amdgcn_mfma_f32_16x16x32_bf16(al[r], bh[c], acc[r][c], 0, 0, 0);
            }
        __syncthreads();
    }
#pragma unroll
    for (int r = 0; r < 2; ++r)
#pragma unroll
        for (int c = 0; c < 4; ++c)
#pragma unroll
            for (int j = 0; j < 4; ++j)
                acc[r][c][j] = relu_f(acc[r][c][j] + bias[wc * 64 + c * 16 + lrow]);
#pragma unroll
    for (int r = 0; r < 2; ++r)
#pragma unroll
        for (int j = 0; j < 4; ++j) {
            float s2 = 0.0f;
#pragma unroll
            for (int c = 0; c < 4; ++c) { float v = acc[r][c][j]; s2 += v * v; }
#pragma unroll
            for (int m = 1; m < 16; m <<= 1) s2 += __shfl_xor(s2, m, 64);
            if (lrow == 0) sP[wr * 32 + r * 16 + quad * 4 + j][wc] = s2;
        }
    __syncthreads();
#pragma unroll
    for (int r = 0; r < 2; ++r)
#pragma unroll
        for (int j = 0; j < 4; ++j) {
            int lr = wr * 32 + r * 16 + quad * 4 + j;
            long grow = rowbase + lr;
            if (grow < NN) {
                float tot = sP[lr][0] + sP[lr][1];
                float rn = 1.0f / fmaxf(sqrtf(tot), 1e-12f);
#pragma unroll
                for (int c = 0; c < 4; ++c) {
                    float v = acc[r][c][j] * rn;
                    long o = grow * 128 + wc * 64 + c * 16 + lrow;
                    u16 h = f2bf(v);
                    xh[o] = h;
                    xl[o] = f2bf(v - bf2f(h));
                }
            }
        }
}

// ================= edge update (layer 0 only): e' = relu(u1[src]+u2[dst]+e@We3) =================
__global__ __launch_bounds__(256, 4) void k_edge2(
    u16* __restrict__ eh, u16* __restrict__ el,
    const int* __restrict__ sp, const int* __restrict__ dp,
    const u16* __restrict__ Bth, const u16* __restrict__ Btl,
    const float* __restrict__ uu)
{
    __shared__ union {
        struct { u16 Bh[64][72]; u16 Bl[64][72]; } b;
        float cbuf[128][66];
    } u;
    __shared__ int s_sp[128], s_dp[128];
    const int tid = threadIdx.x;
    const long rowbase = (long)blockIdx.x * 128;
    if (tid < 128) {
        long r = rowbase + tid;
        int rr = (r < NE) ? (int)r : (NE - 1);
        s_sp[tid] = sp[rr];
        s_dp[tid] = dp[rr];
    }
    {
        int colb = tid >> 2, kh = (tid & 3) * 16;
        long bb = (long)colb * 320 + 256 + kh;
        *(int4*)&u.b.Bh[colb][kh]     = *(const int4*)(Bth + bb);
        *(int4*)&u.b.Bh[colb][kh + 8] = *(const int4*)(Bth + bb + 8);
        *(int4*)&u.b.Bl[colb][kh]     = *(const int4*)(Btl + bb);
        *(int4*)&u.b.Bl[colb][kh + 8] = *(const int4*)(Btl + bb + 8);
    }
    __syncthreads();
    const int wave = tid >> 6, lane = tid & 63;
    const int quad = lane >> 4, lrow = lane & 15;

    f32x4 acc[2][4];
#pragma unroll
    for (int r = 0; r < 2; ++r)
#pragma unroll
        for (int c = 0; c < 4; ++c) acc[r][c] = (f32x4){0.f, 0.f, 0.f, 0.f};

#pragma unroll
    for (int kp = 0; kp < 2; ++kp) {
        bf16x8 ah[2], al[2], bh[4], bl[4];
#pragma unroll
        for (int r = 0; r < 2; ++r) {
            long row = rowbase + wave * 32 + r * 16 + lrow; if (row >= NE) row = NE - 1;
            long ba = row * 64 + kp * 32 + quad * 8;
            ah[r] = *(const bf16x8*)(eh + ba);
            al[r] = *(const bf16x8*)(el + ba);
        }
#pragma unroll
        for (int c = 0; c < 4; ++c) {
            bh[c] = *(const bf16x8*)&u.b.Bh[c * 16 + lrow][kp * 32 + quad * 8];
            bl[c] = *(const bf16x8*)&u.b.Bl[c * 16 + lrow][kp * 32 + quad * 8];
        }
#pragma unroll
        for (int r = 0; r < 2; ++r)
#pragma unroll
            for (int c = 0; c < 4; ++c) {
                acc[r][c] = __builtin_amdgcn_mfma_f32_16x16x32_bf16(ah[r], bh[c], acc[r][c], 0, 0, 0);
                acc[r][c] = __builtin_amdgcn_mfma_f32_16x16x32_bf16(ah[r], bl[c], acc[r][c], 0, 0, 0);
                acc[r][c] = __builtin_amdgcn_mfma_f32_16x16x32_bf16(al[r], bh[c], acc[r][c], 0, 0, 0);
            }
    }
    __syncthreads();
#pragma unroll
    for (int c = 0; c < 4; ++c)
#pragma unroll
        for (int r = 0; r < 2; ++r)
#pragma unroll
            for (int j = 0; j < 4; ++j)
                u.cbuf[wave * 32 + r * 16 + quad * 4 + j][c * 16 + lrow] = acc[r][c][j];
    __syncthreads();
    {
        const int row = tid >> 1, half = tid & 1;
        const long grow = rowbase + row;
        if (grow < NE) {
            const float* pu1 = uu + (long)s_sp[row] * 128 + half * 32;
            const float* pu2 = uu + (long)s_dp[row] * 128 + 64 + half * 32;
            const long o = grow * 64 + half * 32;
#pragma unroll
            for (int g = 0; g < 4; ++g) {
                float4 a0 = *(const float4*)(pu1 + g * 8);
                float4 a1 = *(const float4*)(pu1 + g * 8 + 4);
                float4 b0 = *(const float4*)(pu2 + g * 8);
                float4 b1 = *(const float4*)(pu2 + g * 8 + 4);
                float s[8] = {a0.x + b0.x, a0.y + b0.y, a0.z + b0.z, a0.w + b0.w,
                              a1.x + b1.x, a1.y + b1.y, a1.z + b1.z, a1.w + b1.w};
                u16x8 hv, lv;
#pragma unroll
                for (int k = 0; k < 8; ++k) {
                    float v = relu_f(u.cbuf[row][half * 32 + g * 8 + k] + s[k]);
                    u16 h = f2bf(v);
                    hv[k] = h;
                    lv[k] = f2bf(v - bf2f(h));
                }
                *(u16x8*)(eh + o + g * 8) = hv;
                *(u16x8*)(el + o + g * 8) = lv;
            }
        }
    }
}

// ---------------- fused MLP head: out = relu(x@W1+b1)@W2+b2 ----------------
__global__ __launch_bounds__(256) void k_head(
    const u16* __restrict__ xh, const u16* __restrict__ xl,
    const float* __restrict__ W1, const float* __restrict__ b1,
    const float* __restrict__ W2, const float* __restrict__ b2,
    float* __restrict__ out)
{
    constexpr int KC = 64, NP = 2, EB = 32;
    __shared__ __align__(16) float At[KC][EB + 4];
    __shared__ __align__(16) union { float W1s[KC][64]; float W2s[KC][128]; } w;
    const int tid = threadIdx.x;
    const int rowbase = blockIdx.x * EB;
    const int wave = tid >> 6, lane = tid & 63;
    float acc[8];
#pragma unroll
    for (int i = 0; i < 8; ++i) acc[i] = 0.0f;

    for (int kp = 0; kp < NP; ++kp) {
        const int k0 = kp * KC;
        for (int i = tid; i < KC * EB; i += 256) {
            int e = i >> 6, kk = i & 63, k = k0 + kk;
            int r = min(rowbase + e, NN - 1);
            long b = (long)r * 128 + k;
            At[kk][e] = bf2f(xh[b]) + bf2f(xl[b]);
        }
        for (int i = tid; i < KC * 64; i += 256) {
            int kk = i >> 6, cc = i & 63;
            w.W1s[kk][cc] = W1[(size_t)(k0 + kk) * 64 + cc];
        }
        __syncthreads();
#pragma unroll 4
        for (int kk = 0; kk < KC; ++kk) {
            const float* ar = &At[kk][wave * 8];
            float4 a0 = *(const float4*)ar;
            float4 a1 = *(const float4*)(ar + 4);
            float wv = w.W1s[kk][lane];
            acc[0] += a0.x * wv; acc[1] += a0.y * wv; acc[2] += a0.z * wv; acc[3] += a0.w * wv;
            acc[4] += a1.x * wv; acc[5] += a1.y * wv; acc[6] += a1.z * wv; acc[7] += a1.w * wv;
        }
        __syncthreads();
    }
    {
        const float bv = b1[lane];
#pragma unroll
        for (int j = 0; j < 8; ++j)
            At[lane][wave * 8 + j] = relu_f(acc[j] + bv);
    }
    for (int i = tid; i < KC * 128; i += 256) {
        int kk = i >> 7, cc = i & 127;
        w.W2s[kk][cc] = W2[(size_t)kk * 128 + cc];
    }
    __syncthreads();
    float a2[16];
#pragma unroll
    for (int i = 0; i < 16; ++i) a2[i] = 0.0f;
#pragma unroll 4
    for (int kk = 0; kk < KC; ++kk) {
        const float* ar = &At[kk][wave * 8];
        float4 a0 = *(const float4*)ar;
        float4 a1 = *(const float4*)(ar + 4);
        float w0 = w.W2s[kk][lane], w1 = w.W2s[kk][64 + lane];
        a2[0] += a0.x * w0;  a2[1] += a0.y * w0;  a2[2] += a0.z * w0;  a2[3] += a0.w * w0;
        a2[4] += a1.x * w0;  a2[5] += a1.y * w0;  a2[6] += a1.z * w0;  a2[7] += a1.w * w0;
        a2[8] += a0.x * w1;  a2[9] += a0.y * w1;  a2[10] += a0.z * w1; a2[11] += a0.w * w1;
        a2[12] += a1.x * w1; a2[13] += a1.y * w1; a2[14] += a1.z * w1; a2[15] += a1.w * w1;
    }
    const float o0 = b2[lane], o1 = b2[64 + lane];
#pragma unroll
    for (int j = 0; j < 8; ++j) {
        int r = rowbase + wave * 8 + j;
        if (r < NN) {
            out[(size_t)r * 128 + lane] = a2[j] + o0;
            out[(size_t)r * 128 + 64 + lane] = a2[8 + j] + o1;
        }
    }
}

// ---------------- host-side launch ----------------
extern "C" void kernel_launch(void* const* d_in, const int* in_sizes, int n_in,
                              void* d_out, int out_size, void* d_ws, size_t ws_size,
                              hipStream_t stream) {
    const float* d_x  = (const float*)d_in[0];
    const float* d_ea = (const float*)d_in[1];
    const int*   d_ei = (const int*)d_in[2];
    const float* Wm   = (const float*)d_in[3];
    const float* bm   = (const float*)d_in[4];
    const float* Wa   = (const float*)d_in[5];
    const float* ba   = (const float*)d_in[6];
    const float* We   = (const float*)d_in[7];
    const float* be   = (const float*)d_in[8];
    const float* W1   = (const float*)d_in[9];
    const float* b1   = (const float*)d_in[10];
    const float* W2   = (const float*)d_in[11];
    const float* b2   = (const float*)d_in[12];
    float* out = (float*)d_out;

    const int* src = d_ei;
    const int* dst = d_ei + NE;

    char* p = (char*)d_ws;
    auto alloc = [&](size_t bytes) { char* q = p; p += (bytes + 255) & ~(size_t)255; return q; };
    u16* xh  = (u16*)alloc((size_t)NN * 128 * 2);
    u16* xl  = (u16*)alloc((size_t)NN * 128 * 2);
    u16* ehb = (u16*)alloc((size_t)NE * 64 * 2);
    u16* elb = (u16*)alloc((size_t)NE * 64 * 2);
    float* agg = (float*)alloc((size_t)NN * 128 * 4);
    float* yu  = (float*)alloc((size_t)NN * 128 * 4);   // y (and u for layer 0)
    float* ubuf = (float*)alloc((size_t)NN * 128 * 4);  // u for layer 1 (coexists with y2)
    float* cnt = (float*)alloc((size_t)NN * 4);
    float* zbuf = (float*)alloc(64 * 4);
    u16* Wmt_h = (u16*)alloc((size_t)3 * 192 * 128 * 2);
    u16* Wmt_l = (u16*)alloc((size_t)3 * 192 * 128 * 2);
    u16* Wat_h = (u16*)alloc((size_t)3 * 256 * 128 * 2);
    u16* Wat_l = (u16*)alloc((size_t)3 * 256 * 128 * 2);
    u16* Wet_h = (u16*)alloc((size_t)3 * 320 * 64 * 2);
    u16* Wet_l = (u16*)alloc((size_t)3 * 320 * 64 * 2);
    u16* Wxt_h = (u16*)alloc((size_t)3 * 128 * 128 * 2);
    u16* Wxt_l = (u16*)alloc((size_t)3 * 128 * 128 * 2);
    int* hist   = (int*)alloc((size_t)NN * 4);
    int* excl   = (int*)alloc((size_t)NN * 4);
    int* bsum   = (int*)alloc(128 * 4);
    int* cursor = (int*)alloc((size_t)NN * 4);
    int* perm   = (int*)alloc((size_t)NE * 4);
    int* sp     = (int*)alloc((size_t)NE * 4);
    int* dp     = (int*)alloc((size_t)NE * 4);

    const int NB1 = (NN + 511) / 512;

    hipMemsetAsync(hist, 0, NN * sizeof(int), stream);
    k_hist<<<(NE + 255) / 256, 256, 0, stream>>>(dst, hist);
    k_scan1<<<NB1, 512, 0, stream>>>(hist, excl, bsum, cnt);
    k_scan2<<<1, 128, 0, stream>>>(bsum, NB1);
    k_scan3<<<NB1, 512, 0, stream>>>(excl, bsum, cursor);
    k_scatter<<<(NE + 255) / 256, 256, 0, stream>>>(dst, cursor, perm);

    k_split_all<<<(XQ + NE * 16 + 255) / 256, 256, 0, stream>>>(
        d_x, xh, xl, d_ea, perm, ehb, elb, src, dst, sp, dp);
    k_wtall<<<(245824 + 255) / 256, 256, 0, stream>>>(
        Wm, Wa, We, Wmt_h, Wmt_l, Wat_h, Wat_l, Wet_h, Wet_l, Wxt_h, Wxt_l, zbuf);

    hipMemsetAsync(agg, 0, (size_t)NN * 128 * sizeof(float), stream);   // layer-0 only

    const int NGB = (NN + 63) / 64;
    // ---- layer 0 ----
    k_ngemm<<<NGB, 256, 0, stream>>>(xh, xl, Wmt_h, Wmt_l, 192, bm, bm + 64, yu);
    k_msg2<<<(NE + 63) / 64, 256, 0, stream>>>(ehb, elb, sp, dp, Wmt_h, Wmt_l, yu, agg);
    k_update_mfma<<<NGB, 256, 0, stream>>>(agg, cnt, xh, xl, Wat_h, Wat_l, ba, 1);
    k_ngemm<<<NGB, 256, 0, stream>>>(xh, xl, Wxt_h, Wxt_l, 128, be, zbuf, yu);
    k_edge2<<<(NE + 127) / 128, 256, 0, stream>>>(ehb, elb, sp, dp, Wet_h, Wet_l, yu);
    // ---- layer 1 (edge update deferred into fused layer-2 kernel) ----
    k_ngemm<<<NGB, 256, 0, stream>>>(xh, xl,
        Wmt_h + (size_t)1 * 192 * 128, Wmt_l + (size_t)1 * 192 * 128, 192,
        bm + 128, bm + 128 + 64, yu);
    k_msg2<<<(NE + 63) / 64, 256, 0, stream>>>(ehb, elb, sp, dp,
        Wmt_h + (size_t)1 * 192 * 128, Wmt_l + (size_t)1 * 192 * 128, yu, agg);
    k_update_mfma<<<NGB, 256, 0, stream>>>(agg, cnt, xh, xl,
        Wat_h + (size_t)1 * 256 * 128, Wat_l + (size_t)1 * 256 * 128, ba + 128, 1);
    k_ngemm<<<NGB, 256, 0, stream>>>(xh, xl,
        Wxt_h + (size_t)1 * 128 * 128, Wxt_l + (size_t)1 * 128 * 128, 128,
        be + 64, zbuf, ubuf);
    // ---- layer 2 (fused edge(1)+msg(2)) ----
    k_ngemm<<<NGB, 256, 0, stream>>>(xh, xl,
        Wmt_h + (size_t)2 * 192 * 128, Wmt_l + (size_t)2 * 192 * 128, 192,
        bm + 256, bm + 256 + 64, yu);
    k_msg2e<<<(NE + 63) / 64, 256, 0, stream>>>(ehb, elb, sp, dp,
        Wet_h + (size_t)1 * 320 * 64, Wet_l + (size_t)1 * 320 * 64,
        Wmt_h + (size_t)2 * 192 * 128, Wmt_l + (size_t)2 * 192 * 128,
        ubuf, yu, agg);
    k_update_mfma<<<NGB, 256, 0, stream>>>(agg, cnt, xh, xl,
        Wat_h + (size_t)2 * 256 * 128, Wat_l + (size_t)2 * 256 * 128, ba + 256, 0);

    k_head<<<(NN + 31) / 32, 256, 0, stream>>>(xh, xl, W1, b1, W2, b2, out);
}

// Round 11
// 931.020 us; speedup vs baseline: 1.1951x; 1.0261x over previous
//
#include <hip/hip_runtime.h>
#include <cstdint>
#include <cstddef>

#define NN 50000
#define NE 500000
#define XQ (NN * 128 / 4)

typedef unsigned short u16;
typedef __attribute__((ext_vector_type(8))) short bf16x8;
typedef __attribute__((ext_vector_type(4))) float f32x4;
typedef __attribute__((ext_vector_type(4))) unsigned short u16x4;
typedef __attribute__((ext_vector_type(8))) unsigned short u16x8;

__device__ __forceinline__ float relu_f(float v) { return fmaxf(v, 0.0f); }

__device__ __forceinline__ u16 f2bf(float f) {
    union { float f; unsigned u; } c; c.f = f;
    unsigned u = c.u;
    unsigned r = u + 0x7FFFu + ((u >> 16) & 1u);
    return (u16)(r >> 16);
}
__device__ __forceinline__ float bf2f(u16 h) {
    union { unsigned u; float f; } c; c.u = ((unsigned)h) << 16;
    return c.f;
}

// ---------------- counting sort of edges by dst ----------------
__global__ __launch_bounds__(256) void k_hist(const int* __restrict__ dst, int* __restrict__ h) {
    int e = blockIdx.x * 256 + threadIdx.x;
    if (e < NE) atomicAdd(&h[dst[e]], 1);
}

// prefix-scan of hist; also emits cnt = 1/max(hist,1)
__global__ __launch_bounds__(512) void k_scan1(const int* __restrict__ h,
                                               int* __restrict__ excl, int* __restrict__ bsum,
                                               float* __restrict__ cnt) {
    __shared__ int s[512];
    int tid = threadIdx.x;
    int i = blockIdx.x * 512 + tid;
    int v = (i < NN) ? h[i] : 0;
    if (i < NN) cnt[i] = 1.0f / fmaxf((float)v, 1.0f);
    s[tid] = v;
    __syncthreads();
    for (int off = 1; off < 512; off <<= 1) {
        int t = (tid >= off) ? s[tid - off] : 0;
        __syncthreads();
        s[tid] += t;
        __syncthreads();
    }
    if (i < NN) excl[i] = s[tid] - v;
    if (tid == 511) bsum[blockIdx.x] = s[511];
}

__global__ __launch_bounds__(128) void k_scan2(int* __restrict__ bsum, int nb) {
    __shared__ int s[128];
    int tid = threadIdx.x;
    int v = (tid < nb) ? bsum[tid] : 0;
    s[tid] = v;
    __syncthreads();
    for (int off = 1; off < 128; off <<= 1) {
        int t = (tid >= off) ? s[tid - off] : 0;
        __syncthreads();
        s[tid] += t;
        __syncthreads();
    }
    if (tid < nb) bsum[tid] = s[tid] - v;
}

__global__ __launch_bounds__(512) void k_scan3(const int* __restrict__ excl, const int* __restrict__ bsum,
                                               int* __restrict__ cursor) {
    int i = blockIdx.x * 512 + threadIdx.x;
    if (i < NN) cursor[i] = excl[i] + bsum[blockIdx.x];
}

__global__ __launch_bounds__(256) void k_scatter(const int* __restrict__ dst,
                                                 int* __restrict__ cursor, int* __restrict__ perm) {
    int e = blockIdx.x * 256 + threadIdx.x;
    if (e < NE) {
        int pos = atomicAdd(&cursor[dst[e]], 1);
        perm[pos] = e;
    }
}

// ---------------- merged split kernel: x-split + permuted e-split + sp/dp ----------------
__global__ __launch_bounds__(256) void k_split_all(
    const float* __restrict__ x, u16* __restrict__ xh, u16* __restrict__ xl,
    const float* __restrict__ e, const int* __restrict__ perm,
    u16* __restrict__ eh, u16* __restrict__ el,
    const int* __restrict__ src, const int* __restrict__ dst,
    int* __restrict__ sp, int* __restrict__ dp)
{
    long t = (long)blockIdx.x * 256 + threadIdx.x;
    if (t < XQ) {
        float4 v = ((const float4*)x)[t];
        float vv[4] = {v.x, v.y, v.z, v.w};
        u16x4 hv, lv;
#pragma unroll
        for (int j = 0; j < 4; ++j) {
            u16 h = f2bf(vv[j]);
            hv[j] = h;
            lv[j] = f2bf(vv[j] - bf2f(h));
        }
        ((u16x4*)xh)[t] = hv;
        ((u16x4*)xl)[t] = lv;
    } else {
        long g = t - XQ;
        int i = (int)(g >> 4), c4 = ((int)g & 15) << 2;
        if (i < NE) {
            int pe = perm[i];
            if ((g & 15) == 0) { sp[i] = src[pe]; dp[i] = dst[pe]; }
            float4 v = *(const float4*)(e + (long)pe * 64 + c4);
            float vv[4] = {v.x, v.y, v.z, v.w};
            u16x4 hv, lv;
#pragma unroll
            for (int j = 0; j < 4; ++j) {
                u16 h = f2bf(vv[j]);
                hv[j] = h;
                lv[j] = f2bf(vv[j] - bf2f(h));
            }
            long o = (long)i * 64 + c4;
            *(u16x4*)(eh + o) = hv;
            *(u16x4*)(el + o) = lv;
        }
    }
}

// ---------------- batched weight transposes (all layers, all W) + zbuf zero ----------------
__global__ __launch_bounds__(256) void k_wtall(
    const float* __restrict__ Wm, const float* __restrict__ Wa, const float* __restrict__ We,
    u16* __restrict__ Wmt_h, u16* __restrict__ Wmt_l,
    u16* __restrict__ Wat_h, u16* __restrict__ Wat_l,
    u16* __restrict__ Wet_h, u16* __restrict__ Wet_l,
    u16* __restrict__ Wxt_h, u16* __restrict__ Wxt_l,
    float* __restrict__ zbuf)
{
    int i = blockIdx.x * 256 + threadIdx.x;
    float v; u16* th; u16* tl; int oi;
    if (i < 73728) {
        int l = i / 24576, j = i % 24576;
        int n = j / 192, k = j - n * 192;
        v = Wm[(size_t)l * 24576 + (size_t)k * 128 + n];
        th = Wmt_h; tl = Wmt_l; oi = i;
    } else if ((i -= 73728) < 98304) {
        int l = i / 32768, j = i % 32768;
        int n = j / 256, k = j - n * 256;
        v = Wa[(size_t)l * 32768 + (size_t)k * 128 + n];
        th = Wat_h; tl = Wat_l; oi = i;
    } else if ((i -= 98304) < 40960) {
        int l = i / 20480, j = i % 20480;
        int n = j / 320, k = j - n * 320;
        v = We[(size_t)l * 20480 + (size_t)k * 64 + n];
        th = Wet_h; tl = Wet_l; oi = i;
    } else if ((i -= 40960) < 32768) {
        int l = i / 16384, j2 = i % 16384;
        int jj = j2 >> 7, k = j2 & 127;
        v = We[(size_t)l * 20480 + (size_t)(k + ((jj >> 6) << 7)) * 64 + (jj & 63)];
        th = Wxt_h; tl = Wxt_l; oi = i;
    } else if ((i -= 32768) < 64) {
        zbuf[i] = 0.0f;
        return;
    } else {
        return;
    }
    u16 h = f2bf(v);
    th[oi] = h;
    tl[oi] = f2bf(v - bf2f(h));
}

// ================= node GEMM: C = x @ B + bias (fp32 out, no relu) =================
__global__ __launch_bounds__(256) void k_ngemm(
    const u16* __restrict__ xh, const u16* __restrict__ xl,
    const u16* __restrict__ Bth, const u16* __restrict__ Btl, int bstride,
    const float* __restrict__ bias0, const float* __restrict__ bias1,
    float* __restrict__ C)
{
    __shared__ u16 Ah[64][40], Al[64][40], Bh[128][40], Bl[128][40];
    const int tid = threadIdx.x;
    const long rowbase = (long)blockIdx.x * 64;
    const int wave = tid >> 6, lane = tid & 63;
    const int quad = lane >> 4, lrow = lane & 15;
    const int wr = wave >> 1, wc = wave & 1;
    const int arow = tid >> 2, akh = (tid & 3) * 8;
    const int brow = tid >> 1, bkh = (tid & 1) << 4;

    f32x4 acc[2][4];
#pragma unroll
    for (int r = 0; r < 2; ++r)
#pragma unroll
        for (int c = 0; c < 4; ++c) acc[r][c] = (f32x4){0.f, 0.f, 0.f, 0.f};

    for (int kp = 0; kp < 4; ++kp) {
        const int k0 = kp * 32;
        {
            long r = rowbase + arow; if (r >= NN) r = NN - 1;
            long b = r * 128 + k0 + akh;
            *(int4*)&Ah[arow][akh] = *(const int4*)(xh + b);
            *(int4*)&Al[arow][akh] = *(const int4*)(xl + b);
        }
        {
            long b = (long)brow * bstride + k0 + bkh;
            *(int4*)&Bh[brow][bkh]     = *(const int4*)(Bth + b);
            *(int4*)&Bh[brow][bkh + 8] = *(const int4*)(Bth + b + 8);
            *(int4*)&Bl[brow][bkh]     = *(const int4*)(Btl + b);
            *(int4*)&Bl[brow][bkh + 8] = *(const int4*)(Btl + b + 8);
        }
        __syncthreads();
        bf16x8 ah[2], al[2], bh[4], bl[4];
#pragma unroll
        for (int r = 0; r < 2; ++r) {
            ah[r] = *(const bf16x8*)&Ah[wr * 32 + r * 16 + lrow][quad * 8];
            al[r] = *(const bf16x8*)&Al[wr * 32 + r * 16 + lrow][quad * 8];
        }
#pragma unroll
        for (int c = 0; c < 4; ++c) {
            bh[c] = *(const bf16x8*)&Bh[wc * 64 + c * 16 + lrow][quad * 8];
            bl[c] = *(const bf16x8*)&Bl[wc * 64 + c * 16 + lrow][quad * 8];
        }
#pragma unroll
        for (int r = 0; r < 2; ++r)
#pragma unroll
            for (int c = 0; c < 4; ++c) {
                acc[r][c] = __builtin_amdgcn_mfma_f32_16x16x32_bf16(ah[r], bh[c], acc[r][c], 0, 0, 0);
                acc[r][c] = __builtin_amdgcn_mfma_f32_16x16x32_bf16(ah[r], bl[c], acc[r][c], 0, 0, 0);
                acc[r][c] = __builtin_amdgcn_mfma_f32_16x16x32_bf16(al[r], bh[c], acc[r][c], 0, 0, 0);
            }
        __syncthreads();
    }
#pragma unroll
    for (int c = 0; c < 4; ++c) {
        int colg = wc * 64 + c * 16 + lrow;
        float bv = (colg < 64) ? bias0[colg] : bias1[colg - 64];
#pragma unroll
        for (int r = 0; r < 2; ++r)
#pragma unroll
            for (int j = 0; j < 4; ++j) {
                long grow = rowbase + wr * 32 + r * 16 + quad * 4 + j;
                if (grow < NN) C[grow * 128 + colg] = acc[r][c][j] + bv;
            }
    }
}

// ================= message kernel: m = relu(y[src] + e@Wme); run-scan aggregate =================
__global__ __launch_bounds__(256, 4) void k_msg2(
    const u16* __restrict__ eh, const u16* __restrict__ el,
    const int* __restrict__ sp, const int* __restrict__ dp,
    const u16* __restrict__ Bth, const u16* __restrict__ Btl,
    const float* __restrict__ y,
    float* __restrict__ agg)
{
    __shared__ union {
        struct { u16 Bh[128][72]; u16 Bl[128][72]; } b;
        float cbuf[64][66];
    } u;
    __shared__ int s_sp[64], s_dp[64];
    const int tid = threadIdx.x;
    const long rowbase = (long)blockIdx.x * 64;
    if (tid < 64) {
        long r = rowbase + tid;
        if (r < NE) { s_sp[tid] = sp[r]; s_dp[tid] = dp[r]; }
        else        { s_sp[tid] = 0;     s_dp[tid] = -1;    }
    }
    {
        int colb = tid >> 1, kh = (tid & 1) * 32;
        long bb = (long)colb * 192 + 128 + kh;
#pragma unroll
        for (int q = 0; q < 32; q += 8) {
            *(int4*)&u.b.Bh[colb][kh + q] = *(const int4*)(Bth + bb + q);
            *(int4*)&u.b.Bl[colb][kh + q] = *(const int4*)(Btl + bb + q);
        }
    }
    __syncthreads();
    const int wave = tid >> 6, lane = tid & 63;
    const int quad = lane >> 4, lrow = lane & 15;
    const int wr = wave >> 1, wc = wave & 1;

    f32x4 acc[2][4];
#pragma unroll
    for (int r = 0; r < 2; ++r)
#pragma unroll
        for (int c = 0; c < 4; ++c) acc[r][c] = (f32x4){0.f, 0.f, 0.f, 0.f};

#pragma unroll
    for (int kp = 0; kp < 2; ++kp) {
        bf16x8 ah[2], al[2], bh[4], bl[4];
#pragma unroll
        for (int r = 0; r < 2; ++r) {
            long row = rowbase + wr * 32 + r * 16 + lrow; if (row >= NE) row = NE - 1;
            long ba = row * 64 + kp * 32 + quad * 8;
            ah[r] = *(const bf16x8*)(eh + ba);
            al[r] = *(const bf16x8*)(el + ba);
        }
#pragma unroll
        for (int c = 0; c < 4; ++c) {
            bh[c] = *(const bf16x8*)&u.b.Bh[wc * 64 + c * 16 + lrow][kp * 32 + quad * 8];
            bl[c] = *(const bf16x8*)&u.b.Bl[wc * 64 + c * 16 + lrow][kp * 32 + quad * 8];
        }
#pragma unroll
        for (int r = 0; r < 2; ++r)
#pragma unroll
            for (int c = 0; c < 4; ++c) {
                acc[r][c] = __builtin_amdgcn_mfma_f32_16x16x32_bf16(ah[r], bh[c], acc[r][c], 0, 0, 0);
                acc[r][c] = __builtin_amdgcn_mfma_f32_16x16x32_bf16(ah[r], bl[c], acc[r][c], 0, 0, 0);
                acc[r][c] = __builtin_amdgcn_mfma_f32_16x16x32_bf16(al[r], bh[c], acc[r][c], 0, 0, 0);
            }
    }
    __syncthreads();
    const int col = tid & 63, seg = tid >> 6;
    for (int p = 0; p < 2; ++p) {
        if (wc == p) {
#pragma unroll
            for (int c = 0; c < 4; ++c)
#pragma unroll
                for (int r = 0; r < 2; ++r)
#pragma unroll
                    for (int j = 0; j < 4; ++j)
                        u.cbuf[wr * 32 + r * 16 + quad * 4 + j][c * 16 + lrow] = acc[r][c][j];
        }
        __syncthreads();
        {
            int row = tid >> 2, q = tid & 3;
            const float* py = y + (long)s_sp[row] * 128 + p * 64 + q * 16;
            float* pc = &u.cbuf[row][q * 16];
#pragma unroll
            for (int g = 0; g < 4; ++g) {
                float4 yv = *(const float4*)(py + g * 4);
                pc[g * 4 + 0] = relu_f(pc[g * 4 + 0] + yv.x);
                pc[g * 4 + 1] = relu_f(pc[g * 4 + 1] + yv.y);
                pc[g * 4 + 2] = relu_f(pc[g * 4 + 2] + yv.z);
                pc[g * 4 + 3] = relu_f(pc[g * 4 + 3] + yv.w);
            }
        }
        __syncthreads();
        int cur = -1; float sum = 0.0f;
        for (int rr = seg * 16; rr < seg * 16 + 16; ++rr) {
            int d = s_dp[rr];
            if (d != cur) {
                if (cur >= 0) atomicAdd(&agg[(long)cur * 128 + p * 64 + col], sum);
                cur = d; sum = 0.0f;
            }
            sum += u.cbuf[rr][col];
        }
        if (cur >= 0) atomicAdd(&agg[(long)cur * 128 + p * 64 + col], sum);
        __syncthreads();
    }
}

// ========== fused last-layer kernel: e' = relu(e@We3 + u1[src]+u2[dst]) in LDS, then
// ========== m = relu(y[src] + e'@Wm); run-scan aggregate.
// R11: B2 read DIRECT from L2 (no LDS staging) — LDS 55.8KB -> 37.4KB lifts the 2-block/CU
// cap to 4 blocks/CU. (Differs from R7's null: there occupancy wasn't LDS-capped; here it is.)
__global__ __launch_bounds__(256) void k_msg2e(
    const u16* __restrict__ eh, const u16* __restrict__ el,
    const int* __restrict__ sp, const int* __restrict__ dp,
    const u16* __restrict__ B1th, const u16* __restrict__ B1tl,  // Wet l=1 [64][320]; k=256..319
    const u16* __restrict__ B2th, const u16* __restrict__ B2tl,  // Wmt l=2 [128][192]; k=128..191
    const float* __restrict__ uu,   // [NN][128] = [u1|u2]
    const float* __restrict__ y,    // [NN][128]
    float* __restrict__ agg)
{
    __shared__ union {                                   // region R1: 18432 B
        struct { u16 h[64][72]; u16 l[64][72]; } b1;     //   We3 tile (MFMA-1)
        float cb[64][66];                                //   then edge-cbuf, then msg-cbuf
    } r1;
    __shared__ struct { u16 h[64][72]; u16 l[64][72]; } r3;  // e' planes: 18432 B
    __shared__ int s_sp[64], s_dp[64];
    const int tid = threadIdx.x;
    const long rowbase = (long)blockIdx.x * 64;
    if (tid < 64) {
        long r = rowbase + tid;
        int rr = (r < NE) ? (int)r : (NE - 1);
        s_sp[tid] = sp[rr];
        s_dp[tid] = dp[rr];
    }
    // stage B1 (We3: 64 cols x K=64)
    {
        int colb = tid >> 2, kh = (tid & 3) * 16;
        long bb = (long)colb * 320 + 256 + kh;
        *(int4*)&r1.b1.h[colb][kh]     = *(const int4*)(B1th + bb);
        *(int4*)&r1.b1.h[colb][kh + 8] = *(const int4*)(B1th + bb + 8);
        *(int4*)&r1.b1.l[colb][kh]     = *(const int4*)(B1tl + bb);
        *(int4*)&r1.b1.l[colb][kh + 8] = *(const int4*)(B1tl + bb + 8);
    }
    __syncthreads();
    const int wave = tid >> 6, lane = tid & 63;
    const int quad = lane >> 4, lrow = lane & 15;
    const int wr = wave >> 1, wc = wave & 1;   // 2x2 wave grid; 32-row x 32-col tiles

    // ---- MFMA-1: e @ We3 -> acc1 (64 edges x 64 cols) ----
    f32x4 acc1[2][2];
#pragma unroll
    for (int r = 0; r < 2; ++r)
#pragma unroll
        for (int c = 0; c < 2; ++c) acc1[r][c] = (f32x4){0.f, 0.f, 0.f, 0.f};
#pragma unroll
    for (int kp = 0; kp < 2; ++kp) {
        bf16x8 ah[2], al[2], bh[2], bl[2];
#pragma unroll
        for (int r = 0; r < 2; ++r) {
            long row = rowbase + wr * 32 + r * 16 + lrow; if (row >= NE) row = NE - 1;
            long ba = row * 64 + kp * 32 + quad * 8;
            ah[r] = *(const bf16x8*)(eh + ba);
            al[r] = *(const bf16x8*)(el + ba);
        }
#pragma unroll
        for (int c = 0; c < 2; ++c) {
            bh[c] = *(const bf16x8*)&r1.b1.h[wc * 32 + c * 16 + lrow][kp * 32 + quad * 8];
            bl[c] = *(const bf16x8*)&r1.b1.l[wc * 32 + c * 16 + lrow][kp * 32 + quad * 8];
        }
#pragma unroll
        for (int r = 0; r < 2; ++r)
#pragma unroll
            for (int c = 0; c < 2; ++c) {
                acc1[r][c] = __builtin_amdgcn_mfma_f32_16x16x32_bf16(ah[r], bh[c], acc1[r][c], 0, 0, 0);
                acc1[r][c] = __builtin_amdgcn_mfma_f32_16x16x32_bf16(ah[r], bl[c], acc1[r][c], 0, 0, 0);
                acc1[r][c] = __builtin_amdgcn_mfma_f32_16x16x32_bf16(al[r], bh[c], acc1[r][c], 0, 0, 0);
            }
    }
    __syncthreads();   // all waves done reading B1 -> R1 reusable as cbuf
    // transpose acc1 -> r1.cb
#pragma unroll
    for (int c = 0; c < 2; ++c)
#pragma unroll
        for (int r = 0; r < 2; ++r)
#pragma unroll
            for (int j = 0; j < 4; ++j)
                r1.cb[wr * 32 + r * 16 + quad * 4 + j][wc * 32 + c * 16 + lrow] = acc1[r][c][j];
    __syncthreads();
    // edge epilogue: e' = relu(cb + u1[src] + u2[dst]) -> r3 bf16 split planes
    {
        const int row = tid >> 2, q = tid & 3;
        const float* pu1 = uu + (long)s_sp[row] * 128 + q * 16;
        const float* pu2 = uu + (long)s_dp[row] * 128 + 64 + q * 16;
        const float* pc = &r1.cb[row][q * 16];
        u16x8 hv0, lv0, hv1, lv1;
#pragma unroll
        for (int half = 0; half < 2; ++half) {
            float4 a0 = *(const float4*)(pu1 + half * 8);
            float4 a1 = *(const float4*)(pu1 + half * 8 + 4);
            float4 b0 = *(const float4*)(pu2 + half * 8);
            float4 b1 = *(const float4*)(pu2 + half * 8 + 4);
            float s[8] = {a0.x + b0.x, a0.y + b0.y, a0.z + b0.z, a0.w + b0.w,
                          a1.x + b1.x, a1.y + b1.y, a1.z + b1.z, a1.w + b1.w};
            u16x8 hv, lv;
#pragma unroll
            for (int k = 0; k < 8; ++k) {
                float v = relu_f(pc[half * 8 + k] + s[k]);
                u16 h = f2bf(v);
                hv[k] = h;
                lv[k] = f2bf(v - bf2f(h));
            }
            if (half == 0) { hv0 = hv; lv0 = lv; } else { hv1 = hv; lv1 = lv; }
        }
        *(u16x8*)&r3.h[row][q * 16]     = hv0;
        *(u16x8*)&r3.h[row][q * 16 + 8] = hv1;
        *(u16x8*)&r3.l[row][q * 16]     = lv0;
        *(u16x8*)&r3.l[row][q * 16 + 8] = lv1;
    }
    __syncthreads();
    // ---- per col-half of the message GEMM: B2 direct from L2, MFMA-2, msg epilogue ----
    const int col = tid & 63, seg = tid >> 6;
    // per-lane B2 base: row (wc*32 + lrow), k offset 128 + quad*8
    const u16* pB2h = B2th + (long)(wc * 32 + lrow) * 192 + 128 + quad * 8;
    const u16* pB2l = B2tl + (long)(wc * 32 + lrow) * 192 + 128 + quad * 8;
    for (int p = 0; p < 2; ++p) {
        f32x4 acc2[2][2];
#pragma unroll
        for (int r = 0; r < 2; ++r)
#pragma unroll
            for (int c = 0; c < 2; ++c) acc2[r][c] = (f32x4){0.f, 0.f, 0.f, 0.f};
#pragma unroll
        for (int kp = 0; kp < 2; ++kp) {
            bf16x8 ah[2], al[2], bh[2], bl[2];
#pragma unroll
            for (int r = 0; r < 2; ++r) {
                ah[r] = *(const bf16x8*)&r3.h[wr * 32 + r * 16 + lrow][kp * 32 + quad * 8];
                al[r] = *(const bf16x8*)&r3.l[wr * 32 + r * 16 + lrow][kp * 32 + quad * 8];
            }
#pragma unroll
            for (int c = 0; c < 2; ++c) {
                long off = (long)(p * 64 + c * 16) * 192 + kp * 32;
                bh[c] = *(const bf16x8*)(pB2h + off);
                bl[c] = *(const bf16x8*)(pB2l + off);
            }
#pragma unroll
            for (int r = 0; r < 2; ++r)
#pragma unroll
                for (int c = 0; c < 2; ++c) {
                    acc2[r][c] = __builtin_amdgcn_mfma_f32_16x16x32_bf16(ah[r], bh[c], acc2[r][c], 0, 0, 0);
                    acc2[r][c] = __builtin_amdgcn_mfma_f32_16x16x32_bf16(ah[r], bl[c], acc2[r][c], 0, 0, 0);
                    acc2[r][c] = __builtin_amdgcn_mfma_f32_16x16x32_bf16(al[r], bh[c], acc2[r][c], 0, 0, 0);
                }
        }
        // phase A: acc2 -> r1.cb
#pragma unroll
        for (int c = 0; c < 2; ++c)
#pragma unroll
            for (int r = 0; r < 2; ++r)
#pragma unroll
                for (int j = 0; j < 4; ++j)
                    r1.cb[wr * 32 + r * 16 + quad * 4 + j][wc * 32 + c * 16 + lrow] = acc2[r][c][j];
        __syncthreads();
        // phase B: y add + relu
        {
            int row = tid >> 2, q = tid & 3;
            const float* py = y + (long)s_sp[row] * 128 + p * 64 + q * 16;
            float* pc = &r1.cb[row][q * 16];
#pragma unroll
            for (int g = 0; g < 4; ++g) {
                float4 yv = *(const float4*)(py + g * 4);
                pc[g * 4 + 0] = relu_f(pc[g * 4 + 0] + yv.x);
                pc[g * 4 + 1] = relu_f(pc[g * 4 + 1] + yv.y);
                pc[g * 4 + 2] = relu_f(pc[g * 4 + 2] + yv.z);
                pc[g * 4 + 3] = relu_f(pc[g * 4 + 3] + yv.w);
            }
        }
        __syncthreads();
        // phase C: run-scan over dst-runs, atomic flush (ghost rows masked)
        {
            int cur = -1; float sum = 0.0f;
            for (int rr = seg * 16; rr < seg * 16 + 16; ++rr) {
                int d = (rowbase + rr < NE) ? s_dp[rr] : -1;
                if (d != cur) {
                    if (cur >= 0) atomicAdd(&agg[(long)cur * 128 + p * 64 + col], sum);
                    cur = d; sum = 0.0f;
                }
                sum += r1.cb[rr][col];
            }
            if (cur >= 0) atomicAdd(&agg[(long)cur * 128 + p * 64 + col], sum);
        }
        __syncthreads();
    }
}

// ================= node update GEMM (MFMA, split bf16, fused L2-norm) =================
__global__ __launch_bounds__(256) void k_update_mfma(
    float* __restrict__ agg, const float* __restrict__ icnt,
    u16* __restrict__ xh, u16* __restrict__ xl,
    const u16* __restrict__ Bth, const u16* __restrict__ Btl,
    const float* __restrict__ bias, int zero_agg)
{
    __shared__ u16 Ah[64][40], Al[64][40], Bh[128][40], Bl[128][40];
    __shared__ float s_ic[64];
    __shared__ float sP[64][2];
    const int tid = threadIdx.x;
    const long rowbase = (long)blockIdx.x * 64;
    if (tid < 64) {
        long r = rowbase + tid;
        int rr = (r < NN) ? (int)r : (NN - 1);
        s_ic[tid] = icnt[rr];
    }
    __syncthreads();
    const int wave = tid >> 6, lane = tid & 63;
    const int quad = lane >> 4, lrow = lane & 15;
    const int wr = wave >> 1, wc = wave & 1;
    const int arow = tid >> 2, akh = (tid & 3) * 8;
    const int brow = tid >> 1, bkh = (tid & 1) << 4;

    f32x4 acc[2][4];
#pragma unroll
    for (int r = 0; r < 2; ++r)
#pragma unroll
        for (int c = 0; c < 4; ++c) acc[r][c] = (f32x4){0.f, 0.f, 0.f, 0.f};

    for (int kp = 0; kp < 8; ++kp) {
        const int k0 = kp * 32;
        if (k0 < 128) {
            long r = rowbase + arow;
            const bool own = (r < NN);
            if (!own) r = NN - 1;
            float* pa = agg + r * 128 + k0 + akh;
            float ic = s_ic[arow];
#pragma unroll
            for (int q = 0; q < 8; q += 4) {
                float4 f = *(const float4*)(pa + q);
                float vv[4] = {f.x, f.y, f.z, f.w};
#pragma unroll
                for (int j = 0; j < 4; ++j) {
                    float v = vv[j] * ic;
                    u16 h = f2bf(v);
                    Ah[arow][akh + q + j] = h;
                    Al[arow][akh + q + j] = f2bf(v - bf2f(h));
                }
            }
            if (zero_agg && own) {
                float4 z = {0.f, 0.f, 0.f, 0.f};
                *(float4*)(pa + 0) = z;
                *(float4*)(pa + 4) = z;
            }
        } else {
            long r = rowbase + arow; if (r >= NN) r = NN - 1;
            long b = r * 128 + (k0 - 128 + akh);
            *(int4*)&Ah[arow][akh] = *(const int4*)(xh + b);
            *(int4*)&Al[arow][akh] = *(const int4*)(xl + b);
        }
        {
            long b = (long)brow * 256 + k0 + bkh;
            *(int4*)&Bh[brow][bkh]     = *(const int4*)(Bth + b);
            *(int4*)&Bh[brow][bkh + 8] = *(const int4*)(Bth + b + 8);
            *(int4*)&Bl[brow][bkh]     = *(const int4*)(Btl + b);
            *(int4*)&Bl[brow][bkh + 8] = *(const int4*)(Btl + b + 8);
        }
        __syncthreads();
        bf16x8 ah[2], al[2], bh[4], bl[4];
#pragma unroll
        for (int r = 0; r < 2; ++r) {
            ah[r] = *(const bf16x8*)&Ah[wr * 32 + r * 16 + lrow][quad * 8];
            al[r] = *(const bf16x8*)&Al[wr * 32 + r * 16 + lrow][quad * 8];
        }
#pragma unroll
        for (int c = 0; c < 4; ++c) {
            bh[c] = *(const bf16x8*)&Bh[wc * 64 + c * 16 + lrow][quad * 8];
            bl[c] = *(const bf16x8*)&Bl[wc * 64 + c * 16 + lrow][quad * 8];
        }
#pragma unroll
        for (int r = 0; r < 2; ++r)
#pragma unroll
            for (int c = 0; c < 4; ++c) {
                acc[r][c] = __builtin_amdgcn_mfma_f32_16x16x32_bf16(ah[r], bh[c], acc[r][c], 0, 0, 0);
                acc[r][c] = __builtin_amdgcn_mfma_f32_16x16x32_bf16(ah[r], bl[c], acc[r][c], 0, 0, 0);
                acc[r][c] = __builtin_amdgcn_mfma_f32_16x16x32_bf16(al[r], bh[c], acc[r][c], 0, 0, 0);
            }
        __syncthreads();
    }
#pragma unroll
    for (int r = 0; r < 2; ++r)
#pragma unroll
        for (int c = 0; c < 4; ++c)
#pragma unroll
            for (int j = 0; j < 4; ++j)
                acc[r][c][j] = relu_f(acc[r][c][j] + bias[wc * 64 + c * 16 + lrow]);
#pragma unroll
    for (int r = 0; r < 2; ++r)
#pragma unroll
        for (int j = 0; j < 4; ++j) {
            float s2 = 0.0f;
#pragma unroll
            for (int c = 0; c < 4; ++c) { float v = acc[r][c][j]; s2 += v * v; }
#pragma unroll
            for (int m = 1; m < 16; m <<= 1) s2 += __shfl_xor(s2, m, 64);
            if (lrow == 0) sP[wr * 32 + r * 16 + quad * 4 + j][wc] = s2;
        }
    __syncthreads();
#pragma unroll
    for (int r = 0; r < 2; ++r)
#pragma unroll
        for (int j = 0; j < 4; ++j) {
            int lr = wr * 32 + r * 16 + quad * 4 + j;
            long grow = rowbase + lr;
            if (grow < NN) {
                float tot = sP[lr][0] + sP[lr][1];
                float rn = 1.0f / fmaxf(sqrtf(tot), 1e-12f);
#pragma unroll
                for (int c = 0; c < 4; ++c) {
                    float v = acc[r][c][j] * rn;
                    long o = grow * 128 + wc * 64 + c * 16 + lrow;
                    u16 h = f2bf(v);
                    xh[o] = h;
                    xl[o] = f2bf(v - bf2f(h));
                }
            }
        }
}

// ================= edge update (layer 0 only): e' = relu(u1[src]+u2[dst]+e@We3) =================
__global__ __launch_bounds__(256, 4) void k_edge2(
    u16* __restrict__ eh, u16* __restrict__ el,
    const int* __restrict__ sp, const int* __restrict__ dp,
    const u16* __restrict__ Bth, const u16* __restrict__ Btl,
    const float* __restrict__ uu)
{
    __shared__ union {
        struct { u16 Bh[64][72]; u16 Bl[64][72]; } b;
        float cbuf[128][66];
    } u;
    __shared__ int s_sp[128], s_dp[128];
    const int tid = threadIdx.x;
    const long rowbase = (long)blockIdx.x * 128;
    if (tid < 128) {
        long r = rowbase + tid;
        int rr = (r < NE) ? (int)r : (NE - 1);
        s_sp[tid] = sp[rr];
        s_dp[tid] = dp[rr];
    }
    {
        int colb = tid >> 2, kh = (tid & 3) * 16;
        long bb = (long)colb * 320 + 256 + kh;
        *(int4*)&u.b.Bh[colb][kh]     = *(const int4*)(Bth + bb);
        *(int4*)&u.b.Bh[colb][kh + 8] = *(const int4*)(Bth + bb + 8);
        *(int4*)&u.b.Bl[colb][kh]     = *(const int4*)(Btl + bb);
        *(int4*)&u.b.Bl[colb][kh + 8] = *(const int4*)(Btl + bb + 8);
    }
    __syncthreads();
    const int wave = tid >> 6, lane = tid & 63;
    const int quad = lane >> 4, lrow = lane & 15;

    f32x4 acc[2][4];
#pragma unroll
    for (int r = 0; r < 2; ++r)
#pragma unroll
        for (int c = 0; c < 4; ++c) acc[r][c] = (f32x4){0.f, 0.f, 0.f, 0.f};

#pragma unroll
    for (int kp = 0; kp < 2; ++kp) {
        bf16x8 ah[2], al[2], bh[4], bl[4];
#pragma unroll
        for (int r = 0; r < 2; ++r) {
            long row = rowbase + wave * 32 + r * 16 + lrow; if (row >= NE) row = NE - 1;
            long ba = row * 64 + kp * 32 + quad * 8;
            ah[r] = *(const bf16x8*)(eh + ba);
            al[r] = *(const bf16x8*)(el + ba);
        }
#pragma unroll
        for (int c = 0; c < 4; ++c) {
            bh[c] = *(const bf16x8*)&u.b.Bh[c * 16 + lrow][kp * 32 + quad * 8];
            bl[c] = *(const bf16x8*)&u.b.Bl[c * 16 + lrow][kp * 32 + quad * 8];
        }
#pragma unroll
        for (int r = 0; r < 2; ++r)
#pragma unroll
            for (int c = 0; c < 4; ++c) {
                acc[r][c] = __builtin_amdgcn_mfma_f32_16x16x32_bf16(ah[r], bh[c], acc[r][c], 0, 0, 0);
                acc[r][c] = __builtin_amdgcn_mfma_f32_16x16x32_bf16(ah[r], bl[c], acc[r][c], 0, 0, 0);
                acc[r][c] = __builtin_amdgcn_mfma_f32_16x16x32_bf16(al[r], bh[c], acc[r][c], 0, 0, 0);
            }
    }
    __syncthreads();
#pragma unroll
    for (int c = 0; c < 4; ++c)
#pragma unroll
        for (int r = 0; r < 2; ++r)
#pragma unroll
            for (int j = 0; j < 4; ++j)
                u.cbuf[wave * 32 + r * 16 + quad * 4 + j][c * 16 + lrow] = acc[r][c][j];
    __syncthreads();
    {
        const int row = tid >> 1, half = tid & 1;
        const long grow = rowbase + row;
        if (grow < NE) {
            const float* pu1 = uu + (long)s_sp[row] * 128 + half * 32;
            const float* pu2 = uu + (long)s_dp[row] * 128 + 64 + half * 32;
            const long o = grow * 64 + half * 32;
#pragma unroll
            for (int g = 0; g < 4; ++g) {
                float4 a0 = *(const float4*)(pu1 + g * 8);
                float4 a1 = *(const float4*)(pu1 + g * 8 + 4);
                float4 b0 = *(const float4*)(pu2 + g * 8);
                float4 b1 = *(const float4*)(pu2 + g * 8 + 4);
                float s[8] = {a0.x + b0.x, a0.y + b0.y, a0.z + b0.z, a0.w + b0.w,
                              a1.x + b1.x, a1.y + b1.y, a1.z + b1.z, a1.w + b1.w};
                u16x8 hv, lv;
#pragma unroll
                for (int k = 0; k < 8; ++k) {
                    float v = relu_f(u.cbuf[row][half * 32 + g * 8 + k] + s[k]);
                    u16 h = f2bf(v);
                    hv[k] = h;
                    lv[k] = f2bf(v - bf2f(h));
                }
                *(u16x8*)(eh + o + g * 8) = hv;
                *(u16x8*)(el + o + g * 8) = lv;
            }
        }
    }
}

// ---------------- fused MLP head: out = relu(x@W1+b1)@W2+b2 ----------------
__global__ __launch_bounds__(256) void k_head(
    const u16* __restrict__ xh, const u16* __restrict__ xl,
    const float* __restrict__ W1, const float* __restrict__ b1,
    const float* __restrict__ W2, const float* __restrict__ b2,
    float* __restrict__ out)
{
    constexpr int KC = 64, NP = 2, EB = 32;
    __shared__ __align__(16) float At[KC][EB + 4];
    __shared__ __align__(16) union { float W1s[KC][64]; float W2s[KC][128]; } w;
    const int tid = threadIdx.x;
    const int rowbase = blockIdx.x * EB;
    const int wave = tid >> 6, lane = tid & 63;
    float acc[8];
#pragma unroll
    for (int i = 0; i < 8; ++i) acc[i] = 0.0f;

    for (int kp = 0; kp < NP; ++kp) {
        const int k0 = kp * KC;
        for (int i = tid; i < KC * EB; i += 256) {
            int e = i >> 6, kk = i & 63, k = k0 + kk;
            int r = min(rowbase + e, NN - 1);
            long b = (long)r * 128 + k;
            At[kk][e] = bf2f(xh[b]) + bf2f(xl[b]);
        }
        for (int i = tid; i < KC * 64; i += 256) {
            int kk = i >> 6, cc = i & 63;
            w.W1s[kk][cc] = W1[(size_t)(k0 + kk) * 64 + cc];
        }
        __syncthreads();
#pragma unroll 4
        for (int kk = 0; kk < KC; ++kk) {
            const float* ar = &At[kk][wave * 8];
            float4 a0 = *(const float4*)ar;
            float4 a1 = *(const float4*)(ar + 4);
            float wv = w.W1s[kk][lane];
            acc[0] += a0.x * wv; acc[1] += a0.y * wv; acc[2] += a0.z * wv; acc[3] += a0.w * wv;
            acc[4] += a1.x * wv; acc[5] += a1.y * wv; acc[6] += a1.z * wv; acc[7] += a1.w * wv;
        }
        __syncthreads();
    }
    {
        const float bv = b1[lane];
#pragma unroll
        for (int j = 0; j < 8; ++j)
            At[lane][wave * 8 + j] = relu_f(acc[j] + bv);
    }
    for (int i = tid; i < KC * 128; i += 256) {
        int kk = i >> 7, cc = i & 127;
        w.W2s[kk][cc] = W2[(size_t)kk * 128 + cc];
    }
    __syncthreads();
    float a2[16];
#pragma unroll
    for (int i = 0; i < 16; ++i) a2[i] = 0.0f;
#pragma unroll 4
    for (int kk = 0; kk < KC; ++kk) {
        const float* ar = &At[kk][wave * 8];
        float4 a0 = *(const float4*)ar;
        float4 a1 = *(const float4*)(ar + 4);
        float w0 = w.W2s[kk][lane], w1 = w.W2s[kk][64 + lane];
        a2[0] += a0.x * w0;  a2[1] += a0.y * w0;  a2[2] += a0.z * w0;  a2[3] += a0.w * w0;
        a2[4] += a1.x * w0;  a2[5] += a1.y * w0;  a2[6] += a1.z * w0;  a2[7] += a1.w * w0;
        a2[8] += a0.x * w1;  a2[9] += a0.y * w1;  a2[10] += a0.z * w1; a2[11] += a0.w * w1;
        a2[12] += a1.x * w1; a2[13] += a1.y * w1; a2[14] += a1.z * w1; a2[15] += a1.w * w1;
    }
    const float o0 = b2[lane], o1 = b2[64 + lane];
#pragma unroll
    for (int j = 0; j < 8; ++j) {
        int r = rowbase + wave * 8 + j;
        if (r < NN) {
            out[(size_t)r * 128 + lane] = a2[j] + o0;
            out[(size_t)r * 128 + 64 + lane] = a2[8 + j] + o1;
        }
    }
}

// ---------------- host-side launch ----------------
extern "C" void kernel_launch(void* const* d_in, const int* in_sizes, int n_in,
                              void* d_out, int out_size, void* d_ws, size_t ws_size,
                              hipStream_t stream) {
    const float* d_x  = (const float*)d_in[0];
    const float* d_ea = (const float*)d_in[1];
    const int*   d_ei = (const int*)d_in[2];
    const float* Wm   = (const float*)d_in[3];
    const float* bm   = (const float*)d_in[4];
    const float* Wa   = (const float*)d_in[5];
    const float* ba   = (const float*)d_in[6];
    const float* We   = (const float*)d_in[7];
    const float* be   = (const float*)d_in[8];
    const float* W1   = (const float*)d_in[9];
    const float* b1   = (const float*)d_in[10];
    const float* W2   = (const float*)d_in[11];
    const float* b2   = (const float*)d_in[12];
    float* out = (float*)d_out;

    const int* src = d_ei;
    const int* dst = d_ei + NE;

    char* p = (char*)d_ws;
    auto alloc = [&](size_t bytes) { char* q = p; p += (bytes + 255) & ~(size_t)255; return q; };
    u16* xh  = (u16*)alloc((size_t)NN * 128 * 2);
    u16* xl  = (u16*)alloc((size_t)NN * 128 * 2);
    u16* ehb = (u16*)alloc((size_t)NE * 64 * 2);
    u16* elb = (u16*)alloc((size_t)NE * 64 * 2);
    float* agg = (float*)alloc((size_t)NN * 128 * 4);
    float* yu  = (float*)alloc((size_t)NN * 128 * 4);   // y (and u for layer 0)
    float* ubuf = (float*)alloc((size_t)NN * 128 * 4);  // u for layer 1 (coexists with y2)
    float* cnt = (float*)alloc((size_t)NN * 4);
    float* zbuf = (float*)alloc(64 * 4);
    u16* Wmt_h = (u16*)alloc((size_t)3 * 192 * 128 * 2);
    u16* Wmt_l = (u16*)alloc((size_t)3 * 192 * 128 * 2);
    u16* Wat_h = (u16*)alloc((size_t)3 * 256 * 128 * 2);
    u16* Wat_l = (u16*)alloc((size_t)3 * 256 * 128 * 2);
    u16* Wet_h = (u16*)alloc((size_t)3 * 320 * 64 * 2);
    u16* Wet_l = (u16*)alloc((size_t)3 * 320 * 64 * 2);
    u16* Wxt_h = (u16*)alloc((size_t)3 * 128 * 128 * 2);
    u16* Wxt_l = (u16*)alloc((size_t)3 * 128 * 128 * 2);
    int* hist   = (int*)alloc((size_t)NN * 4);
    int* excl   = (int*)alloc((size_t)NN * 4);
    int* bsum   = (int*)alloc(128 * 4);
    int* cursor = (int*)alloc((size_t)NN * 4);
    int* perm   = (int*)alloc((size_t)NE * 4);
    int* sp     = (int*)alloc((size_t)NE * 4);
    int* dp     = (int*)alloc((size_t)NE * 4);

    const int NB1 = (NN + 511) / 512;

    hipMemsetAsync(hist, 0, NN * sizeof(int), stream);
    k_hist<<<(NE + 255) / 256, 256, 0, stream>>>(dst, hist);
    k_scan1<<<NB1, 512, 0, stream>>>(hist, excl, bsum, cnt);
    k_scan2<<<1, 128, 0, stream>>>(bsum, NB1);
    k_scan3<<<NB1, 512, 0, stream>>>(excl, bsum, cursor);
    k_scatter<<<(NE + 255) / 256, 256, 0, stream>>>(dst, cursor, perm);

    k_split_all<<<(XQ + NE * 16 + 255) / 256, 256, 0, stream>>>(
        d_x, xh, xl, d_ea, perm, ehb, elb, src, dst, sp, dp);
    k_wtall<<<(245824 + 255) / 256, 256, 0, stream>>>(
        Wm, Wa, We, Wmt_h, Wmt_l, Wat_h, Wat_l, Wet_h, Wet_l, Wxt_h, Wxt_l, zbuf);

    hipMemsetAsync(agg, 0, (size_t)NN * 128 * sizeof(float), stream);   // layer-0 only

    const int NGB = (NN + 63) / 64;
    // ---- layer 0 ----
    k_ngemm<<<NGB, 256, 0, stream>>>(xh, xl, Wmt_h, Wmt_l, 192, bm, bm + 64, yu);
    k_msg2<<<(NE + 63) / 64, 256, 0, stream>>>(ehb, elb, sp, dp, Wmt_h, Wmt_l, yu, agg);
    k_update_mfma<<<NGB, 256, 0, stream>>>(agg, cnt, xh, xl, Wat_h, Wat_l, ba, 1);
    k_ngemm<<<NGB, 256, 0, stream>>>(xh, xl, Wxt_h, Wxt_l, 128, be, zbuf, yu);
    k_edge2<<<(NE + 127) / 128, 256, 0, stream>>>(ehb, elb, sp, dp, Wet_h, Wet_l, yu);
    // ---- layer 1 (edge update deferred into fused layer-2 kernel) ----
    k_ngemm<<<NGB, 256, 0, stream>>>(xh, xl,
        Wmt_h + (size_t)1 * 192 * 128, Wmt_l + (size_t)1 * 192 * 128, 192,
        bm + 128, bm + 128 + 64, yu);
    k_msg2<<<(NE + 63) / 64, 256, 0, stream>>>(ehb, elb, sp, dp,
        Wmt_h + (size_t)1 * 192 * 128, Wmt_l + (size_t)1 * 192 * 128, yu, agg);
    k_update_mfma<<<NGB, 256, 0, stream>>>(agg, cnt, xh, xl,
        Wat_h + (size_t)1 * 256 * 128, Wat_l + (size_t)1 * 256 * 128, ba + 128, 1);
    k_ngemm<<<NGB, 256, 0, stream>>>(xh, xl,
        Wxt_h + (size_t)1 * 128 * 128, Wxt_l + (size_t)1 * 128 * 128, 128,
        be + 64, zbuf, ubuf);
    // ---- layer 2 (fused edge(1)+msg(2)) ----
    k_ngemm<<<NGB, 256, 0, stream>>>(xh, xl,
        Wmt_h + (size_t)2 * 192 * 128, Wmt_l + (size_t)2 * 192 * 128, 192,
        bm + 256, bm + 256 + 64, yu);
    k_msg2e<<<(NE + 63) / 64, 256, 0, stream>>>(ehb, elb, sp, dp,
        Wet_h + (size_t)1 * 320 * 64, Wet_l + (size_t)1 * 320 * 64,
        Wmt_h + (size_t)2 * 192 * 128, Wmt_l + (size_t)2 * 192 * 128,
        ubuf, yu, agg);
    k_update_mfma<<<NGB, 256, 0, stream>>>(agg, cnt, xh, xl,
        Wat_h + (size_t)2 * 256 * 128, Wat_l + (size_t)2 * 256 * 128, ba + 256, 0);

    k_head<<<(NN + 31) / 32, 256, 0, stream>>>(xh, xl, W1, b1, W2, b2, out);
}

// Round 12
// 900.371 us; speedup vs baseline: 1.2357x; 1.0340x over previous
//
#include <hip/hip_runtime.h>
#include <cstdint>
#include <cstddef>

#define NN 50000
#define NE 500000
#define XQ (NN * 128 / 4)

typedef unsigned short u16;
typedef __attribute__((ext_vector_type(8))) short bf16x8;
typedef __attribute__((ext_vector_type(4))) float f32x4;
typedef __attribute__((ext_vector_type(4))) unsigned short u16x4;
typedef __attribute__((ext_vector_type(8))) unsigned short u16x8;

__device__ __forceinline__ float relu_f(float v) { return fmaxf(v, 0.0f); }

__device__ __forceinline__ u16 f2bf(float f) {
    union { float f; unsigned u; } c; c.f = f;
    unsigned u = c.u;
    unsigned r = u + 0x7FFFu + ((u >> 16) & 1u);
    return (u16)(r >> 16);
}
__device__ __forceinline__ float bf2f(u16 h) {
    union { unsigned u; float f; } c; c.u = ((unsigned)h) << 16;
    return c.f;
}

// ---------------- counting sort of edges by dst ----------------
__global__ __launch_bounds__(256) void k_hist(const int* __restrict__ dst, int* __restrict__ h) {
    int e = blockIdx.x * 256 + threadIdx.x;
    if (e < NE) atomicAdd(&h[dst[e]], 1);
}

// prefix-scan of hist; also emits cnt = 1/max(hist,1)
__global__ __launch_bounds__(512) void k_scan1(const int* __restrict__ h,
                                               int* __restrict__ excl, int* __restrict__ bsum,
                                               float* __restrict__ cnt) {
    __shared__ int s[512];
    int tid = threadIdx.x;
    int i = blockIdx.x * 512 + tid;
    int v = (i < NN) ? h[i] : 0;
    if (i < NN) cnt[i] = 1.0f / fmaxf((float)v, 1.0f);
    s[tid] = v;
    __syncthreads();
    for (int off = 1; off < 512; off <<= 1) {
        int t = (tid >= off) ? s[tid - off] : 0;
        __syncthreads();
        s[tid] += t;
        __syncthreads();
    }
    if (i < NN) excl[i] = s[tid] - v;
    if (tid == 511) bsum[blockIdx.x] = s[511];
}

__global__ __launch_bounds__(128) void k_scan2(int* __restrict__ bsum, int nb) {
    __shared__ int s[128];
    int tid = threadIdx.x;
    int v = (tid < nb) ? bsum[tid] : 0;
    s[tid] = v;
    __syncthreads();
    for (int off = 1; off < 128; off <<= 1) {
        int t = (tid >= off) ? s[tid - off] : 0;
        __syncthreads();
        s[tid] += t;
        __syncthreads();
    }
    if (tid < nb) bsum[tid] = s[tid] - v;
}

__global__ __launch_bounds__(512) void k_scan3(const int* __restrict__ excl, const int* __restrict__ bsum,
                                               int* __restrict__ cursor) {
    int i = blockIdx.x * 512 + threadIdx.x;
    if (i < NN) cursor[i] = excl[i] + bsum[blockIdx.x];
}

__global__ __launch_bounds__(256) void k_scatter(const int* __restrict__ dst,
                                                 int* __restrict__ cursor, int* __restrict__ perm) {
    int e = blockIdx.x * 256 + threadIdx.x;
    if (e < NE) {
        int pos = atomicAdd(&cursor[dst[e]], 1);
        perm[pos] = e;
    }
}

// ---------------- merged split kernel: x-split + permuted e-split + sp/dp ----------------
__global__ __launch_bounds__(256) void k_split_all(
    const float* __restrict__ x, u16* __restrict__ xh, u16* __restrict__ xl,
    const float* __restrict__ e, const int* __restrict__ perm,
    u16* __restrict__ eh, u16* __restrict__ el,
    const int* __restrict__ src, const int* __restrict__ dst,
    int* __restrict__ sp, int* __restrict__ dp)
{
    long t = (long)blockIdx.x * 256 + threadIdx.x;
    if (t < XQ) {
        float4 v = ((const float4*)x)[t];
        float vv[4] = {v.x, v.y, v.z, v.w};
        u16x4 hv, lv;
#pragma unroll
        for (int j = 0; j < 4; ++j) {
            u16 h = f2bf(vv[j]);
            hv[j] = h;
            lv[j] = f2bf(vv[j] - bf2f(h));
        }
        ((u16x4*)xh)[t] = hv;
        ((u16x4*)xl)[t] = lv;
    } else {
        long g = t - XQ;
        int i = (int)(g >> 4), c4 = ((int)g & 15) << 2;
        if (i < NE) {
            int pe = perm[i];
            if ((g & 15) == 0) { sp[i] = src[pe]; dp[i] = dst[pe]; }
            float4 v = *(const float4*)(e + (long)pe * 64 + c4);
            float vv[4] = {v.x, v.y, v.z, v.w};
            u16x4 hv, lv;
#pragma unroll
            for (int j = 0; j < 4; ++j) {
                u16 h = f2bf(vv[j]);
                hv[j] = h;
                lv[j] = f2bf(vv[j] - bf2f(h));
            }
            long o = (long)i * 64 + c4;
            *(u16x4*)(eh + o) = hv;
            *(u16x4*)(el + o) = lv;
        }
    }
}

// ---------------- batched weight transposes (all layers, all W) + zbuf zero ----------------
__global__ __launch_bounds__(256) void k_wtall(
    const float* __restrict__ Wm, const float* __restrict__ Wa, const float* __restrict__ We,
    u16* __restrict__ Wmt_h, u16* __restrict__ Wmt_l,
    u16* __restrict__ Wat_h, u16* __restrict__ Wat_l,
    u16* __restrict__ Wet_h, u16* __restrict__ Wet_l,
    u16* __restrict__ Wxt_h, u16* __restrict__ Wxt_l,
    float* __restrict__ zbuf)
{
    int i = blockIdx.x * 256 + threadIdx.x;
    float v; u16* th; u16* tl; int oi;
    if (i < 73728) {
        int l = i / 24576, j = i % 24576;
        int n = j / 192, k = j - n * 192;
        v = Wm[(size_t)l * 24576 + (size_t)k * 128 + n];
        th = Wmt_h; tl = Wmt_l; oi = i;
    } else if ((i -= 73728) < 98304) {
        int l = i / 32768, j = i % 32768;
        int n = j / 256, k = j - n * 256;
        v = Wa[(size_t)l * 32768 + (size_t)k * 128 + n];
        th = Wat_h; tl = Wat_l; oi = i;
    } else if ((i -= 98304) < 40960) {
        int l = i / 20480, j = i % 20480;
        int n = j / 320, k = j - n * 320;
        v = We[(size_t)l * 20480 + (size_t)k * 64 + n];
        th = Wet_h; tl = Wet_l; oi = i;
    } else if ((i -= 40960) < 32768) {
        int l = i / 16384, j2 = i % 16384;
        int jj = j2 >> 7, k = j2 & 127;
        v = We[(size_t)l * 20480 + (size_t)(k + ((jj >> 6) << 7)) * 64 + (jj & 63)];
        th = Wxt_h; tl = Wxt_l; oi = i;
    } else if ((i -= 32768) < 64) {
        zbuf[i] = 0.0f;
        return;
    } else {
        return;
    }
    u16 h = f2bf(v);
    th[oi] = h;
    tl[oi] = f2bf(v - bf2f(h));
}

// ================= node GEMM: C = x @ B + bias (fp32 out, no relu) =================
__global__ __launch_bounds__(256) void k_ngemm(
    const u16* __restrict__ xh, const u16* __restrict__ xl,
    const u16* __restrict__ Bth, const u16* __restrict__ Btl, int bstride,
    const float* __restrict__ bias0, const float* __restrict__ bias1,
    float* __restrict__ C)
{
    __shared__ u16 Ah[64][40], Al[64][40], Bh[128][40], Bl[128][40];
    const int tid = threadIdx.x;
    const long rowbase = (long)blockIdx.x * 64;
    const int wave = tid >> 6, lane = tid & 63;
    const int quad = lane >> 4, lrow = lane & 15;
    const int wr = wave >> 1, wc = wave & 1;
    const int arow = tid >> 2, akh = (tid & 3) * 8;
    const int brow = tid >> 1, bkh = (tid & 1) << 4;

    f32x4 acc[2][4];
#pragma unroll
    for (int r = 0; r < 2; ++r)
#pragma unroll
        for (int c = 0; c < 4; ++c) acc[r][c] = (f32x4){0.f, 0.f, 0.f, 0.f};

    for (int kp = 0; kp < 4; ++kp) {
        const int k0 = kp * 32;
        {
            long r = rowbase + arow; if (r >= NN) r = NN - 1;
            long b = r * 128 + k0 + akh;
            *(int4*)&Ah[arow][akh] = *(const int4*)(xh + b);
            *(int4*)&Al[arow][akh] = *(const int4*)(xl + b);
        }
        {
            long b = (long)brow * bstride + k0 + bkh;
            *(int4*)&Bh[brow][bkh]     = *(const int4*)(Bth + b);
            *(int4*)&Bh[brow][bkh + 8] = *(const int4*)(Bth + b + 8);
            *(int4*)&Bl[brow][bkh]     = *(const int4*)(Btl + b);
            *(int4*)&Bl[brow][bkh + 8] = *(const int4*)(Btl + b + 8);
        }
        __syncthreads();
        bf16x8 ah[2], al[2], bh[4], bl[4];
#pragma unroll
        for (int r = 0; r < 2; ++r) {
            ah[r] = *(const bf16x8*)&Ah[wr * 32 + r * 16 + lrow][quad * 8];
            al[r] = *(const bf16x8*)&Al[wr * 32 + r * 16 + lrow][quad * 8];
        }
#pragma unroll
        for (int c = 0; c < 4; ++c) {
            bh[c] = *(const bf16x8*)&Bh[wc * 64 + c * 16 + lrow][quad * 8];
            bl[c] = *(const bf16x8*)&Bl[wc * 64 + c * 16 + lrow][quad * 8];
        }
#pragma unroll
        for (int r = 0; r < 2; ++r)
#pragma unroll
            for (int c = 0; c < 4; ++c) {
                acc[r][c] = __builtin_amdgcn_mfma_f32_16x16x32_bf16(ah[r], bh[c], acc[r][c], 0, 0, 0);
                acc[r][c] = __builtin_amdgcn_mfma_f32_16x16x32_bf16(ah[r], bl[c], acc[r][c], 0, 0, 0);
                acc[r][c] = __builtin_amdgcn_mfma_f32_16x16x32_bf16(al[r], bh[c], acc[r][c], 0, 0, 0);
            }
        __syncthreads();
    }
#pragma unroll
    for (int c = 0; c < 4; ++c) {
        int colg = wc * 64 + c * 16 + lrow;
        float bv = (colg < 64) ? bias0[colg] : bias1[colg - 64];
#pragma unroll
        for (int r = 0; r < 2; ++r)
#pragma unroll
            for (int j = 0; j < 4; ++j) {
                long grow = rowbase + wr * 32 + r * 16 + quad * 4 + j;
                if (grow < NN) C[grow * 128 + colg] = acc[r][c][j] + bv;
            }
    }
}

// ================= message kernel: m = relu(y[src] + e@Wme); run-scan aggregate =================
__global__ __launch_bounds__(256, 4) void k_msg2(
    const u16* __restrict__ eh, const u16* __restrict__ el,
    const int* __restrict__ sp, const int* __restrict__ dp,
    const u16* __restrict__ Bth, const u16* __restrict__ Btl,
    const float* __restrict__ y,
    float* __restrict__ agg)
{
    __shared__ union {
        struct { u16 Bh[128][72]; u16 Bl[128][72]; } b;
        float cbuf[64][66];
    } u;
    __shared__ int s_sp[64], s_dp[64];
    const int tid = threadIdx.x;
    const long rowbase = (long)blockIdx.x * 64;
    if (tid < 64) {
        long r = rowbase + tid;
        if (r < NE) { s_sp[tid] = sp[r]; s_dp[tid] = dp[r]; }
        else        { s_sp[tid] = 0;     s_dp[tid] = -1;    }
    }
    {
        int colb = tid >> 1, kh = (tid & 1) * 32;
        long bb = (long)colb * 192 + 128 + kh;
#pragma unroll
        for (int q = 0; q < 32; q += 8) {
            *(int4*)&u.b.Bh[colb][kh + q] = *(const int4*)(Bth + bb + q);
            *(int4*)&u.b.Bl[colb][kh + q] = *(const int4*)(Btl + bb + q);
        }
    }
    __syncthreads();
    const int wave = tid >> 6, lane = tid & 63;
    const int quad = lane >> 4, lrow = lane & 15;
    const int wr = wave >> 1, wc = wave & 1;

    f32x4 acc[2][4];
#pragma unroll
    for (int r = 0; r < 2; ++r)
#pragma unroll
        for (int c = 0; c < 4; ++c) acc[r][c] = (f32x4){0.f, 0.f, 0.f, 0.f};

#pragma unroll
    for (int kp = 0; kp < 2; ++kp) {
        bf16x8 ah[2], al[2], bh[4], bl[4];
#pragma unroll
        for (int r = 0; r < 2; ++r) {
            long row = rowbase + wr * 32 + r * 16 + lrow; if (row >= NE) row = NE - 1;
            long ba = row * 64 + kp * 32 + quad * 8;
            ah[r] = *(const bf16x8*)(eh + ba);
            al[r] = *(const bf16x8*)(el + ba);
        }
#pragma unroll
        for (int c = 0; c < 4; ++c) {
            bh[c] = *(const bf16x8*)&u.b.Bh[wc * 64 + c * 16 + lrow][kp * 32 + quad * 8];
            bl[c] = *(const bf16x8*)&u.b.Bl[wc * 64 + c * 16 + lrow][kp * 32 + quad * 8];
        }
#pragma unroll
        for (int r = 0; r < 2; ++r)
#pragma unroll
            for (int c = 0; c < 4; ++c) {
                acc[r][c] = __builtin_amdgcn_mfma_f32_16x16x32_bf16(ah[r], bh[c], acc[r][c], 0, 0, 0);
                acc[r][c] = __builtin_amdgcn_mfma_f32_16x16x32_bf16(ah[r], bl[c], acc[r][c], 0, 0, 0);
                acc[r][c] = __builtin_amdgcn_mfma_f32_16x16x32_bf16(al[r], bh[c], acc[r][c], 0, 0, 0);
            }
    }
    __syncthreads();
    const int col = tid & 63, seg = tid >> 6;
    for (int p = 0; p < 2; ++p) {
        if (wc == p) {
#pragma unroll
            for (int c = 0; c < 4; ++c)
#pragma unroll
                for (int r = 0; r < 2; ++r)
#pragma unroll
                    for (int j = 0; j < 4; ++j)
                        u.cbuf[wr * 32 + r * 16 + quad * 4 + j][c * 16 + lrow] = acc[r][c][j];
        }
        __syncthreads();
        {
            int row = tid >> 2, q = tid & 3;
            const float* py = y + (long)s_sp[row] * 128 + p * 64 + q * 16;
            float* pc = &u.cbuf[row][q * 16];
#pragma unroll
            for (int g = 0; g < 4; ++g) {
                float4 yv = *(const float4*)(py + g * 4);
                pc[g * 4 + 0] = relu_f(pc[g * 4 + 0] + yv.x);
                pc[g * 4 + 1] = relu_f(pc[g * 4 + 1] + yv.y);
                pc[g * 4 + 2] = relu_f(pc[g * 4 + 2] + yv.z);
                pc[g * 4 + 3] = relu_f(pc[g * 4 + 3] + yv.w);
            }
        }
        __syncthreads();
        int cur = -1; float sum = 0.0f;
        for (int rr = seg * 16; rr < seg * 16 + 16; ++rr) {
            int d = s_dp[rr];
            if (d != cur) {
                if (cur >= 0) atomicAdd(&agg[(long)cur * 128 + p * 64 + col], sum);
                cur = d; sum = 0.0f;
            }
            sum += u.cbuf[rr][col];
        }
        if (cur >= 0) atomicAdd(&agg[(long)cur * 128 + p * 64 + col], sum);
        __syncthreads();
    }
}

// ========== fused edge-update + message kernel:
// e' = relu(e@We + u1[src]+u2[dst]) computed in LDS; optionally written back to eh/el
// (write_e=1: used for layer1, materializing e1 for layer2; write_e=0: last layer).
// Then m = relu(y[src] + e'@Wm); run-scan aggregate. B2 read direct from L2 (37.4KB LDS).
__global__ __launch_bounds__(256) void k_msg2e(
    u16* __restrict__ eh, u16* __restrict__ el,
    const int* __restrict__ sp, const int* __restrict__ dp,
    const u16* __restrict__ B1th, const u16* __restrict__ B1tl,  // Wet layer [64][320]; k=256..319
    const u16* __restrict__ B2th, const u16* __restrict__ B2tl,  // Wmt layer [128][192]; k=128..191
    const float* __restrict__ uu,   // [NN][128] = [u1|u2]
    const float* __restrict__ y,    // [NN][128]
    float* __restrict__ agg,
    int write_e)
{
    __shared__ union {                                   // region R1: 18432 B
        struct { u16 h[64][72]; u16 l[64][72]; } b1;     //   We tile (MFMA-1)
        float cb[64][66];                                //   then edge-cbuf, then msg-cbuf
    } r1;
    __shared__ struct { u16 h[64][72]; u16 l[64][72]; } r3;  // e' planes: 18432 B
    __shared__ int s_sp[64], s_dp[64];
    const int tid = threadIdx.x;
    const long rowbase = (long)blockIdx.x * 64;
    if (tid < 64) {
        long r = rowbase + tid;
        int rr = (r < NE) ? (int)r : (NE - 1);
        s_sp[tid] = sp[rr];
        s_dp[tid] = dp[rr];
    }
    // stage B1 (We: 64 cols x K=64)
    {
        int colb = tid >> 2, kh = (tid & 3) * 16;
        long bb = (long)colb * 320 + 256 + kh;
        *(int4*)&r1.b1.h[colb][kh]     = *(const int4*)(B1th + bb);
        *(int4*)&r1.b1.h[colb][kh + 8] = *(const int4*)(B1th + bb + 8);
        *(int4*)&r1.b1.l[colb][kh]     = *(const int4*)(B1tl + bb);
        *(int4*)&r1.b1.l[colb][kh + 8] = *(const int4*)(B1tl + bb + 8);
    }
    __syncthreads();
    const int wave = tid >> 6, lane = tid & 63;
    const int quad = lane >> 4, lrow = lane & 15;
    const int wr = wave >> 1, wc = wave & 1;   // 2x2 wave grid; 32-row x 32-col tiles

    // ---- MFMA-1: e @ We -> acc1 (64 edges x 64 cols) ----
    f32x4 acc1[2][2];
#pragma unroll
    for (int r = 0; r < 2; ++r)
#pragma unroll
        for (int c = 0; c < 2; ++c) acc1[r][c] = (f32x4){0.f, 0.f, 0.f, 0.f};
#pragma unroll
    for (int kp = 0; kp < 2; ++kp) {
        bf16x8 ah[2], al[2], bh[2], bl[2];
#pragma unroll
        for (int r = 0; r < 2; ++r) {
            long row = rowbase + wr * 32 + r * 16 + lrow; if (row >= NE) row = NE - 1;
            long ba = row * 64 + kp * 32 + quad * 8;
            ah[r] = *(const bf16x8*)(eh + ba);
            al[r] = *(const bf16x8*)(el + ba);
        }
#pragma unroll
        for (int c = 0; c < 2; ++c) {
            bh[c] = *(const bf16x8*)&r1.b1.h[wc * 32 + c * 16 + lrow][kp * 32 + quad * 8];
            bl[c] = *(const bf16x8*)&r1.b1.l[wc * 32 + c * 16 + lrow][kp * 32 + quad * 8];
        }
#pragma unroll
        for (int r = 0; r < 2; ++r)
#pragma unroll
            for (int c = 0; c < 2; ++c) {
                acc1[r][c] = __builtin_amdgcn_mfma_f32_16x16x32_bf16(ah[r], bh[c], acc1[r][c], 0, 0, 0);
                acc1[r][c] = __builtin_amdgcn_mfma_f32_16x16x32_bf16(ah[r], bl[c], acc1[r][c], 0, 0, 0);
                acc1[r][c] = __builtin_amdgcn_mfma_f32_16x16x32_bf16(al[r], bh[c], acc1[r][c], 0, 0, 0);
            }
    }
    __syncthreads();   // all waves done reading B1 -> R1 reusable as cbuf
    // transpose acc1 -> r1.cb
#pragma unroll
    for (int c = 0; c < 2; ++c)
#pragma unroll
        for (int r = 0; r < 2; ++r)
#pragma unroll
            for (int j = 0; j < 4; ++j)
                r1.cb[wr * 32 + r * 16 + quad * 4 + j][wc * 32 + c * 16 + lrow] = acc1[r][c][j];
    __syncthreads();
    // edge epilogue: e' = relu(cb + u1[src] + u2[dst]) -> r3 planes (+ optional global store)
    {
        const int row = tid >> 2, q = tid & 3;
        const float* pu1 = uu + (long)s_sp[row] * 128 + q * 16;
        const float* pu2 = uu + (long)s_dp[row] * 128 + 64 + q * 16;
        const float* pc = &r1.cb[row][q * 16];
        u16x8 hv0, lv0, hv1, lv1;
#pragma unroll
        for (int half = 0; half < 2; ++half) {
            float4 a0 = *(const float4*)(pu1 + half * 8);
            float4 a1 = *(const float4*)(pu1 + half * 8 + 4);
            float4 b0 = *(const float4*)(pu2 + half * 8);
            float4 b1 = *(const float4*)(pu2 + half * 8 + 4);
            float s[8] = {a0.x + b0.x, a0.y + b0.y, a0.z + b0.z, a0.w + b0.w,
                          a1.x + b1.x, a1.y + b1.y, a1.z + b1.z, a1.w + b1.w};
            u16x8 hv, lv;
#pragma unroll
            for (int k = 0; k < 8; ++k) {
                float v = relu_f(pc[half * 8 + k] + s[k]);
                u16 h = f2bf(v);
                hv[k] = h;
                lv[k] = f2bf(v - bf2f(h));
            }
            if (half == 0) { hv0 = hv; lv0 = lv; } else { hv1 = hv; lv1 = lv; }
        }
        *(u16x8*)&r3.h[row][q * 16]     = hv0;
        *(u16x8*)&r3.h[row][q * 16 + 8] = hv1;
        *(u16x8*)&r3.l[row][q * 16]     = lv0;
        *(u16x8*)&r3.l[row][q * 16 + 8] = lv1;
        // materialize e' for the next layer (in-place: block writes only its own rows)
        long grow = rowbase + row;
        if (write_e && grow < NE) {
            long o = grow * 64 + q * 16;
            *(u16x8*)(eh + o)     = hv0;
            *(u16x8*)(eh + o + 8) = hv1;
            *(u16x8*)(el + o)     = lv0;
            *(u16x8*)(el + o + 8) = lv1;
        }
    }
    __syncthreads();
    // ---- per col-half of the message GEMM: B2 direct from L2, MFMA-2, msg epilogue ----
    const int col = tid & 63, seg = tid >> 6;
    const u16* pB2h = B2th + (long)(wc * 32 + lrow) * 192 + 128 + quad * 8;
    const u16* pB2l = B2tl + (long)(wc * 32 + lrow) * 192 + 128 + quad * 8;
    for (int p = 0; p < 2; ++p) {
        f32x4 acc2[2][2];
#pragma unroll
        for (int r = 0; r < 2; ++r)
#pragma unroll
            for (int c = 0; c < 2; ++c) acc2[r][c] = (f32x4){0.f, 0.f, 0.f, 0.f};
#pragma unroll
        for (int kp = 0; kp < 2; ++kp) {
            bf16x8 ah[2], al[2], bh[2], bl[2];
#pragma unroll
            for (int r = 0; r < 2; ++r) {
                ah[r] = *(const bf16x8*)&r3.h[wr * 32 + r * 16 + lrow][kp * 32 + quad * 8];
                al[r] = *(const bf16x8*)&r3.l[wr * 32 + r * 16 + lrow][kp * 32 + quad * 8];
            }
#pragma unroll
            for (int c = 0; c < 2; ++c) {
                long off = (long)(p * 64 + c * 16) * 192 + kp * 32;
                bh[c] = *(const bf16x8*)(pB2h + off);
                bl[c] = *(const bf16x8*)(pB2l + off);
            }
#pragma unroll
            for (int r = 0; r < 2; ++r)
#pragma unroll
                for (int c = 0; c < 2; ++c) {
                    acc2[r][c] = __builtin_amdgcn_mfma_f32_16x16x32_bf16(ah[r], bh[c], acc2[r][c], 0, 0, 0);
                    acc2[r][c] = __builtin_amdgcn_mfma_f32_16x16x32_bf16(ah[r], bl[c], acc2[r][c], 0, 0, 0);
                    acc2[r][c] = __builtin_amdgcn_mfma_f32_16x16x32_bf16(al[r], bh[c], acc2[r][c], 0, 0, 0);
                }
        }
        // phase A: acc2 -> r1.cb
#pragma unroll
        for (int c = 0; c < 2; ++c)
#pragma unroll
            for (int r = 0; r < 2; ++r)
#pragma unroll
                for (int j = 0; j < 4; ++j)
                    r1.cb[wr * 32 + r * 16 + quad * 4 + j][wc * 32 + c * 16 + lrow] = acc2[r][c][j];
        __syncthreads();
        // phase B: y add + relu
        {
            int row = tid >> 2, q = tid & 3;
            const float* py = y + (long)s_sp[row] * 128 + p * 64 + q * 16;
            float* pc = &r1.cb[row][q * 16];
#pragma unroll
            for (int g = 0; g < 4; ++g) {
                float4 yv = *(const float4*)(py + g * 4);
                pc[g * 4 + 0] = relu_f(pc[g * 4 + 0] + yv.x);
                pc[g * 4 + 1] = relu_f(pc[g * 4 + 1] + yv.y);
                pc[g * 4 + 2] = relu_f(pc[g * 4 + 2] + yv.z);
                pc[g * 4 + 3] = relu_f(pc[g * 4 + 3] + yv.w);
            }
        }
        __syncthreads();
        // phase C: run-scan over dst-runs, atomic flush (ghost rows masked)
        {
            int cur = -1; float sum = 0.0f;
            for (int rr = seg * 16; rr < seg * 16 + 16; ++rr) {
                int d = (rowbase + rr < NE) ? s_dp[rr] : -1;
                if (d != cur) {
                    if (cur >= 0) atomicAdd(&agg[(long)cur * 128 + p * 64 + col], sum);
                    cur = d; sum = 0.0f;
                }
                sum += r1.cb[rr][col];
            }
            if (cur >= 0) atomicAdd(&agg[(long)cur * 128 + p * 64 + col], sum);
        }
        __syncthreads();
    }
}

// ================= node update GEMM (MFMA, split bf16, fused L2-norm) =================
__global__ __launch_bounds__(256) void k_update_mfma(
    float* __restrict__ agg, const float* __restrict__ icnt,
    u16* __restrict__ xh, u16* __restrict__ xl,
    const u16* __restrict__ Bth, const u16* __restrict__ Btl,
    const float* __restrict__ bias, int zero_agg)
{
    __shared__ u16 Ah[64][40], Al[64][40], Bh[128][40], Bl[128][40];
    __shared__ float s_ic[64];
    __shared__ float sP[64][2];
    const int tid = threadIdx.x;
    const long rowbase = (long)blockIdx.x * 64;
    if (tid < 64) {
        long r = rowbase + tid;
        int rr = (r < NN) ? (int)r : (NN - 1);
        s_ic[tid] = icnt[rr];
    }
    __syncthreads();
    const int wave = tid >> 6, lane = tid & 63;
    const int quad = lane >> 4, lrow = lane & 15;
    const int wr = wave >> 1, wc = wave & 1;
    const int arow = tid >> 2, akh = (tid & 3) * 8;
    const int brow = tid >> 1, bkh = (tid & 1) << 4;

    f32x4 acc[2][4];
#pragma unroll
    for (int r = 0; r < 2; ++r)
#pragma unroll
        for (int c = 0; c < 4; ++c) acc[r][c] = (f32x4){0.f, 0.f, 0.f, 0.f};

    for (int kp = 0; kp < 8; ++kp) {
        const int k0 = kp * 32;
        if (k0 < 128) {
            long r = rowbase + arow;
            const bool own = (r < NN);
            if (!own) r = NN - 1;
            float* pa = agg + r * 128 + k0 + akh;
            float ic = s_ic[arow];
#pragma unroll
            for (int q = 0; q < 8; q += 4) {
                float4 f = *(const float4*)(pa + q);
                float vv[4] = {f.x, f.y, f.z, f.w};
#pragma unroll
                for (int j = 0; j < 4; ++j) {
                    float v = vv[j] * ic;
                    u16 h = f2bf(v);
                    Ah[arow][akh + q + j] = h;
                    Al[arow][akh + q + j] = f2bf(v - bf2f(h));
                }
            }
            if (zero_agg && own) {
                float4 z = {0.f, 0.f, 0.f, 0.f};
                *(float4*)(pa + 0) = z;
                *(float4*)(pa + 4) = z;
            }
        } else {
            long r = rowbase + arow; if (r >= NN) r = NN - 1;
            long b = r * 128 + (k0 - 128 + akh);
            *(int4*)&Ah[arow][akh] = *(const int4*)(xh + b);
            *(int4*)&Al[arow][akh] = *(const int4*)(xl + b);
        }
        {
            long b = (long)brow * 256 + k0 + bkh;
            *(int4*)&Bh[brow][bkh]     = *(const int4*)(Bth + b);
            *(int4*)&Bh[brow][bkh + 8] = *(const int4*)(Bth + b + 8);
            *(int4*)&Bl[brow][bkh]     = *(const int4*)(Btl + b);
            *(int4*)&Bl[brow][bkh + 8] = *(const int4*)(Btl + b + 8);
        }
        __syncthreads();
        bf16x8 ah[2], al[2], bh[4], bl[4];
#pragma unroll
        for (int r = 0; r < 2; ++r) {
            ah[r] = *(const bf16x8*)&Ah[wr * 32 + r * 16 + lrow][quad * 8];
            al[r] = *(const bf16x8*)&Al[wr * 32 + r * 16 + lrow][quad * 8];
        }
#pragma unroll
        for (int c = 0; c < 4; ++c) {
            bh[c] = *(const bf16x8*)&Bh[wc * 64 + c * 16 + lrow][quad * 8];
            bl[c] = *(const bf16x8*)&Bl[wc * 64 + c * 16 + lrow][quad * 8];
        }
#pragma unroll
        for (int r = 0; r < 2; ++r)
#pragma unroll
            for (int c = 0; c < 4; ++c) {
                acc[r][c] = __builtin_amdgcn_mfma_f32_16x16x32_bf16(ah[r], bh[c], acc[r][c], 0, 0, 0);
                acc[r][c] = __builtin_amdgcn_mfma_f32_16x16x32_bf16(ah[r], bl[c], acc[r][c], 0, 0, 0);
                acc[r][c] = __builtin_amdgcn_mfma_f32_16x16x32_bf16(al[r], bh[c], acc[r][c], 0, 0, 0);
            }
        __syncthreads();
    }
#pragma unroll
    for (int r = 0; r < 2; ++r)
#pragma unroll
        for (int c = 0; c < 4; ++c)
#pragma unroll
            for (int j = 0; j < 4; ++j)
                acc[r][c][j] = relu_f(acc[r][c][j] + bias[wc * 64 + c * 16 + lrow]);
#pragma unroll
    for (int r = 0; r < 2; ++r)
#pragma unroll
        for (int j = 0; j < 4; ++j) {
            float s2 = 0.0f;
#pragma unroll
            for (int c = 0; c < 4; ++c) { float v = acc[r][c][j]; s2 += v * v; }
#pragma unroll
            for (int m = 1; m < 16; m <<= 1) s2 += __shfl_xor(s2, m, 64);
            if (lrow == 0) sP[wr * 32 + r * 16 + quad * 4 + j][wc] = s2;
        }
    __syncthreads();
#pragma unroll
    for (int r = 0; r < 2; ++r)
#pragma unroll
        for (int j = 0; j < 4; ++j) {
            int lr = wr * 32 + r * 16 + quad * 4 + j;
            long grow = rowbase + lr;
            if (grow < NN) {
                float tot = sP[lr][0] + sP[lr][1];
                float rn = 1.0f / fmaxf(sqrtf(tot), 1e-12f);
#pragma unroll
                for (int c = 0; c < 4; ++c) {
                    float v = acc[r][c][j] * rn;
                    long o = grow * 128 + wc * 64 + c * 16 + lrow;
                    u16 h = f2bf(v);
                    xh[o] = h;
                    xl[o] = f2bf(v - bf2f(h));
                }
            }
        }
}

// ---------------- fused MLP head: out = relu(x@W1+b1)@W2+b2 ----------------
__global__ __launch_bounds__(256) void k_head(
    const u16* __restrict__ xh, const u16* __restrict__ xl,
    const float* __restrict__ W1, const float* __restrict__ b1,
    const float* __restrict__ W2, const float* __restrict__ b2,
    float* __restrict__ out)
{
    constexpr int KC = 64, NP = 2, EB = 32;
    __shared__ __align__(16) float At[KC][EB + 4];
    __shared__ __align__(16) union { float W1s[KC][64]; float W2s[KC][128]; } w;
    const int tid = threadIdx.x;
    const int rowbase = blockIdx.x * EB;
    const int wave = tid >> 6, lane = tid & 63;
    float acc[8];
#pragma unroll
    for (int i = 0; i < 8; ++i) acc[i] = 0.0f;

    for (int kp = 0; kp < NP; ++kp) {
        const int k0 = kp * KC;
        for (int i = tid; i < KC * EB; i += 256) {
            int e = i >> 6, kk = i & 63, k = k0 + kk;
            int r = min(rowbase + e, NN - 1);
            long b = (long)r * 128 + k;
            At[kk][e] = bf2f(xh[b]) + bf2f(xl[b]);
        }
        for (int i = tid; i < KC * 64; i += 256) {
            int kk = i >> 6, cc = i & 63;
            w.W1s[kk][cc] = W1[(size_t)(k0 + kk) * 64 + cc];
        }
        __syncthreads();
#pragma unroll 4
        for (int kk = 0; kk < KC; ++kk) {
            const float* ar = &At[kk][wave * 8];
            float4 a0 = *(const float4*)ar;
            float4 a1 = *(const float4*)(ar + 4);
            float wv = w.W1s[kk][lane];
            acc[0] += a0.x * wv; acc[1] += a0.y * wv; acc[2] += a0.z * wv; acc[3] += a0.w * wv;
            acc[4] += a1.x * wv; acc[5] += a1.y * wv; acc[6] += a1.z * wv; acc[7] += a1.w * wv;
        }
        __syncthreads();
    }
    {
        const float bv = b1[lane];
#pragma unroll
        for (int j = 0; j < 8; ++j)
            At[lane][wave * 8 + j] = relu_f(acc[j] + bv);
    }
    for (int i = tid; i < KC * 128; i += 256) {
        int kk = i >> 7, cc = i & 127;
        w.W2s[kk][cc] = W2[(size_t)kk * 128 + cc];
    }
    __syncthreads();
    float a2[16];
#pragma unroll
    for (int i = 0; i < 16; ++i) a2[i] = 0.0f;
#pragma unroll 4
    for (int kk = 0; kk < KC; ++kk) {
        const float* ar = &At[kk][wave * 8];
        float4 a0 = *(const float4*)ar;
        float4 a1 = *(const float4*)(ar + 4);
        float w0 = w.W2s[kk][lane], w1 = w.W2s[kk][64 + lane];
        a2[0] += a0.x * w0;  a2[1] += a0.y * w0;  a2[2] += a0.z * w0;  a2[3] += a0.w * w0;
        a2[4] += a1.x * w0;  a2[5] += a1.y * w0;  a2[6] += a1.z * w0;  a2[7] += a1.w * w0;
        a2[8] += a0.x * w1;  a2[9] += a0.y * w1;  a2[10] += a0.z * w1; a2[11] += a0.w * w1;
        a2[12] += a1.x * w1; a2[13] += a1.y * w1; a2[14] += a1.z * w1; a2[15] += a1.w * w1;
    }
    const float o0 = b2[lane], o1 = b2[64 + lane];
#pragma unroll
    for (int j = 0; j < 8; ++j) {
        int r = rowbase + wave * 8 + j;
        if (r < NN) {
            out[(size_t)r * 128 + lane] = a2[j] + o0;
            out[(size_t)r * 128 + 64 + lane] = a2[8 + j] + o1;
        }
    }
}

// ---------------- host-side launch ----------------
extern "C" void kernel_launch(void* const* d_in, const int* in_sizes, int n_in,
                              void* d_out, int out_size, void* d_ws, size_t ws_size,
                              hipStream_t stream) {
    const float* d_x  = (const float*)d_in[0];
    const float* d_ea = (const float*)d_in[1];
    const int*   d_ei = (const int*)d_in[2];
    const float* Wm   = (const float*)d_in[3];
    const float* bm   = (const float*)d_in[4];
    const float* Wa   = (const float*)d_in[5];
    const float* ba   = (const float*)d_in[6];
    const float* We   = (const float*)d_in[7];
    const float* be   = (const float*)d_in[8];
    const float* W1   = (const float*)d_in[9];
    const float* b1   = (const float*)d_in[10];
    const float* W2   = (const float*)d_in[11];
    const float* b2   = (const float*)d_in[12];
    float* out = (float*)d_out;

    const int* src = d_ei;
    const int* dst = d_ei + NE;

    char* p = (char*)d_ws;
    auto alloc = [&](size_t bytes) { char* q = p; p += (bytes + 255) & ~(size_t)255; return q; };
    u16* xh  = (u16*)alloc((size_t)NN * 128 * 2);
    u16* xl  = (u16*)alloc((size_t)NN * 128 * 2);
    u16* ehb = (u16*)alloc((size_t)NE * 64 * 2);
    u16* elb = (u16*)alloc((size_t)NE * 64 * 2);
    float* agg = (float*)alloc((size_t)NN * 128 * 4);
    float* yu  = (float*)alloc((size_t)NN * 128 * 4);   // y per layer
    float* ubuf = (float*)alloc((size_t)NN * 128 * 4);  // u per layer (coexists with y)
    float* cnt = (float*)alloc((size_t)NN * 4);
    float* zbuf = (float*)alloc(64 * 4);
    u16* Wmt_h = (u16*)alloc((size_t)3 * 192 * 128 * 2);
    u16* Wmt_l = (u16*)alloc((size_t)3 * 192 * 128 * 2);
    u16* Wat_h = (u16*)alloc((size_t)3 * 256 * 128 * 2);
    u16* Wat_l = (u16*)alloc((size_t)3 * 256 * 128 * 2);
    u16* Wet_h = (u16*)alloc((size_t)3 * 320 * 64 * 2);
    u16* Wet_l = (u16*)alloc((size_t)3 * 320 * 64 * 2);
    u16* Wxt_h = (u16*)alloc((size_t)3 * 128 * 128 * 2);
    u16* Wxt_l = (u16*)alloc((size_t)3 * 128 * 128 * 2);
    int* hist   = (int*)alloc((size_t)NN * 4);
    int* excl   = (int*)alloc((size_t)NN * 4);
    int* bsum   = (int*)alloc(128 * 4);
    int* cursor = (int*)alloc((size_t)NN * 4);
    int* perm   = (int*)alloc((size_t)NE * 4);
    int* sp     = (int*)alloc((size_t)NE * 4);
    int* dp     = (int*)alloc((size_t)NE * 4);

    const int NB1 = (NN + 511) / 512;

    hipMemsetAsync(hist, 0, NN * sizeof(int), stream);
    k_hist<<<(NE + 255) / 256, 256, 0, stream>>>(dst, hist);
    k_scan1<<<NB1, 512, 0, stream>>>(hist, excl, bsum, cnt);
    k_scan2<<<1, 128, 0, stream>>>(bsum, NB1);
    k_scan3<<<NB1, 512, 0, stream>>>(excl, bsum, cursor);
    k_scatter<<<(NE + 255) / 256, 256, 0, stream>>>(dst, cursor, perm);

    k_split_all<<<(XQ + NE * 16 + 255) / 256, 256, 0, stream>>>(
        d_x, xh, xl, d_ea, perm, ehb, elb, src, dst, sp, dp);
    k_wtall<<<(245824 + 255) / 256, 256, 0, stream>>>(
        Wm, Wa, We, Wmt_h, Wmt_l, Wat_h, Wat_l, Wet_h, Wet_l, Wxt_h, Wxt_l, zbuf);

    hipMemsetAsync(agg, 0, (size_t)NN * 128 * sizeof(float), stream);   // layer-0 only

    const int NGB = (NN + 63) / 64;
    // ---- layer 0 ----
    k_ngemm<<<NGB, 256, 0, stream>>>(xh, xl, Wmt_h, Wmt_l, 192, bm, bm + 64, yu);
    k_msg2<<<(NE + 63) / 64, 256, 0, stream>>>(ehb, elb, sp, dp, Wmt_h, Wmt_l, yu, agg);
    k_update_mfma<<<NGB, 256, 0, stream>>>(agg, cnt, xh, xl, Wat_h, Wat_l, ba, 1);
    // u0 = x1 @ [We1|We2](l=0) -> ubuf (consumed by fused layer-1 kernel)
    k_ngemm<<<NGB, 256, 0, stream>>>(xh, xl, Wxt_h, Wxt_l, 128, be, zbuf, ubuf);
    // ---- layer 1: fused edge(l=0, written back) + msg(l=1) ----
    k_ngemm<<<NGB, 256, 0, stream>>>(xh, xl,
        Wmt_h + (size_t)1 * 192 * 128, Wmt_l + (size_t)1 * 192 * 128, 192,
        bm + 128, bm + 128 + 64, yu);
    k_msg2e<<<(NE + 63) / 64, 256, 0, stream>>>(ehb, elb, sp, dp,
        Wet_h, Wet_l,                                                     // We l=0
        Wmt_h + (size_t)1 * 192 * 128, Wmt_l + (size_t)1 * 192 * 128,     // Wm l=1
        ubuf, yu, agg, 1);
    k_update_mfma<<<NGB, 256, 0, stream>>>(agg, cnt, xh, xl,
        Wat_h + (size_t)1 * 256 * 128, Wat_l + (size_t)1 * 256 * 128, ba + 128, 1);
    // u1 = x2 @ [We1|We2](l=1) -> ubuf
    k_ngemm<<<NGB, 256, 0, stream>>>(xh, xl,
        Wxt_h + (size_t)1 * 128 * 128, Wxt_l + (size_t)1 * 128 * 128, 128,
        be + 64, zbuf, ubuf);
    // ---- layer 2: fused edge(l=1, not written) + msg(l=2) ----
    k_ngemm<<<NGB, 256, 0, stream>>>(xh, xl,
        Wmt_h + (size_t)2 * 192 * 128, Wmt_l + (size_t)2 * 192 * 128, 192,
        bm + 256, bm + 256 + 64, yu);
    k_msg2e<<<(NE + 63) / 64, 256, 0, stream>>>(ehb, elb, sp, dp,
        Wet_h + (size_t)1 * 320 * 64, Wet_l + (size_t)1 * 320 * 64,       // We l=1
        Wmt_h + (size_t)2 * 192 * 128, Wmt_l + (size_t)2 * 192 * 128,     // Wm l=2
        ubuf, yu, agg, 0);
    k_update_mfma<<<NGB, 256, 0, stream>>>(agg, cnt, xh, xl,
        Wat_h + (size_t)2 * 256 * 128, Wat_l + (size_t)2 * 256 * 128, ba + 256, 0);

    k_head<<<(NN + 31) / 32, 256, 0, stream>>>(xh, xl, W1, b1, W2, b2, out);
}

// Round 14
// 896.426 us; speedup vs baseline: 1.2412x; 1.0044x over previous
//
#include <hip/hip_runtime.h>
#include <cstdint>
#include <cstddef>

#define NN 50000
#define NE 500000
#define XQ (NN * 128 / 4)

typedef unsigned short u16;
typedef __attribute__((ext_vector_type(8))) short bf16x8;
typedef __attribute__((ext_vector_type(4))) float f32x4;
typedef __attribute__((ext_vector_type(4))) unsigned short u16x4;
typedef __attribute__((ext_vector_type(8))) unsigned short u16x8;

__device__ __forceinline__ float relu_f(float v) { return fmaxf(v, 0.0f); }

__device__ __forceinline__ u16 f2bf(float f) {
    union { float f; unsigned u; } c; c.f = f;
    unsigned u = c.u;
    unsigned r = u + 0x7FFFu + ((u >> 16) & 1u);
    return (u16)(r >> 16);
}
__device__ __forceinline__ float bf2f(u16 h) {
    union { unsigned u; float f; } c; c.u = ((unsigned)h) << 16;
    return c.f;
}

// ---------------- counting sort of edges by dst ----------------
__global__ __launch_bounds__(256) void k_hist(const int* __restrict__ dst, int* __restrict__ h) {
    int e = blockIdx.x * 256 + threadIdx.x;
    if (e < NE) atomicAdd(&h[dst[e]], 1);
}

// prefix-scan of hist; also emits cnt = 1/max(hist,1)
__global__ __launch_bounds__(512) void k_scan1(const int* __restrict__ h,
                                               int* __restrict__ excl, int* __restrict__ bsum,
                                               float* __restrict__ cnt) {
    __shared__ int s[512];
    int tid = threadIdx.x;
    int i = blockIdx.x * 512 + tid;
    int v = (i < NN) ? h[i] : 0;
    if (i < NN) cnt[i] = 1.0f / fmaxf((float)v, 1.0f);
    s[tid] = v;
    __syncthreads();
    for (int off = 1; off < 512; off <<= 1) {
        int t = (tid >= off) ? s[tid - off] : 0;
        __syncthreads();
        s[tid] += t;
        __syncthreads();
    }
    if (i < NN) excl[i] = s[tid] - v;
    if (tid == 511) bsum[blockIdx.x] = s[511];
}

__global__ __launch_bounds__(128) void k_scan2(int* __restrict__ bsum, int nb) {
    __shared__ int s[128];
    int tid = threadIdx.x;
    int v = (tid < nb) ? bsum[tid] : 0;
    s[tid] = v;
    __syncthreads();
    for (int off = 1; off < 128; off <<= 1) {
        int t = (tid >= off) ? s[tid - off] : 0;
        __syncthreads();
        s[tid] += t;
        __syncthreads();
    }
    if (tid < nb) bsum[tid] = s[tid] - v;
}

__global__ __launch_bounds__(512) void k_scan3(const int* __restrict__ excl, const int* __restrict__ bsum,
                                               int* __restrict__ cursor) {
    int i = blockIdx.x * 512 + threadIdx.x;
    if (i < NN) cursor[i] = excl[i] + bsum[blockIdx.x];
}

__global__ __launch_bounds__(256) void k_scatter(const int* __restrict__ dst,
                                                 int* __restrict__ cursor, int* __restrict__ perm) {
    int e = blockIdx.x * 256 + threadIdx.x;
    if (e < NE) {
        int pos = atomicAdd(&cursor[dst[e]], 1);
        perm[pos] = e;
    }
}

// ---------------- merged split kernel: x-split + permuted e-split + sp/dp ----------------
__global__ __launch_bounds__(256) void k_split_all(
    const float* __restrict__ x, u16* __restrict__ xh, u16* __restrict__ xl,
    const float* __restrict__ e, const int* __restrict__ perm,
    u16* __restrict__ eh, u16* __restrict__ el,
    const int* __restrict__ src, const int* __restrict__ dst,
    int* __restrict__ sp, int* __restrict__ dp)
{
    long t = (long)blockIdx.x * 256 + threadIdx.x;
    if (t < XQ) {
        float4 v = ((const float4*)x)[t];
        float vv[4] = {v.x, v.y, v.z, v.w};
        u16x4 hv, lv;
#pragma unroll
        for (int j = 0; j < 4; ++j) {
            u16 h = f2bf(vv[j]);
            hv[j] = h;
            lv[j] = f2bf(vv[j] - bf2f(h));
        }
        ((u16x4*)xh)[t] = hv;
        ((u16x4*)xl)[t] = lv;
    } else {
        long g = t - XQ;
        int i = (int)(g >> 4), c4 = ((int)g & 15) << 2;
        if (i < NE) {
            int pe = perm[i];
            if ((g & 15) == 0) { sp[i] = src[pe]; dp[i] = dst[pe]; }
            float4 v = *(const float4*)(e + (long)pe * 64 + c4);
            float vv[4] = {v.x, v.y, v.z, v.w};
            u16x4 hv, lv;
#pragma unroll
            for (int j = 0; j < 4; ++j) {
                u16 h = f2bf(vv[j]);
                hv[j] = h;
                lv[j] = f2bf(vv[j] - bf2f(h));
            }
            long o = (long)i * 64 + c4;
            *(u16x4*)(eh + o) = hv;
            *(u16x4*)(el + o) = lv;
        }
    }
}

// ---------------- batched weight transposes (all layers, all W) + zbuf zero ----------------
__global__ __launch_bounds__(256) void k_wtall(
    const float* __restrict__ Wm, const float* __restrict__ Wa, const float* __restrict__ We,
    u16* __restrict__ Wmt_h, u16* __restrict__ Wmt_l,
    u16* __restrict__ Wat_h, u16* __restrict__ Wat_l,
    u16* __restrict__ Wet_h, u16* __restrict__ Wet_l,
    u16* __restrict__ Wxt_h, u16* __restrict__ Wxt_l,
    float* __restrict__ zbuf)
{
    int i = blockIdx.x * 256 + threadIdx.x;
    float v; u16* th; u16* tl; int oi;
    if (i < 73728) {
        int l = i / 24576, j = i % 24576;
        int n = j / 192, k = j - n * 192;
        v = Wm[(size_t)l * 24576 + (size_t)k * 128 + n];
        th = Wmt_h; tl = Wmt_l; oi = i;
    } else if ((i -= 73728) < 98304) {
        int l = i / 32768, j = i % 32768;
        int n = j / 256, k = j - n * 256;
        v = Wa[(size_t)l * 32768 + (size_t)k * 128 + n];
        th = Wat_h; tl = Wat_l; oi = i;
    } else if ((i -= 98304) < 40960) {
        int l = i / 20480, j = i % 20480;
        int n = j / 320, k = j - n * 320;
        v = We[(size_t)l * 20480 + (size_t)k * 64 + n];
        th = Wet_h; tl = Wet_l; oi = i;
    } else if ((i -= 40960) < 32768) {
        int l = i / 16384, j2 = i % 16384;
        int jj = j2 >> 7, k = j2 & 127;
        v = We[(size_t)l * 20480 + (size_t)(k + ((jj >> 6) << 7)) * 64 + (jj & 63)];
        th = Wxt_h; tl = Wxt_l; oi = i;
    } else if ((i -= 32768) < 64) {
        zbuf[i] = 0.0f;
        return;
    } else {
        return;
    }
    u16 h = f2bf(v);
    th[oi] = h;
    tl[oi] = f2bf(v - bf2f(h));
}

// ================= node GEMM: C = x @ B + bias (fp32 out, no relu) =================
__global__ __launch_bounds__(256) void k_ngemm(
    const u16* __restrict__ xh, const u16* __restrict__ xl,
    const u16* __restrict__ Bth, const u16* __restrict__ Btl, int bstride,
    const float* __restrict__ bias0, const float* __restrict__ bias1,
    float* __restrict__ C)
{
    __shared__ u16 Ah[64][40], Al[64][40], Bh[128][40], Bl[128][40];
    const int tid = threadIdx.x;
    const long rowbase = (long)blockIdx.x * 64;
    const int wave = tid >> 6, lane = tid & 63;
    const int quad = lane >> 4, lrow = lane & 15;
    const int wr = wave >> 1, wc = wave & 1;
    const int arow = tid >> 2, akh = (tid & 3) * 8;
    const int brow = tid >> 1, bkh = (tid & 1) << 4;

    f32x4 acc[2][4];
#pragma unroll
    for (int r = 0; r < 2; ++r)
#pragma unroll
        for (int c = 0; c < 4; ++c) acc[r][c] = (f32x4){0.f, 0.f, 0.f, 0.f};

    for (int kp = 0; kp < 4; ++kp) {
        const int k0 = kp * 32;
        {
            long r = rowbase + arow; if (r >= NN) r = NN - 1;
            long b = r * 128 + k0 + akh;
            *(int4*)&Ah[arow][akh] = *(const int4*)(xh + b);
            *(int4*)&Al[arow][akh] = *(const int4*)(xl + b);
        }
        {
            long b = (long)brow * bstride + k0 + bkh;
            *(int4*)&Bh[brow][bkh]     = *(const int4*)(Bth + b);
            *(int4*)&Bh[brow][bkh + 8] = *(const int4*)(Bth + b + 8);
            *(int4*)&Bl[brow][bkh]     = *(const int4*)(Btl + b);
            *(int4*)&Bl[brow][bkh + 8] = *(const int4*)(Btl + b + 8);
        }
        __syncthreads();
        bf16x8 ah[2], al[2], bh[4], bl[4];
#pragma unroll
        for (int r = 0; r < 2; ++r) {
            ah[r] = *(const bf16x8*)&Ah[wr * 32 + r * 16 + lrow][quad * 8];
            al[r] = *(const bf16x8*)&Al[wr * 32 + r * 16 + lrow][quad * 8];
        }
#pragma unroll
        for (int c = 0; c < 4; ++c) {
            bh[c] = *(const bf16x8*)&Bh[wc * 64 + c * 16 + lrow][quad * 8];
            bl[c] = *(const bf16x8*)&Bl[wc * 64 + c * 16 + lrow][quad * 8];
        }
#pragma unroll
        for (int r = 0; r < 2; ++r)
#pragma unroll
            for (int c = 0; c < 4; ++c) {
                acc[r][c] = __builtin_amdgcn_mfma_f32_16x16x32_bf16(ah[r], bh[c], acc[r][c], 0, 0, 0);
                acc[r][c] = __builtin_amdgcn_mfma_f32_16x16x32_bf16(ah[r], bl[c], acc[r][c], 0, 0, 0);
                acc[r][c] = __builtin_amdgcn_mfma_f32_16x16x32_bf16(al[r], bh[c], acc[r][c], 0, 0, 0);
            }
        __syncthreads();
    }
#pragma unroll
    for (int c = 0; c < 4; ++c) {
        int colg = wc * 64 + c * 16 + lrow;
        float bv = (colg < 64) ? bias0[colg] : bias1[colg - 64];
#pragma unroll
        for (int r = 0; r < 2; ++r)
#pragma unroll
            for (int j = 0; j < 4; ++j) {
                long grow = rowbase + wr * 32 + r * 16 + quad * 4 + j;
                if (grow < NN) C[grow * 128 + colg] = acc[r][c][j] + bv;
            }
    }
}

// ================= paired node GEMM: U = x@B1 + [be|0], Y = x@B2 + bm ==================
// Merges ngemm(u_l) + ngemm(y_{l+1}) (identical A operand): A staged once per kp,
// both B tiles resident, two accumulator sets. Saves one full A-stream + one launch.
__global__ __launch_bounds__(256) void k_ngemm2(
    const u16* __restrict__ xh, const u16* __restrict__ xl,
    const u16* __restrict__ B1th, const u16* __restrict__ B1tl,  // Wxt [128][128], stride 128
    const u16* __restrict__ B2th, const u16* __restrict__ B2tl,  // Wmt [128][192], k=0..127
    const float* __restrict__ biasU,                              // be (cols 0-63); cols 64-127 = 0
    const float* __restrict__ biasY,                              // bm[128]
    float* __restrict__ U, float* __restrict__ Y)
{
    __shared__ u16 Ah[64][40], Al[64][40];
    __shared__ u16 B1h[128][40], B1l[128][40], B2h[128][40], B2l[128][40];
    const int tid = threadIdx.x;
    const long rowbase = (long)blockIdx.x * 64;
    const int wave = tid >> 6, lane = tid & 63;
    const int quad = lane >> 4, lrow = lane & 15;
    const int wr = wave >> 1, wc = wave & 1;
    const int arow = tid >> 2, akh = (tid & 3) * 8;
    const int brow = tid >> 1, bkh = (tid & 1) << 4;

    f32x4 accU[2][4], accY[2][4];
#pragma unroll
    for (int r = 0; r < 2; ++r)
#pragma unroll
        for (int c = 0; c < 4; ++c) {
            accU[r][c] = (f32x4){0.f, 0.f, 0.f, 0.f};
            accY[r][c] = (f32x4){0.f, 0.f, 0.f, 0.f};
        }

    for (int kp = 0; kp < 4; ++kp) {
        const int k0 = kp * 32;
        {
            long r = rowbase + arow; if (r >= NN) r = NN - 1;
            long b = r * 128 + k0 + akh;
            *(int4*)&Ah[arow][akh] = *(const int4*)(xh + b);
            *(int4*)&Al[arow][akh] = *(const int4*)(xl + b);
        }
        {
            long b1 = (long)brow * 128 + k0 + bkh;
            *(int4*)&B1h[brow][bkh]     = *(const int4*)(B1th + b1);
            *(int4*)&B1h[brow][bkh + 8] = *(const int4*)(B1th + b1 + 8);
            *(int4*)&B1l[brow][bkh]     = *(const int4*)(B1tl + b1);
            *(int4*)&B1l[brow][bkh + 8] = *(const int4*)(B1tl + b1 + 8);
            long b2 = (long)brow * 192 + k0 + bkh;
            *(int4*)&B2h[brow][bkh]     = *(const int4*)(B2th + b2);
            *(int4*)&B2h[brow][bkh + 8] = *(const int4*)(B2th + b2 + 8);
            *(int4*)&B2l[brow][bkh]     = *(const int4*)(B2tl + b2);
            *(int4*)&B2l[brow][bkh + 8] = *(const int4*)(B2tl + b2 + 8);
        }
        __syncthreads();
        bf16x8 ah[2], al[2], bh[4], bl[4];
#pragma unroll
        for (int r = 0; r < 2; ++r) {
            ah[r] = *(const bf16x8*)&Ah[wr * 32 + r * 16 + lrow][quad * 8];
            al[r] = *(const bf16x8*)&Al[wr * 32 + r * 16 + lrow][quad * 8];
        }
        // matrix 1 -> accU
#pragma unroll
        for (int c = 0; c < 4; ++c) {
            bh[c] = *(const bf16x8*)&B1h[wc * 64 + c * 16 + lrow][quad * 8];
            bl[c] = *(const bf16x8*)&B1l[wc * 64 + c * 16 + lrow][quad * 8];
        }
#pragma unroll
        for (int r = 0; r < 2; ++r)
#pragma unroll
            for (int c = 0; c < 4; ++c) {
                accU[r][c] = __builtin_amdgcn_mfma_f32_16x16x32_bf16(ah[r], bh[c], accU[r][c], 0, 0, 0);
                accU[r][c] = __builtin_amdgcn_mfma_f32_16x16x32_bf16(ah[r], bl[c], accU[r][c], 0, 0, 0);
                accU[r][c] = __builtin_amdgcn_mfma_f32_16x16x32_bf16(al[r], bh[c], accU[r][c], 0, 0, 0);
            }
        // matrix 2 -> accY
#pragma unroll
        for (int c = 0; c < 4; ++c) {
            bh[c] = *(const bf16x8*)&B2h[wc * 64 + c * 16 + lrow][quad * 8];
            bl[c] = *(const bf16x8*)&B2l[wc * 64 + c * 16 + lrow][quad * 8];
        }
#pragma unroll
        for (int r = 0; r < 2; ++r)
#pragma unroll
            for (int c = 0; c < 4; ++c) {
                accY[r][c] = __builtin_amdgcn_mfma_f32_16x16x32_bf16(ah[r], bh[c], accY[r][c], 0, 0, 0);
                accY[r][c] = __builtin_amdgcn_mfma_f32_16x16x32_bf16(ah[r], bl[c], accY[r][c], 0, 0, 0);
                accY[r][c] = __builtin_amdgcn_mfma_f32_16x16x32_bf16(al[r], bh[c], accY[r][c], 0, 0, 0);
            }
        __syncthreads();
    }
#pragma unroll
    for (int c = 0; c < 4; ++c) {
        int colg = wc * 64 + c * 16 + lrow;
        float bu = (colg < 64) ? biasU[colg] : 0.0f;
        float by = biasY[colg];
#pragma unroll
        for (int r = 0; r < 2; ++r)
#pragma unroll
            for (int j = 0; j < 4; ++j) {
                long grow = rowbase + wr * 32 + r * 16 + quad * 4 + j;
                if (grow < NN) {
                    U[grow * 128 + colg] = accU[r][c][j] + bu;
                    Y[grow * 128 + colg] = accY[r][c][j] + by;
                }
            }
    }
}

// ================= message kernel: m = relu(y[src] + e@Wme); run-scan aggregate =================
__global__ __launch_bounds__(256, 4) void k_msg2(
    const u16* __restrict__ eh, const u16* __restrict__ el,
    const int* __restrict__ sp, const int* __restrict__ dp,
    const u16* __restrict__ Bth, const u16* __restrict__ Btl,
    const float* __restrict__ y,
    float* __restrict__ agg)
{
    __shared__ union {
        struct { u16 Bh[128][72]; u16 Bl[128][72]; } b;
        float cbuf[64][66];
    } u;
    __shared__ int s_sp[64], s_dp[64];
    const int tid = threadIdx.x;
    const long rowbase = (long)blockIdx.x * 64;
    if (tid < 64) {
        long r = rowbase + tid;
        if (r < NE) { s_sp[tid] = sp[r]; s_dp[tid] = dp[r]; }
        else        { s_sp[tid] = 0;     s_dp[tid] = -1;    }
    }
    {
        int colb = tid >> 1, kh = (tid & 1) * 32;
        long bb = (long)colb * 192 + 128 + kh;
#pragma unroll
        for (int q = 0; q < 32; q += 8) {
            *(int4*)&u.b.Bh[colb][kh + q] = *(const int4*)(Bth + bb + q);
            *(int4*)&u.b.Bl[colb][kh + q] = *(const int4*)(Btl + bb + q);
        }
    }
    __syncthreads();
    const int wave = tid >> 6, lane = tid & 63;
    const int quad = lane >> 4, lrow = lane & 15;
    const int wr = wave >> 1, wc = wave & 1;

    f32x4 acc[2][4];
#pragma unroll
    for (int r = 0; r < 2; ++r)
#pragma unroll
        for (int c = 0; c < 4; ++c) acc[r][c] = (f32x4){0.f, 0.f, 0.f, 0.f};

#pragma unroll
    for (int kp = 0; kp < 2; ++kp) {
        bf16x8 ah[2], al[2], bh[4], bl[4];
#pragma unroll
        for (int r = 0; r < 2; ++r) {
            long row = rowbase + wr * 32 + r * 16 + lrow; if (row >= NE) row = NE - 1;
            long ba = row * 64 + kp * 32 + quad * 8;
            ah[r] = *(const bf16x8*)(eh + ba);
            al[r] = *(const bf16x8*)(el + ba);
        }
#pragma unroll
        for (int c = 0; c < 4; ++c) {
            bh[c] = *(const bf16x8*)&u.b.Bh[wc * 64 + c * 16 + lrow][kp * 32 + quad * 8];
            bl[c] = *(const bf16x8*)&u.b.Bl[wc * 64 + c * 16 + lrow][kp * 32 + quad * 8];
        }
#pragma unroll
        for (int r = 0; r < 2; ++r)
#pragma unroll
            for (int c = 0; c < 4; ++c) {
                acc[r][c] = __builtin_amdgcn_mfma_f32_16x16x32_bf16(ah[r], bh[c], acc[r][c], 0, 0, 0);
                acc[r][c] = __builtin_amdgcn_mfma_f32_16x16x32_bf16(ah[r], bl[c], acc[r][c], 0, 0, 0);
                acc[r][c] = __builtin_amdgcn_mfma_f32_16x16x32_bf16(al[r], bh[c], acc[r][c], 0, 0, 0);
            }
    }
    __syncthreads();
    const int col = tid & 63, seg = tid >> 6;
    for (int p = 0; p < 2; ++p) {
        if (wc == p) {
#pragma unroll
            for (int c = 0; c < 4; ++c)
#pragma unroll
                for (int r = 0; r < 2; ++r)
#pragma unroll
                    for (int j = 0; j < 4; ++j)
                        u.cbuf[wr * 32 + r * 16 + quad * 4 + j][c * 16 + lrow] = acc[r][c][j];
        }
        __syncthreads();
        {
            int row = tid >> 2, q = tid & 3;
            const float* py = y + (long)s_sp[row] * 128 + p * 64 + q * 16;
            float* pc = &u.cbuf[row][q * 16];
#pragma unroll
            for (int g = 0; g < 4; ++g) {
                float4 yv = *(const float4*)(py + g * 4);
                pc[g * 4 + 0] = relu_f(pc[g * 4 + 0] + yv.x);
                pc[g * 4 + 1] = relu_f(pc[g * 4 + 1] + yv.y);
                pc[g * 4 + 2] = relu_f(pc[g * 4 + 2] + yv.z);
                pc[g * 4 + 3] = relu_f(pc[g * 4 + 3] + yv.w);
            }
        }
        __syncthreads();
        int cur = -1; float sum = 0.0f;
        for (int rr = seg * 16; rr < seg * 16 + 16; ++rr) {
            int d = s_dp[rr];
            if (d != cur) {
                if (cur >= 0) atomicAdd(&agg[(long)cur * 128 + p * 64 + col], sum);
                cur = d; sum = 0.0f;
            }
            sum += u.cbuf[rr][col];
        }
        if (cur >= 0) atomicAdd(&agg[(long)cur * 128 + p * 64 + col], sum);
        __syncthreads();
    }
}

// ========== fused edge-update + message kernel (see R11/R12 notes) ==========
__global__ __launch_bounds__(256) void k_msg2e(
    u16* __restrict__ eh, u16* __restrict__ el,
    const int* __restrict__ sp, const int* __restrict__ dp,
    const u16* __restrict__ B1th, const u16* __restrict__ B1tl,  // Wet layer [64][320]; k=256..319
    const u16* __restrict__ B2th, const u16* __restrict__ B2tl,  // Wmt layer [128][192]; k=128..191
    const float* __restrict__ uu,   // [NN][128] = [u1|u2]
    const float* __restrict__ y,    // [NN][128]
    float* __restrict__ agg,
    int write_e)
{
    __shared__ union {
        struct { u16 h[64][72]; u16 l[64][72]; } b1;
        float cb[64][66];
    } r1;
    __shared__ struct { u16 h[64][72]; u16 l[64][72]; } r3;
    __shared__ int s_sp[64], s_dp[64];
    const int tid = threadIdx.x;
    const long rowbase = (long)blockIdx.x * 64;
    if (tid < 64) {
        long r = rowbase + tid;
        int rr = (r < NE) ? (int)r : (NE - 1);
        s_sp[tid] = sp[rr];
        s_dp[tid] = dp[rr];
    }
    {
        int colb = tid >> 2, kh = (tid & 3) * 16;
        long bb = (long)colb * 320 + 256 + kh;
        *(int4*)&r1.b1.h[colb][kh]     = *(const int4*)(B1th + bb);
        *(int4*)&r1.b1.h[colb][kh + 8] = *(const int4*)(B1th + bb + 8);
        *(int4*)&r1.b1.l[colb][kh]     = *(const int4*)(B1tl + bb);
        *(int4*)&r1.b1.l[colb][kh + 8] = *(const int4*)(B1tl + bb + 8);
    }
    __syncthreads();
    const int wave = tid >> 6, lane = tid & 63;
    const int quad = lane >> 4, lrow = lane & 15;
    const int wr = wave >> 1, wc = wave & 1;

    f32x4 acc1[2][2];
#pragma unroll
    for (int r = 0; r < 2; ++r)
#pragma unroll
        for (int c = 0; c < 2; ++c) acc1[r][c] = (f32x4){0.f, 0.f, 0.f, 0.f};
#pragma unroll
    for (int kp = 0; kp < 2; ++kp) {
        bf16x8 ah[2], al[2], bh[2], bl[2];
#pragma unroll
        for (int r = 0; r < 2; ++r) {
            long row = rowbase + wr * 32 + r * 16 + lrow; if (row >= NE) row = NE - 1;
            long ba = row * 64 + kp * 32 + quad * 8;
            ah[r] = *(const bf16x8*)(eh + ba);
            al[r] = *(const bf16x8*)(el + ba);
        }
#pragma unroll
        for (int c = 0; c < 2; ++c) {
            bh[c] = *(const bf16x8*)&r1.b1.h[wc * 32 + c * 16 + lrow][kp * 32 + quad * 8];
            bl[c] = *(const bf16x8*)&r1.b1.l[wc * 32 + c * 16 + lrow][kp * 32 + quad * 8];
        }
#pragma unroll
        for (int r = 0; r < 2; ++r)
#pragma unroll
            for (int c = 0; c < 2; ++c) {
                acc1[r][c] = __builtin_amdgcn_mfma_f32_16x16x32_bf16(ah[r], bh[c], acc1[r][c], 0, 0, 0);
                acc1[r][c] = __builtin_amdgcn_mfma_f32_16x16x32_bf16(ah[r], bl[c], acc1[r][c], 0, 0, 0);
                acc1[r][c] = __builtin_amdgcn_mfma_f32_16x16x32_bf16(al[r], bh[c], acc1[r][c], 0, 0, 0);
            }
    }
    __syncthreads();
#pragma unroll
    for (int c = 0; c < 2; ++c)
#pragma unroll
        for (int r = 0; r < 2; ++r)
#pragma unroll
            for (int j = 0; j < 4; ++j)
                r1.cb[wr * 32 + r * 16 + quad * 4 + j][wc * 32 + c * 16 + lrow] = acc1[r][c][j];
    __syncthreads();
    {
        const int row = tid >> 2, q = tid & 3;
        const float* pu1 = uu + (long)s_sp[row] * 128 + q * 16;
        const float* pu2 = uu + (long)s_dp[row] * 128 + 64 + q * 16;
        const float* pc = &r1.cb[row][q * 16];
        u16x8 hv0, lv0, hv1, lv1;
#pragma unroll
        for (int half = 0; half < 2; ++half) {
            float4 a0 = *(const float4*)(pu1 + half * 8);
            float4 a1 = *(const float4*)(pu1 + half * 8 + 4);
            float4 b0 = *(const float4*)(pu2 + half * 8);
            float4 b1 = *(const float4*)(pu2 + half * 8 + 4);
            float s[8] = {a0.x + b0.x, a0.y + b0.y, a0.z + b0.z, a0.w + b0.w,
                          a1.x + b1.x, a1.y + b1.y, a1.z + b1.z, a1.w + b1.w};
            u16x8 hv, lv;
#pragma unroll
            for (int k = 0; k < 8; ++k) {
                float v = relu_f(pc[half * 8 + k] + s[k]);
                u16 h = f2bf(v);
                hv[k] = h;
                lv[k] = f2bf(v - bf2f(h));
            }
            if (half == 0) { hv0 = hv; lv0 = lv; } else { hv1 = hv; lv1 = lv; }
        }
        *(u16x8*)&r3.h[row][q * 16]     = hv0;
        *(u16x8*)&r3.h[row][q * 16 + 8] = hv1;
        *(u16x8*)&r3.l[row][q * 16]     = lv0;
        *(u16x8*)&r3.l[row][q * 16 + 8] = lv1;
        long grow = rowbase + row;
        if (write_e && grow < NE) {
            long o = grow * 64 + q * 16;
            *(u16x8*)(eh + o)     = hv0;
            *(u16x8*)(eh + o + 8) = hv1;
            *(u16x8*)(el + o)     = lv0;
            *(u16x8*)(el + o + 8) = lv1;
        }
    }
    __syncthreads();
    const int col = tid & 63, seg = tid >> 6;
    const u16* pB2h = B2th + (long)(wc * 32 + lrow) * 192 + 128 + quad * 8;
    const u16* pB2l = B2tl + (long)(wc * 32 + lrow) * 192 + 128 + quad * 8;
    for (int p = 0; p < 2; ++p) {
        f32x4 acc2[2][2];
#pragma unroll
        for (int r = 0; r < 2; ++r)
#pragma unroll
            for (int c = 0; c < 2; ++c) acc2[r][c] = (f32x4){0.f, 0.f, 0.f, 0.f};
#pragma unroll
        for (int kp = 0; kp < 2; ++kp) {
            bf16x8 ah[2], al[2], bh[2], bl[2];
#pragma unroll
            for (int r = 0; r < 2; ++r) {
                ah[r] = *(const bf16x8*)&r3.h[wr * 32 + r * 16 + lrow][kp * 32 + quad * 8];
                al[r] = *(const bf16x8*)&r3.l[wr * 32 + r * 16 + lrow][kp * 32 + quad * 8];
            }
#pragma unroll
            for (int c = 0; c < 2; ++c) {
                long off = (long)(p * 64 + c * 16) * 192 + kp * 32;
                bh[c] = *(const bf16x8*)(pB2h + off);
                bl[c] = *(const bf16x8*)(pB2l + off);
            }
#pragma unroll
            for (int r = 0; r < 2; ++r)
#pragma unroll
                for (int c = 0; c < 2; ++c) {
                    acc2[r][c] = __builtin_amdgcn_mfma_f32_16x16x32_bf16(ah[r], bh[c], acc2[r][c], 0, 0, 0);
                    acc2[r][c] = __builtin_amdgcn_mfma_f32_16x16x32_bf16(ah[r], bl[c], acc2[r][c], 0, 0, 0);
                    acc2[r][c] = __builtin_amdgcn_mfma_f32_16x16x32_bf16(al[r], bh[c], acc2[r][c], 0, 0, 0);
                }
        }
#pragma unroll
        for (int c = 0; c < 2; ++c)
#pragma unroll
            for (int r = 0; r < 2; ++r)
#pragma unroll
                for (int j = 0; j < 4; ++j)
                    r1.cb[wr * 32 + r * 16 + quad * 4 + j][wc * 32 + c * 16 + lrow] = acc2[r][c][j];
        __syncthreads();
        {
            int row = tid >> 2, q = tid & 3;
            const float* py = y + (long)s_sp[row] * 128 + p * 64 + q * 16;
            float* pc = &r1.cb[row][q * 16];
#pragma unroll
            for (int g = 0; g < 4; ++g) {
                float4 yv = *(const float4*)(py + g * 4);
                pc[g * 4 + 0] = relu_f(pc[g * 4 + 0] + yv.x);
                pc[g * 4 + 1] = relu_f(pc[g * 4 + 1] + yv.y);
                pc[g * 4 + 2] = relu_f(pc[g * 4 + 2] + yv.z);
                pc[g * 4 + 3] = relu_f(pc[g * 4 + 3] + yv.w);
            }
        }
        __syncthreads();
        {
            int cur = -1; float sum = 0.0f;
            for (int rr = seg * 16; rr < seg * 16 + 16; ++rr) {
                int d = (rowbase + rr < NE) ? s_dp[rr] : -1;
                if (d != cur) {
                    if (cur >= 0) atomicAdd(&agg[(long)cur * 128 + p * 64 + col], sum);
                    cur = d; sum = 0.0f;
                }
                sum += r1.cb[rr][col];
            }
            if (cur >= 0) atomicAdd(&agg[(long)cur * 128 + p * 64 + col], sum);
        }
        __syncthreads();
    }
}

// ================= node update GEMM (MFMA, split bf16, fused L2-norm) =================
__global__ __launch_bounds__(256) void k_update_mfma(
    float* __restrict__ agg, const float* __restrict__ icnt,
    u16* __restrict__ xh, u16* __restrict__ xl,
    const u16* __restrict__ Bth, const u16* __restrict__ Btl,
    const float* __restrict__ bias, int zero_agg)
{
    __shared__ u16 Ah[64][40], Al[64][40], Bh[128][40], Bl[128][40];
    __shared__ float s_ic[64];
    __shared__ float sP[64][2];
    const int tid = threadIdx.x;
    const long rowbase = (long)blockIdx.x * 64;
    if (tid < 64) {
        long r = rowbase + tid;
        int rr = (r < NN) ? (int)r : (NN - 1);
        s_ic[tid] = icnt[rr];
    }
    __syncthreads();
    const int wave = tid >> 6, lane = tid & 63;
    const int quad = lane >> 4, lrow = lane & 15;
    const int wr = wave >> 1, wc = wave & 1;
    const int arow = tid >> 2, akh = (tid & 3) * 8;
    const int brow = tid >> 1, bkh = (tid & 1) << 4;

    f32x4 acc[2][4];
#pragma unroll
    for (int r = 0; r < 2; ++r)
#pragma unroll
        for (int c = 0; c < 4; ++c) acc[r][c] = (f32x4){0.f, 0.f, 0.f, 0.f};

    for (int kp = 0; kp < 8; ++kp) {
        const int k0 = kp * 32;
        if (k0 < 128) {
            long r = rowbase + arow;
            const bool own = (r < NN);
            if (!own) r = NN - 1;
            float* pa = agg + r * 128 + k0 + akh;
            float ic = s_ic[arow];
#pragma unroll
            for (int q = 0; q < 8; q += 4) {
                float4 f = *(const float4*)(pa + q);
                float vv[4] = {f.x, f.y, f.z, f.w};
#pragma unroll
                for (int j = 0; j < 4; ++j) {
                    float v = vv[j] * ic;
                    u16 h = f2bf(v);
                    Ah[arow][akh + q + j] = h;
                    Al[arow][akh + q + j] = f2bf(v - bf2f(h));
                }
            }
            if (zero_agg && own) {
                float4 z = {0.f, 0.f, 0.f, 0.f};
                *(float4*)(pa + 0) = z;
                *(float4*)(pa + 4) = z;
            }
        } else {
            long r = rowbase + arow; if (r >= NN) r = NN - 1;
            long b = r * 128 + (k0 - 128 + akh);
            *(int4*)&Ah[arow][akh] = *(const int4*)(xh + b);
            *(int4*)&Al[arow][akh] = *(const int4*)(xl + b);
        }
        {
            long b = (long)brow * 256 + k0 + bkh;
            *(int4*)&Bh[brow][bkh]     = *(const int4*)(Bth + b);
            *(int4*)&Bh[brow][bkh + 8] = *(const int4*)(Bth + b + 8);
            *(int4*)&Bl[brow][bkh]     = *(const int4*)(Btl + b);
            *(int4*)&Bl[brow][bkh + 8] = *(const int4*)(Btl + b + 8);
        }
        __syncthreads();
        bf16x8 ah[2], al[2], bh[4], bl[4];
#pragma unroll
        for (int r = 0; r < 2; ++r) {
            ah[r] = *(const bf16x8*)&Ah[wr * 32 + r * 16 + lrow][quad * 8];
            al[r] = *(const bf16x8*)&Al[wr * 32 + r * 16 + lrow][quad * 8];
        }
#pragma unroll
        for (int c = 0; c < 4; ++c) {
            bh[c] = *(const bf16x8*)&Bh[wc * 64 + c * 16 + lrow][quad * 8];
            bl[c] = *(const bf16x8*)&Bl[wc * 64 + c * 16 + lrow][quad * 8];
        }
#pragma unroll
        for (int r = 0; r < 2; ++r)
#pragma unroll
            for (int c = 0; c < 4; ++c) {
                acc[r][c] = __builtin_amdgcn_mfma_f32_16x16x32_bf16(ah[r], bh[c], acc[r][c], 0, 0, 0);
                acc[r][c] = __builtin_amdgcn_mfma_f32_16x16x32_bf16(ah[r], bl[c], acc[r][c], 0, 0, 0);
                acc[r][c] = __builtin_amdgcn_mfma_f32_16x16x32_bf16(al[r], bh[c], acc[r][c], 0, 0, 0);
            }
        __syncthreads();
    }
#pragma unroll
    for (int r = 0; r < 2; ++r)
#pragma unroll
        for (int c = 0; c < 4; ++c)
#pragma unroll
            for (int j = 0; j < 4; ++j)
                acc[r][c][j] = relu_f(acc[r][c][j] + bias[wc * 64 + c * 16 + lrow]);
#pragma unroll
    for (int r = 0; r < 2; ++r)
#pragma unroll
        for (int j = 0; j < 4; ++j) {
            float s2 = 0.0f;
#pragma unroll
            for (int c = 0; c < 4; ++c) { float v = acc[r][c][j]; s2 += v * v; }
#pragma unroll
            for (int m = 1; m < 16; m <<= 1) s2 += __shfl_xor(s2, m, 64);
            if (lrow == 0) sP[wr * 32 + r * 16 + quad * 4 + j][wc] = s2;
        }
    __syncthreads();
#pragma unroll
    for (int r = 0; r < 2; ++r)
#pragma unroll
        for (int j = 0; j < 4; ++j) {
            int lr = wr * 32 + r * 16 + quad * 4 + j;
            long grow = rowbase + lr;
            if (grow < NN) {
                float tot = sP[lr][0] + sP[lr][1];
                float rn = 1.0f / fmaxf(sqrtf(tot), 1e-12f);
#pragma unroll
                for (int c = 0; c < 4; ++c) {
                    float v = acc[r][c][j] * rn;
                    long o = grow * 128 + wc * 64 + c * 16 + lrow;
                    u16 h = f2bf(v);
                    xh[o] = h;
                    xl[o] = f2bf(v - bf2f(h));
                }
            }
        }
}

// ---------------- fused MLP head: out = relu(x@W1+b1)@W2+b2 ----------------
__global__ __launch_bounds__(256) void k_head(
    const u16* __restrict__ xh, const u16* __restrict__ xl,
    const float* __restrict__ W1, const float* __restrict__ b1,
    const float* __restrict__ W2, const float* __restrict__ b2,
    float* __restrict__ out)
{
    constexpr int KC = 64, NP = 2, EB = 32;
    __shared__ __align__(16) float At[KC][EB + 4];
    __shared__ __align__(16) union { float W1s[KC][64]; float W2s[KC][128]; } w;
    const int tid = threadIdx.x;
    const int rowbase = blockIdx.x * EB;
    const int wave = tid >> 6, lane = tid & 63;
    float acc[8];
#pragma unroll
    for (int i = 0; i < 8; ++i) acc[i] = 0.0f;

    for (int kp = 0; kp < NP; ++kp) {
        const int k0 = kp * KC;
        for (int i = tid; i < KC * EB; i += 256) {
            int e = i >> 6, kk = i & 63, k = k0 + kk;
            int r = min(rowbase + e, NN - 1);
            long b = (long)r * 128 + k;
            At[kk][e] = bf2f(xh[b]) + bf2f(xl[b]);
        }
        for (int i = tid; i < KC * 64; i += 256) {
            int kk = i >> 6, cc = i & 63;
            w.W1s[kk][cc] = W1[(size_t)(k0 + kk) * 64 + cc];
        }
        __syncthreads();
#pragma unroll 4
        for (int kk = 0; kk < KC; ++kk) {
            const float* ar = &At[kk][wave * 8];
            float4 a0 = *(const float4*)ar;
            float4 a1 = *(const float4*)(ar + 4);
            float wv = w.W1s[kk][lane];
            acc[0] += a0.x * wv; acc[1] += a0.y * wv; acc[2] += a0.z * wv; acc[3] += a0.w * wv;
            acc[4] += a1.x * wv; acc[5] += a1.y * wv; acc[6] += a1.z * wv; acc[7] += a1.w * wv;
        }
        __syncthreads();
    }
    {
        const float bv = b1[lane];
#pragma unroll
        for (int j = 0; j < 8; ++j)
            At[lane][wave * 8 + j] = relu_f(acc[j] + bv);
    }
    for (int i = tid; i < KC * 128; i += 256) {
        int kk = i >> 7, cc = i & 127;
        w.W2s[kk][cc] = W2[(size_t)kk * 128 + cc];
    }
    __syncthreads();
    float a2[16];
#pragma unroll
    for (int i = 0; i < 16; ++i) a2[i] = 0.0f;
#pragma unroll 4
    for (int kk = 0; kk < KC; ++kk) {
        const float* ar = &At[kk][wave * 8];
        float4 a0 = *(const float4*)ar;
        float4 a1 = *(const float4*)(ar + 4);
        float w0 = w.W2s[kk][lane], w1 = w.W2s[kk][64 + lane];
        a2[0] += a0.x * w0;  a2[1] += a0.y * w0;  a2[2] += a0.z * w0;  a2[3] += a0.w * w0;
        a2[4] += a1.x * w0;  a2[5] += a1.y * w0;  a2[6] += a1.z * w0;  a2[7] += a1.w * w0;
        a2[8] += a0.x * w1;  a2[9] += a0.y * w1;  a2[10] += a0.z * w1; a2[11] += a0.w * w1;
        a2[12] += a1.x * w1; a2[13] += a1.y * w1; a2[14] += a1.z * w1; a2[15] += a1.w * w1;
    }
    const float o0 = b2[lane], o1 = b2[64 + lane];
#pragma unroll
    for (int j = 0; j < 8; ++j) {
        int r = rowbase + wave * 8 + j;
        if (r < NN) {
            out[(size_t)r * 128 + lane] = a2[j] + o0;
            out[(size_t)r * 128 + 64 + lane] = a2[8 + j] + o1;
        }
    }
}

// ---------------- host-side launch ----------------
extern "C" void kernel_launch(void* const* d_in, const int* in_sizes, int n_in,
                              void* d_out, int out_size, void* d_ws, size_t ws_size,
                              hipStream_t stream) {
    const float* d_x  = (const float*)d_in[0];
    const float* d_ea = (const float*)d_in[1];
    const int*   d_ei = (const int*)d_in[2];
    const float* Wm   = (const float*)d_in[3];
    const float* bm   = (const float*)d_in[4];
    const float* Wa   = (const float*)d_in[5];
    const float* ba   = (const float*)d_in[6];
    const float* We   = (const float*)d_in[7];
    const float* be   = (const float*)d_in[8];
    const float* W1   = (const float*)d_in[9];
    const float* b1   = (const float*)d_in[10];
    const float* W2   = (const float*)d_in[11];
    const float* b2   = (const float*)d_in[12];
    float* out = (float*)d_out;

    const int* src = d_ei;
    const int* dst = d_ei + NE;

    char* p = (char*)d_ws;
    auto alloc = [&](size_t bytes) { char* q = p; p += (bytes + 255) & ~(size_t)255; return q; };
    u16* xh  = (u16*)alloc((size_t)NN * 128 * 2);
    u16* xl  = (u16*)alloc((size_t)NN * 128 * 2);
    u16* ehb = (u16*)alloc((size_t)NE * 64 * 2);
    u16* elb = (u16*)alloc((size_t)NE * 64 * 2);
    float* agg = (float*)alloc((size_t)NN * 128 * 4);
    float* yu  = (float*)alloc((size_t)NN * 128 * 4);   // y per layer
    float* ubuf = (float*)alloc((size_t)NN * 128 * 4);  // u per layer (coexists with y)
    float* cnt = (float*)alloc((size_t)NN * 4);
    float* zbuf = (float*)alloc(64 * 4);
    u16* Wmt_h = (u16*)alloc((size_t)3 * 192 * 128 * 2);
    u16* Wmt_l = (u16*)alloc((size_t)3 * 192 * 128 * 2);
    u16* Wat_h = (u16*)alloc((size_t)3 * 256 * 128 * 2);
    u16* Wat_l = (u16*)alloc((size_t)3 * 256 * 128 * 2);
    u16* Wet_h = (u16*)alloc((size_t)3 * 320 * 64 * 2);
    u16* Wet_l = (u16*)alloc((size_t)3 * 320 * 64 * 2);
    u16* Wxt_h = (u16*)alloc((size_t)3 * 128 * 128 * 2);
    u16* Wxt_l = (u16*)alloc((size_t)3 * 128 * 128 * 2);
    int* hist   = (int*)alloc((size_t)NN * 4);
    int* excl   = (int*)alloc((size_t)NN * 4);
    int* bsum   = (int*)alloc(128 * 4);
    int* cursor = (int*)alloc((size_t)NN * 4);
    int* perm   = (int*)alloc((size_t)NE * 4);
    int* sp     = (int*)alloc((size_t)NE * 4);
    int* dp     = (int*)alloc((size_t)NE * 4);

    const int NB1 = (NN + 511) / 512;

    hipMemsetAsync(hist, 0, NN * sizeof(int), stream);
    k_hist<<<(NE + 255) / 256, 256, 0, stream>>>(dst, hist);
    k_scan1<<<NB1, 512, 0, stream>>>(hist, excl, bsum, cnt);
    k_scan2<<<1, 128, 0, stream>>>(bsum, NB1);
    k_scan3<<<NB1, 512, 0, stream>>>(excl, bsum, cursor);
    k_scatter<<<(NE + 255) / 256, 256, 0, stream>>>(dst, cursor, perm);

    k_split_all<<<(XQ + NE * 16 + 255) / 256, 256, 0, stream>>>(
        d_x, xh, xl, d_ea, perm, ehb, elb, src, dst, sp, dp);
    k_wtall<<<(245824 + 255) / 256, 256, 0, stream>>>(
        Wm, Wa, We, Wmt_h, Wmt_l, Wat_h, Wat_l, Wet_h, Wet_l, Wxt_h, Wxt_l, zbuf);

    hipMemsetAsync(agg, 0, (size_t)NN * 128 * sizeof(float), stream);   // layer-0 only

    const int NGB = (NN + 63) / 64;
    // ---- layer 0 ----
    k_ngemm<<<NGB, 256, 0, stream>>>(xh, xl, Wmt_h, Wmt_l, 192, bm, bm + 64, yu);
    k_msg2<<<(NE + 63) / 64, 256, 0, stream>>>(ehb, elb, sp, dp, Wmt_h, Wmt_l, yu, agg);
    k_update_mfma<<<NGB, 256, 0, stream>>>(agg, cnt, xh, xl, Wat_h, Wat_l, ba, 1);
    // paired: u0 = x1@Wx(l=0)+[be|0], y1 = x1@Wm(l=1)+bm1  (same A operand)
    k_ngemm2<<<NGB, 256, 0, stream>>>(xh, xl,
        Wxt_h, Wxt_l,
        Wmt_h + (size_t)1 * 192 * 128, Wmt_l + (size_t)1 * 192 * 128,
        be, bm + 128, ubuf, yu);
    // ---- layer 1: fused edge(l=0, written back) + msg(l=1) ----
    k_msg2e<<<(NE + 63) / 64, 256, 0, stream>>>(ehb, elb, sp, dp,
        Wet_h, Wet_l,                                                     // We l=0
        Wmt_h + (size_t)1 * 192 * 128, Wmt_l + (size_t)1 * 192 * 128,     // Wm l=1
        ubuf, yu, agg, 1);
    k_update_mfma<<<NGB, 256, 0, stream>>>(agg, cnt, xh, xl,
        Wat_h + (size_t)1 * 256 * 128, Wat_l + (size_t)1 * 256 * 128, ba + 128, 1);
    // paired: u1 = x2@Wx(l=1)+[be1|0], y2 = x2@Wm(l=2)+bm2
    k_ngemm2<<<NGB, 256, 0, stream>>>(xh, xl,
        Wxt_h + (size_t)1 * 128 * 128, Wxt_l + (size_t)1 * 128 * 128,
        Wmt_h + (size_t)2 * 192 * 128, Wmt_l + (size_t)2 * 192 * 128,
        be + 64, bm + 256, ubuf, yu);
    // ---- layer 2: fused edge(l=1, not written) + msg(l=2) ----
    k_msg2e<<<(NE + 63) / 64, 256, 0, stream>>>(ehb, elb, sp, dp,
        Wet_h + (size_t)1 * 320 * 64, Wet_l + (size_t)1 * 320 * 64,       // We l=1
        Wmt_h + (size_t)2 * 192 * 128, Wmt_l + (size_t)2 * 192 * 128,     // Wm l=2
        ubuf, yu, agg, 0);
    k_update_mfma<<<NGB, 256, 0, stream>>>(agg, cnt, xh, xl,
        Wat_h + (size_t)2 * 256 * 128, Wat_l + (size_t)2 * 256 * 128, ba + 256, 0);

    k_head<<<(NN + 31) / 32, 256, 0, stream>>>(xh, xl, W1, b1, W2, b2, out);
}